// Round 2
// baseline (1100.083 us; speedup 1.0000x reference)
//
#include <hip/hip_runtime.h>
#include <hip/hip_bf16.h>
#include <stdint.h>

typedef unsigned short u16;
typedef __attribute__((ext_vector_type(8))) short bf16x8;
typedef __attribute__((ext_vector_type(4))) float f32x4;

#define AS1 __attribute__((address_space(1)))
#define AS3 __attribute__((address_space(3)))

__device__ __forceinline__ u16 f2bf(float f) {
  uint32_t x = __float_as_uint(f);
  uint32_t r = (x + 0x7FFFu + ((x >> 16) & 1u)) >> 16;
  return (u16)r;
}
__device__ __forceinline__ float bf2f(u16 u) {
  return __uint_as_float(((uint32_t)u) << 16);
}

__device__ __forceinline__ void gload_lds16(const void* g, void* l) {
  __builtin_amdgcn_global_load_lds((const AS1 void*)g, (AS3 void*)l, 16, 0, 0);
}

// ---------------- 3x3 avg pool, stride 1, pad 1, /9 ----------------
__global__ void pool3x3(const float* __restrict__ in, float* __restrict__ out,
                        int H, int W, int total) {
  int idx = blockIdx.x * 256 + threadIdx.x;
  if (idx >= total) return;
  int w = idx % W;
  int h = (idx / W) % H;
  int p = idx / (W * H);  // b*C + c
  const float* pl = in + (size_t)p * H * W;
  float s = 0.0f;
  #pragma unroll
  for (int dy = -1; dy <= 1; dy++) {
    int y = h + dy;
    if ((unsigned)y < (unsigned)H) {
      #pragma unroll
      for (int dx = -1; dx <= 1; dx++) {
        int x = w + dx;
        if ((unsigned)x < (unsigned)W) s += pl[y * W + x];
      }
    }
  }
  out[idx] = s * (1.0f / 9.0f);
}

// ---------------- CoordConv 1x1 ----------------
__global__ __launch_bounds__(256) void conv1x1_coord(
    const float* __restrict__ in,    // [B][K][HW]
    const float* __restrict__ w,     // [O][K+2]
    const float* __restrict__ bias,  // [O]
    float* __restrict__ out, int K, int O, int H, int W) {
  int HW = H * W;
  int b = blockIdx.z;
  int o0 = blockIdx.y * 64;
  int hw0 = blockIdx.x * 64;
  int tid = threadIdx.x;
  int tx = tid & 15;        // hw group
  int to = tid >> 4;        // o group
  __shared__ float in_t[16][64];
  __shared__ float w_t[16][64];
  float acc[4][4] = {};
  const float* inb = in + (size_t)b * K * HW;
  for (int c0 = 0; c0 < K; c0 += 16) {
    {
      int i = tid >> 4;
      int j = (tid & 15) * 4;
      *(f32x4*)&in_t[i][j] = *(const f32x4*)&inb[(size_t)(c0 + i) * HW + hw0 + j];
    }
    {
      int o = tid & 63;
      int ib = (tid >> 6) * 4;
      #pragma unroll
      for (int q = 0; q < 4; q++)
        w_t[ib + q][o] = w[(size_t)(o0 + o) * (K + 2) + c0 + ib + q];
    }
    __syncthreads();
    #pragma unroll
    for (int i = 0; i < 16; i++) {
      f32x4 wv = *(const f32x4*)&w_t[i][to * 4];
      f32x4 xv = *(const f32x4*)&in_t[i][tx * 4];
      #pragma unroll
      for (int oo = 0; oo < 4; oo++)
        #pragma unroll
        for (int xx = 0; xx < 4; xx++)
          acc[oo][xx] = fmaf(wv[oo], xv[xx], acc[oo][xx]);
    }
    __syncthreads();
  }
  float invW = 2.0f / (float)(W - 1);
  float invH = 2.0f / (float)(H - 1);
  int hwb = hw0 + tx * 4;
  int y = hwb / W;
  int xb = hwb % W;
  float yg = -1.0f + y * invH;
  #pragma unroll
  for (int oo = 0; oo < 4; oo++) {
    int o = o0 + to * 4 + oo;
    float wx = w[(size_t)o * (K + 2) + K];
    float wy = w[(size_t)o * (K + 2) + K + 1];
    float bb = bias[o];
    #pragma unroll
    for (int xx = 0; xx < 4; xx++) {
      float xg = -1.0f + (xb + xx) * invW;
      out[((size_t)b * O + o) * HW + hwb + xx] =
          acc[oo][xx] + wx * xg + wy * yg + bb;
    }
  }
}

// bilinear sample (half-pixel, edge clamp == jax renormalized linear for scale>=1)
__device__ __forceinline__ float bilin(const float* __restrict__ pl, int Hin,
                                       int y, int x) {
  float scale = (float)Hin / 64.0f;
  float fy = ((float)y + 0.5f) * scale - 0.5f;
  float fx = ((float)x + 0.5f) * scale - 0.5f;
  float y0f = floorf(fy), x0f = floorf(fx);
  float wy = fy - y0f, wx = fx - x0f;
  int y0 = (int)y0f, x0 = (int)x0f;
  int y1 = min(y0 + 1, Hin - 1), x1 = min(x0 + 1, Hin - 1);
  y0 = max(y0, 0); x0 = max(x0, 0);
  float v00 = pl[y0 * Hin + x0], v01 = pl[y0 * Hin + x1];
  float v10 = pl[y1 * Hin + x0], v11 = pl[y1 * Hin + x1];
  return (1.0f - wy) * ((1.0f - wx) * v00 + wx * v01) +
         wy * ((1.0f - wx) * v10 + wx * v11);
}

// ---------------- emit out_phi (fp32, channel-major, hw fastest) ----------------
__global__ void emit_phi(const float* __restrict__ in, float* __restrict__ outp,
                         int C, int Cin, int Hin, int ch_off, int total) {
  int idx = blockIdx.x * 256 + threadIdx.x;
  if (idx >= total) return;
  int x = idx & 63;
  int y = (idx >> 6) & 63;
  int c = (idx >> 12) % C;
  int b = idx / (C * 4096);
  const float* pl = in + (size_t)(b * Cin + c) * Hin * Hin;
  float v = bilin(pl, Hin, y, x);
  outp[((size_t)b * 896 + ch_off + c) * 4096 + (y << 6) + x] = v;
}

// ---------------- emit A (bf16, hw-major rows of length 1792, c fastest) ----------------
__global__ void emit_A(const float* __restrict__ in, u16* __restrict__ A,
                       int C, int Hin, int ch_off, int total) {
  int idx = blockIdx.x * 256 + threadIdx.x;
  if (idx >= total) return;
  int c = idx % C;
  int hw = (idx / C) & 4095;
  int b = idx / (C * 4096);
  int x = hw & 63, y = hw >> 6;
  const float* pl = in + (size_t)(b * C + c) * Hin * Hin;
  float v = bilin(pl, Hin, y, x);
  A[((size_t)b * 4096 + hw) * 1792 + ch_off + c] = f2bf(v);
}

// ---------------- fp32 [R][Cc] -> bf16 [Cc][R] transpose ----------------
__global__ __launch_bounds__(256) void transpose_f32_bf16(
    const float* __restrict__ in, u16* __restrict__ outT, int R, int Cc) {
  int r0 = blockIdx.y * 32, c0 = blockIdx.x * 32;
  __shared__ float t[32][33];
  int tid = threadIdx.x;
  int cl = tid & 31, rl = tid >> 5;  // rl 0..7
  #pragma unroll
  for (int q = 0; q < 4; q++)
    t[rl + q * 8][cl] = in[(size_t)(r0 + rl + q * 8) * Cc + c0 + cl];
  __syncthreads();
  #pragma unroll
  for (int q = 0; q < 4; q++) {
    int c = c0 + rl + q * 8;
    outT[(size_t)c * R + r0 + cl] = f2bf(t[cl][rl + q * 8]);
  }
}

// ---------------- row sum of squares over bf16 rows ----------------
__global__ __launch_bounds__(256) void rownorm2(const u16* __restrict__ X,
                                                float* __restrict__ out, int ncols) {
  int row = blockIdx.x * 4 + (threadIdx.x >> 6);
  int lane = threadIdx.x & 63;
  const u16* xr = X + (size_t)row * ncols;
  int n8 = ncols >> 3;
  float s = 0.0f;
  for (int c8 = lane; c8 < n8; c8 += 64) {
    bf16x8 v = *(const bf16x8*)&xr[c8 * 8];
    #pragma unroll
    for (int e = 0; e < 8; e++) {
      float f = bf2f((u16)v[e]);
      s = fmaf(f, f, s);
    }
  }
  #pragma unroll
  for (int off = 32; off; off >>= 1) s += __shfl_down(s, off);
  if (lane == 0) out[row] = s;
}

// ---------------- bf16 GEMM: S[m][n] = feats[m] + cents[n] - 2 * A[m]·Bt[n] ----------------
__global__ __launch_bounds__(256) void gemm_dist(
    const u16* __restrict__ A,   // [16384][1792]
    const u16* __restrict__ Bt,  // [4096][1792]
    const float* __restrict__ feats, const float* __restrict__ cents,
    float* __restrict__ S, int m_base) {
  const int K = 1792, N = 4096;
  int m0 = blockIdx.y * 128, n0 = blockIdx.x * 128;
  int tid = threadIdx.x;
  int wid = tid >> 6, lane = tid & 63;
  int wm = wid >> 1, wn = wid & 1;
  __shared__ u16 As[128 * 64];
  __shared__ u16 Bs[128 * 64];
  f32x4 acc[4][4] = {};
  int lrow = tid >> 3;           // 0..31
  int lcol = (tid & 7) * 8;
  const u16* ga = A + (size_t)(m_base + m0 + lrow) * K + lcol;
  const u16* gb = Bt + (size_t)(n0 + lrow) * K + lcol;
  char* lbaseA = (char*)As + wid * 1024;
  char* lbaseB = (char*)Bs + wid * 1024;
  for (int k0 = 0; k0 < K; k0 += 64) {
    #pragma unroll
    for (int q = 0; q < 4; q++) {
      gload_lds16(ga + (size_t)q * 32 * K + k0, lbaseA + q * 4096);
      gload_lds16(gb + (size_t)q * 32 * K + k0, lbaseB + q * 4096);
    }
    __syncthreads();
    #pragma unroll
    for (int kk = 0; kk < 2; kk++) {
      bf16x8 af[4], bfr[4];
      int kb = kk * 32 + (lane >> 4) * 8;
      #pragma unroll
      for (int i = 0; i < 4; i++)
        af[i] = *(const bf16x8*)&As[(wm * 64 + i * 16 + (lane & 15)) * 64 + kb];
      #pragma unroll
      for (int j = 0; j < 4; j++)
        bfr[j] = *(const bf16x8*)&Bs[(wn * 64 + j * 16 + (lane & 15)) * 64 + kb];
      #pragma unroll
      for (int i = 0; i < 4; i++)
        #pragma unroll
        for (int j = 0; j < 4; j++)
          acc[i][j] = __builtin_amdgcn_mfma_f32_16x16x32_bf16(af[i], bfr[j], acc[i][j], 0, 0, 0);
    }
    __syncthreads();
  }
  int rq = lane >> 4;
  int cq = lane & 15;
  #pragma unroll
  for (int i = 0; i < 4; i++) {
    int lm = m0 + wm * 64 + i * 16 + rq * 4;  // row within chunk
    #pragma unroll
    for (int j = 0; j < 4; j++) {
      int gn = n0 + wn * 64 + j * 16 + cq;
      float cn = cents[gn];
      #pragma unroll
      for (int reg = 0; reg < 4; reg++) {
        int gm = m_base + lm + reg;
        S[(size_t)(lm + reg) * N + gn] = feats[gm] + cn - 2.0f * acc[i][j][reg];
      }
    }
  }
}

// ---------------- per-row top-200 smallest (sorted) of 4096, emit sqrt ----------------
__global__ __launch_bounds__(256) void select_topk(const float* __restrict__ S,
                                                   float* __restrict__ out,
                                                   int row_base) {
  int row_local = blockIdx.x;
  int tid = threadIdx.x;
  const float* Sr = S + (size_t)row_local * 4096;
  uint32_t ku[16];
  #pragma unroll
  for (int j = 0; j < 16; j++) {
    uint32_t u = __float_as_uint(Sr[tid + 256 * j]);
    u ^= (u & 0x80000000u) ? 0xFFFFFFFFu : 0x80000000u;  // order-preserving
    ku[j] = u;
  }
  __shared__ uint32_t red[4];
  __shared__ uint32_t selv[256];
  __shared__ uint32_t cnt2[2];
  uint32_t lo = 0u, hi = 0xFFFFFFFFu;
  while (lo < hi) {
    uint32_t mid = lo + ((hi - lo) >> 1);
    int c = 0;
    #pragma unroll
    for (int j = 0; j < 16; j++) c += (ku[j] <= mid) ? 1 : 0;
    #pragma unroll
    for (int off = 32; off; off >>= 1) c += __shfl_down(c, off);
    if ((tid & 63) == 0) red[tid >> 6] = (uint32_t)c;
    __syncthreads();
    uint32_t total = red[0] + red[1] + red[2] + red[3];
    if (total >= 200u) hi = mid; else lo = mid + 1u;
    __syncthreads();
  }
  uint32_t T = lo;
  {
    int c = 0;
    #pragma unroll
    for (int j = 0; j < 16; j++) c += (ku[j] < T) ? 1 : 0;
    #pragma unroll
    for (int off = 32; off; off >>= 1) c += __shfl_down(c, off);
    if ((tid & 63) == 0) red[tid >> 6] = (uint32_t)c;
  }
  if (tid == 0) { cnt2[0] = 0; cnt2[1] = 0; }
  selv[tid] = 0xFFFFFFFFu;
  __syncthreads();
  uint32_t nless = red[0] + red[1] + red[2] + red[3];
  #pragma unroll
  for (int j = 0; j < 16; j++) {
    uint32_t u = ku[j];
    if (u < T) {
      uint32_t p = atomicAdd(&cnt2[0], 1u);
      selv[p] = u;
    } else if (u == T) {
      uint32_t p = atomicAdd(&cnt2[1], 1u);
      uint32_t d = nless + p;
      if (d < 200u) selv[d] = u;
    }
  }
  __syncthreads();
  for (int kk = 2; kk <= 256; kk <<= 1) {
    for (int jj = kk >> 1; jj > 0; jj >>= 1) {
      int ixj = tid ^ jj;
      if (ixj > tid) {
        uint32_t a = selv[tid], bb = selv[ixj];
        bool up = ((tid & kk) == 0);
        if ((a > bb) == up) { selv[tid] = bb; selv[ixj] = a; }
      }
      __syncthreads();
    }
  }
  if (tid < 200) {
    uint32_t u = selv[tid];
    u ^= (u & 0x80000000u) ? 0x80000000u : 0xFFFFFFFFu;
    float v = __uint_as_float(u);
    int grow = row_base + row_local;
    int b = grow >> 12, r = grow & 4095;
    out[((size_t)b * 200 + tid) * 4096 + r] = sqrtf(v);
  }
}

extern "C" void kernel_launch(void* const* d_in, const int* in_sizes, int n_in,
                              void* d_out, int out_size, void* d_ws, size_t ws_size,
                              hipStream_t stream) {
  const float* p0 = (const float*)d_in[0];   // (4,256,64,64)
  const float* p1 = (const float*)d_in[1];   // (4,512,32,32)
  const float* p2 = (const float*)d_in[2];   // (4,1024,16,16)
  const float* w1 = (const float*)d_in[5];   // (256,258)
  const float* b1 = (const float*)d_in[6];
  const float* w2 = (const float*)d_in[7];   // (512,514)
  const float* b2 = (const float*)d_in[8];
  const float* w3 = (const float*)d_in[9];   // (1024,1026)
  const float* b3 = (const float*)d_in[10];
  const float* Cm = (const float*)d_in[11];  // (1792,4096)

  float* out_score = (float*)d_out;                  // 4*200*4096 fp32
  float* out_phi = (float*)d_out + 3276800;          // 4*896*4096 fp32

  // workspace layout (peak ~140.6 MB)
  char* w = (char*)d_ws;
  u16* Abf = (u16*)w;                                //  58,720,256 B
  u16* Ct = (u16*)(w + 58720256);                    //  14,680,064 B
  float* feats = (float*)(w + 73400320);             //      65,536 B
  float* cents = (float*)(w + 73465856);             //      16,384 B
  float* S = (float*)(w + 73482240);                 //  67,108,864 B (per-chunk)
  // stage-A temps alias the S region and beyond (dead before first gemm)
  float* O1 = (float*)(w + 73482240);                //  16,777,216 B
  float* O2 = (float*)(w + 90259456);                //   8,388,608 B
  float* O3 = (float*)(w + 98648064);                //   4,194,304 B
  float* pooled1 = (float*)(w + 102842368);          //  16,777,216 B
  float* pooled2 = (float*)(w + 119619584);          //   8,388,608 B
  float* pooled3 = (float*)(w + 128008192);          //   4,194,304 B  -> ends 132,202,496

  // ---- stage A: pool ----
  pool3x3<<<16384, 256, 0, stream>>>(p0, pooled1, 64, 64, 4 * 256 * 64 * 64);
  pool3x3<<<8192, 256, 0, stream>>>(p1, pooled2, 32, 32, 4 * 512 * 32 * 32);
  pool3x3<<<4096, 256, 0, stream>>>(p2, pooled3, 16, 16, 4 * 1024 * 16 * 16);

  // ---- stage A: coordconv 1x1 ----
  conv1x1_coord<<<dim3(64, 4, 4), 256, 0, stream>>>(pooled1, w1, b1, O1, 256, 256, 64, 64);
  conv1x1_coord<<<dim3(16, 8, 4), 256, 0, stream>>>(pooled2, w2, b2, O2, 512, 512, 32, 32);
  conv1x1_coord<<<dim3(4, 16, 4), 256, 0, stream>>>(pooled3, w3, b3, O3, 1024, 1024, 16, 16);

  // ---- output 1: PHI[:, :896] (resize where needed) ----
  emit_phi<<<16384, 256, 0, stream>>>(O1, out_phi, 256, 256, 64, 0, 4 * 256 * 4096);
  emit_phi<<<32768, 256, 0, stream>>>(O2, out_phi, 512, 512, 32, 256, 4 * 512 * 4096);
  emit_phi<<<8192, 256, 0, stream>>>(O3, out_phi, 128, 1024, 16, 768, 4 * 128 * 4096);

  // ---- A matrix (bf16, [b*4096+hw][1792]) ----
  emit_A<<<16384, 256, 0, stream>>>(O1, Abf, 256, 64, 0, 4 * 256 * 4096);
  emit_A<<<32768, 256, 0, stream>>>(O2, Abf, 512, 32, 256, 4 * 512 * 4096);
  emit_A<<<65536, 256, 0, stream>>>(O3, Abf, 1024, 16, 768, 4 * 1024 * 4096);

  // ---- C transpose + bf16 ----
  transpose_f32_bf16<<<dim3(128, 56), 256, 0, stream>>>(Cm, Ct, 1792, 4096);

  // ---- norms ----
  rownorm2<<<4096, 256, 0, stream>>>(Abf, feats, 1792);
  rownorm2<<<1024, 256, 0, stream>>>(Ct, cents, 1792);

  // ---- distance GEMM + top-200, chunked by batch image (S = 67 MB) ----
  for (int mc = 0; mc < 4; mc++) {
    gemm_dist<<<dim3(32, 32), 256, 0, stream>>>(Abf, Ct, feats, cents, S, mc * 4096);
    select_topk<<<4096, 256, 0, stream>>>(S, out_score, mc * 4096);
  }
}

// Round 3
// 1090.337 us; speedup vs baseline: 1.0089x; 1.0089x over previous
//
#include <hip/hip_runtime.h>
#include <hip/hip_bf16.h>
#include <stdint.h>

typedef unsigned short u16;
typedef __attribute__((ext_vector_type(8))) short bf16x8;
typedef __attribute__((ext_vector_type(4))) float f32x4;

#define AS1 __attribute__((address_space(1)))
#define AS3 __attribute__((address_space(3)))

__device__ __forceinline__ u16 f2bf(float f) {
  uint32_t x = __float_as_uint(f);
  uint32_t r = (x + 0x7FFFu + ((x >> 16) & 1u)) >> 16;
  return (u16)r;
}
__device__ __forceinline__ float bf2f(u16 u) {
  return __uint_as_float(((uint32_t)u) << 16);
}

__device__ __forceinline__ void gload_lds16(const void* g, void* l) {
  __builtin_amdgcn_global_load_lds((const AS1 void*)g, (AS3 void*)l, 16, 0, 0);
}

// ---------------- 3x3 avg pool, stride 1, pad 1, /9 — 4 outputs/thread ----------------
template <int H, int W>
__global__ void pool3x3_v(const float* __restrict__ in, float* __restrict__ out) {
  constexpr int W4 = W / 4;
  int idx = blockIdx.x * 256 + threadIdx.x;  // over B*C*H*W/4
  int x0 = (idx % W4) * 4;
  int h = (idx / W4) % H;
  int p = idx / (W4 * H);  // b*C + c
  const float* pl = in + (size_t)p * H * W;
  float cs[6] = {0, 0, 0, 0, 0, 0};
  #pragma unroll
  for (int dy = -1; dy <= 1; dy++) {
    int yy = h + dy;
    if ((unsigned)yy < (unsigned)H) {
      const float* row = pl + yy * W;
      #pragma unroll
      for (int k = 0; k < 6; k++) {
        int xx = x0 - 1 + k;
        if ((unsigned)xx < (unsigned)W) cs[k] += row[xx];
      }
    }
  }
  f32x4 o;
  #pragma unroll
  for (int k = 0; k < 4; k++) o[k] = (cs[k] + cs[k + 1] + cs[k + 2]) * (1.0f / 9.0f);
  *(f32x4*)&out[(size_t)p * H * W + h * W + x0] = o;
}

// ---------------- CoordConv 1x1 ----------------
__global__ __launch_bounds__(256) void conv1x1_coord(
    const float* __restrict__ in,    // [B][K][HW]
    const float* __restrict__ w,     // [O][K+2]
    const float* __restrict__ bias,  // [O]
    float* __restrict__ out, int K, int O, int H, int W) {
  int HW = H * W;
  int b = blockIdx.z;
  int o0 = blockIdx.y * 64;
  int hw0 = blockIdx.x * 64;
  int tid = threadIdx.x;
  int tx = tid & 15;        // hw group
  int to = tid >> 4;        // o group
  __shared__ float in_t[16][64];
  __shared__ float w_t[16][64];
  float acc[4][4] = {};
  const float* inb = in + (size_t)b * K * HW;
  for (int c0 = 0; c0 < K; c0 += 16) {
    {
      int i = tid >> 4;
      int j = (tid & 15) * 4;
      *(f32x4*)&in_t[i][j] = *(const f32x4*)&inb[(size_t)(c0 + i) * HW + hw0 + j];
    }
    {
      int o = tid & 63;
      int ib = (tid >> 6) * 4;
      #pragma unroll
      for (int q = 0; q < 4; q++)
        w_t[ib + q][o] = w[(size_t)(o0 + o) * (K + 2) + c0 + ib + q];
    }
    __syncthreads();
    #pragma unroll
    for (int i = 0; i < 16; i++) {
      f32x4 wv = *(const f32x4*)&w_t[i][to * 4];
      f32x4 xv = *(const f32x4*)&in_t[i][tx * 4];
      #pragma unroll
      for (int oo = 0; oo < 4; oo++)
        #pragma unroll
        for (int xx = 0; xx < 4; xx++)
          acc[oo][xx] = fmaf(wv[oo], xv[xx], acc[oo][xx]);
    }
    __syncthreads();
  }
  float invW = 2.0f / (float)(W - 1);
  float invH = 2.0f / (float)(H - 1);
  int hwb = hw0 + tx * 4;
  int y = hwb / W;
  int xb = hwb % W;
  float yg = -1.0f + y * invH;
  #pragma unroll
  for (int oo = 0; oo < 4; oo++) {
    int o = o0 + to * 4 + oo;
    float wx = w[(size_t)o * (K + 2) + K];
    float wy = w[(size_t)o * (K + 2) + K + 1];
    float bb = bias[o];
    #pragma unroll
    for (int xx = 0; xx < 4; xx++) {
      float xg = -1.0f + (xb + xx) * invW;
      out[((size_t)b * O + o) * HW + hwb + xx] =
          acc[oo][xx] + wx * xg + wy * yg + bb;
    }
  }
}

// bilinear helpers (half-pixel, edge clamp)
template <int Hin>
__device__ __forceinline__ void bilin_coords(int v, int& i0, int& i1, float& wgt) {
  constexpr float scale = (float)Hin / 64.0f;
  float f = ((float)v + 0.5f) * scale - 0.5f;
  float f0 = floorf(f);
  wgt = f - f0;
  int i = (int)f0;
  i1 = min(i + 1, Hin - 1);
  i0 = max(i, 0);
}

// ---------------- emit out_phi (fp32, hw fastest) — 4 px/thread ----------------
template <int C, int Cin, int Hin>
__global__ void emit_phi_v(const float* __restrict__ in, float* __restrict__ outp,
                           int ch_off) {
  int idx = blockIdx.x * 256 + threadIdx.x;  // over B*C*1024
  int x0 = (idx & 15) * 4;
  int y = (idx >> 4) & 63;
  int c = (idx >> 10) % C;
  int b = idx / (C * 1024);
  const float* pl = in + (size_t)(b * Cin + c) * (Hin * Hin);
  int y0, y1; float wy;
  bilin_coords<Hin>(y, y0, y1, wy);
  const float* r0 = pl + y0 * Hin;
  const float* r1 = pl + y1 * Hin;
  f32x4 o;
  #pragma unroll
  for (int k = 0; k < 4; k++) {
    int xx0, xx1; float wx;
    bilin_coords<Hin>(x0 + k, xx0, xx1, wx);
    float top = (1.0f - wx) * r0[xx0] + wx * r0[xx1];
    float bot = (1.0f - wx) * r1[xx0] + wx * r1[xx1];
    o[k] = (1.0f - wy) * top + wy * bot;
  }
  *(f32x4*)&outp[((size_t)b * 896 + ch_off + c) * 4096 + (y << 6) + x0] = o;
}

// ---------------- emit A (bf16, c fastest) — 8 channels/thread ----------------
template <int C, int Hin>
__global__ void emit_A_v(const float* __restrict__ in, u16* __restrict__ A,
                         int ch_off) {
  constexpr int C8 = C / 8;
  int idx = blockIdx.x * 256 + threadIdx.x;  // over B*4096*C8
  int c0 = (idx % C8) * 8;
  int hw = (idx / C8) & 4095;
  int b = idx / (C8 * 4096);
  int x = hw & 63, y = hw >> 6;
  int y0, y1, x0, x1; float wy, wx;
  bilin_coords<Hin>(y, y0, y1, wy);
  bilin_coords<Hin>(x, x0, x1, wx);
  float w00 = (1.0f - wy) * (1.0f - wx), w01 = (1.0f - wy) * wx;
  float w10 = wy * (1.0f - wx), w11 = wy * wx;
  const float* base = in + (size_t)(b * C + c0) * (Hin * Hin);
  int i00 = y0 * Hin + x0, i01 = y0 * Hin + x1;
  int i10 = y1 * Hin + x0, i11 = y1 * Hin + x1;
  bf16x8 o;
  #pragma unroll
  for (int e = 0; e < 8; e++) {
    const float* pl = base + e * (Hin * Hin);
    float v = w00 * pl[i00] + w01 * pl[i01] + w10 * pl[i10] + w11 * pl[i11];
    o[e] = (short)f2bf(v);
  }
  *(bf16x8*)&A[((size_t)b * 4096 + hw) * 1792 + ch_off + c0] = o;
}

// ---------------- fp32 [R][Cc] -> bf16 [Cc][R] transpose ----------------
__global__ __launch_bounds__(256) void transpose_f32_bf16(
    const float* __restrict__ in, u16* __restrict__ outT, int R, int Cc) {
  int r0 = blockIdx.y * 32, c0 = blockIdx.x * 32;
  __shared__ float t[32][33];
  int tid = threadIdx.x;
  int cl = tid & 31, rl = tid >> 5;  // rl 0..7
  #pragma unroll
  for (int q = 0; q < 4; q++)
    t[rl + q * 8][cl] = in[(size_t)(r0 + rl + q * 8) * Cc + c0 + cl];
  __syncthreads();
  #pragma unroll
  for (int q = 0; q < 4; q++) {
    int c = c0 + rl + q * 8;
    outT[(size_t)c * R + r0 + cl] = f2bf(t[cl][rl + q * 8]);
  }
}

// ---------------- row sum of squares over bf16 rows ----------------
__global__ __launch_bounds__(256) void rownorm2(const u16* __restrict__ X,
                                                float* __restrict__ out, int ncols) {
  int row = blockIdx.x * 4 + (threadIdx.x >> 6);
  int lane = threadIdx.x & 63;
  const u16* xr = X + (size_t)row * ncols;
  int n8 = ncols >> 3;
  float s = 0.0f;
  for (int c8 = lane; c8 < n8; c8 += 64) {
    bf16x8 v = *(const bf16x8*)&xr[c8 * 8];
    #pragma unroll
    for (int e = 0; e < 8; e++) {
      float f = bf2f((u16)v[e]);
      s = fmaf(f, f, s);
    }
  }
  #pragma unroll
  for (int off = 32; off; off >>= 1) s += __shfl_down(s, off);
  if (lane == 0) out[row] = s;
}

// ---------------- bf16 GEMM: S[m][n] = feats[m] + cents[n] - 2 * A[m]·Bt[n] ----------------
__global__ __launch_bounds__(256) void gemm_dist(
    const u16* __restrict__ A,   // [16384][1792]
    const u16* __restrict__ Bt,  // [4096][1792]
    const float* __restrict__ feats, const float* __restrict__ cents,
    float* __restrict__ S, int m_base) {
  const int K = 1792, N = 4096;
  int m0 = blockIdx.y * 128, n0 = blockIdx.x * 128;
  int tid = threadIdx.x;
  int wid = tid >> 6, lane = tid & 63;
  int wm = wid >> 1, wn = wid & 1;
  __shared__ u16 As[128 * 64];
  __shared__ u16 Bs[128 * 64];
  f32x4 acc[4][4] = {};
  int lrow = tid >> 3;           // 0..31
  int lcol = (tid & 7) * 8;
  const u16* ga = A + (size_t)(m_base + m0 + lrow) * K + lcol;
  const u16* gb = Bt + (size_t)(n0 + lrow) * K + lcol;
  char* lbaseA = (char*)As + wid * 1024;
  char* lbaseB = (char*)Bs + wid * 1024;
  for (int k0 = 0; k0 < K; k0 += 64) {
    #pragma unroll
    for (int q = 0; q < 4; q++) {
      gload_lds16(ga + (size_t)q * 32 * K + k0, lbaseA + q * 4096);
      gload_lds16(gb + (size_t)q * 32 * K + k0, lbaseB + q * 4096);
    }
    __syncthreads();
    #pragma unroll
    for (int kk = 0; kk < 2; kk++) {
      bf16x8 af[4], bfr[4];
      int kb = kk * 32 + (lane >> 4) * 8;
      #pragma unroll
      for (int i = 0; i < 4; i++)
        af[i] = *(const bf16x8*)&As[(wm * 64 + i * 16 + (lane & 15)) * 64 + kb];
      #pragma unroll
      for (int j = 0; j < 4; j++)
        bfr[j] = *(const bf16x8*)&Bs[(wn * 64 + j * 16 + (lane & 15)) * 64 + kb];
      #pragma unroll
      for (int i = 0; i < 4; i++)
        #pragma unroll
        for (int j = 0; j < 4; j++)
          acc[i][j] = __builtin_amdgcn_mfma_f32_16x16x32_bf16(af[i], bfr[j], acc[i][j], 0, 0, 0);
    }
    __syncthreads();
  }
  int rq = lane >> 4;
  int cq = lane & 15;
  #pragma unroll
  for (int i = 0; i < 4; i++) {
    int lm = m0 + wm * 64 + i * 16 + rq * 4;  // row within chunk
    #pragma unroll
    for (int j = 0; j < 4; j++) {
      int gn = n0 + wn * 64 + j * 16 + cq;
      float cn = cents[gn];
      #pragma unroll
      for (int reg = 0; reg < 4; reg++) {
        int gm = m_base + lm + reg;
        S[(size_t)(lm + reg) * N + gn] = feats[gm] + cn - 2.0f * acc[i][j][reg];
      }
    }
  }
}

// ---------------- per-row top-200 smallest (sorted) of 4096, emit sqrt ----------------
__global__ __launch_bounds__(256) void select_topk(const float* __restrict__ S,
                                                   float* __restrict__ out,
                                                   int row_base) {
  int row_local = blockIdx.x;
  int tid = threadIdx.x;
  const float* Sr = S + (size_t)row_local * 4096;
  uint32_t ku[16];
  #pragma unroll
  for (int j = 0; j < 4; j++) {
    f32x4 v = *(const f32x4*)&Sr[(tid + 256 * j) * 4];
    #pragma unroll
    for (int e = 0; e < 4; e++) {
      uint32_t u = __float_as_uint(v[e]);
      u ^= (u & 0x80000000u) ? 0xFFFFFFFFu : 0x80000000u;  // order-preserving
      ku[j * 4 + e] = u;
    }
  }
  __shared__ uint32_t red[4];
  __shared__ uint32_t selv[256];
  __shared__ uint32_t cnt2[2];
  uint32_t lo = 0u, hi = 0xFFFFFFFFu;
  while (lo < hi) {
    uint32_t mid = lo + ((hi - lo) >> 1);
    int c = 0;
    #pragma unroll
    for (int j = 0; j < 16; j++) c += (ku[j] <= mid) ? 1 : 0;
    #pragma unroll
    for (int off = 32; off; off >>= 1) c += __shfl_down(c, off);
    if ((tid & 63) == 0) red[tid >> 6] = (uint32_t)c;
    __syncthreads();
    uint32_t total = red[0] + red[1] + red[2] + red[3];
    if (total >= 200u) hi = mid; else lo = mid + 1u;
    __syncthreads();
  }
  uint32_t T = lo;
  {
    int c = 0;
    #pragma unroll
    for (int j = 0; j < 16; j++) c += (ku[j] < T) ? 1 : 0;
    #pragma unroll
    for (int off = 32; off; off >>= 1) c += __shfl_down(c, off);
    if ((tid & 63) == 0) red[tid >> 6] = (uint32_t)c;
  }
  if (tid == 0) { cnt2[0] = 0; cnt2[1] = 0; }
  selv[tid] = 0xFFFFFFFFu;
  __syncthreads();
  uint32_t nless = red[0] + red[1] + red[2] + red[3];
  #pragma unroll
  for (int j = 0; j < 16; j++) {
    uint32_t u = ku[j];
    if (u < T) {
      uint32_t p = atomicAdd(&cnt2[0], 1u);
      selv[p] = u;
    } else if (u == T) {
      uint32_t p = atomicAdd(&cnt2[1], 1u);
      uint32_t d = nless + p;
      if (d < 200u) selv[d] = u;
    }
  }
  __syncthreads();
  for (int kk = 2; kk <= 256; kk <<= 1) {
    for (int jj = kk >> 1; jj > 0; jj >>= 1) {
      int ixj = tid ^ jj;
      if (ixj > tid) {
        uint32_t a = selv[tid], bb = selv[ixj];
        bool up = ((tid & kk) == 0);
        if ((a > bb) == up) { selv[tid] = bb; selv[ixj] = a; }
      }
      __syncthreads();
    }
  }
  if (tid < 200) {
    uint32_t u = selv[tid];
    u ^= (u & 0x80000000u) ? 0x80000000u : 0xFFFFFFFFu;
    float v = __uint_as_float(u);
    int grow = row_base + row_local;
    int b = grow >> 12, r = grow & 4095;
    out[((size_t)b * 200 + tid) * 4096 + r] = sqrtf(v);
  }
}

extern "C" void kernel_launch(void* const* d_in, const int* in_sizes, int n_in,
                              void* d_out, int out_size, void* d_ws, size_t ws_size,
                              hipStream_t stream) {
  const float* p0 = (const float*)d_in[0];   // (4,256,64,64)
  const float* p1 = (const float*)d_in[1];   // (4,512,32,32)
  const float* p2 = (const float*)d_in[2];   // (4,1024,16,16)
  const float* w1 = (const float*)d_in[5];   // (256,258)
  const float* b1 = (const float*)d_in[6];
  const float* w2 = (const float*)d_in[7];   // (512,514)
  const float* b2 = (const float*)d_in[8];
  const float* w3 = (const float*)d_in[9];   // (1024,1026)
  const float* b3 = (const float*)d_in[10];
  const float* Cm = (const float*)d_in[11];  // (1792,4096)

  float* out_score = (float*)d_out;                  // 4*200*4096 fp32
  float* out_phi = (float*)d_out + 3276800;          // 4*896*4096 fp32

  // workspace layout (peak ~140.6 MB)
  char* w = (char*)d_ws;
  u16* Abf = (u16*)w;                                //  58,720,256 B
  u16* Ct = (u16*)(w + 58720256);                    //  14,680,064 B
  float* feats = (float*)(w + 73400320);             //      65,536 B
  float* cents = (float*)(w + 73465856);             //      16,384 B
  float* S = (float*)(w + 73482240);                 //  67,108,864 B (per-chunk)
  // stage-A temps alias the S region and beyond (dead before first gemm)
  float* O1 = (float*)(w + 73482240);                //  16,777,216 B
  float* O2 = (float*)(w + 90259456);                //   8,388,608 B
  float* O3 = (float*)(w + 98648064);                //   4,194,304 B
  float* pooled1 = (float*)(w + 102842368);          //  16,777,216 B
  float* pooled2 = (float*)(w + 119619584);          //   8,388,608 B
  float* pooled3 = (float*)(w + 128008192);          //   4,194,304 B  -> ends 132,202,496

  // ---- stage A: pool (4 outputs/thread) ----
  pool3x3_v<64, 64><<<4096, 256, 0, stream>>>(p0, pooled1);
  pool3x3_v<32, 32><<<2048, 256, 0, stream>>>(p1, pooled2);
  pool3x3_v<16, 16><<<1024, 256, 0, stream>>>(p2, pooled3);

  // ---- stage A: coordconv 1x1 ----
  conv1x1_coord<<<dim3(64, 4, 4), 256, 0, stream>>>(pooled1, w1, b1, O1, 256, 256, 64, 64);
  conv1x1_coord<<<dim3(16, 8, 4), 256, 0, stream>>>(pooled2, w2, b2, O2, 512, 512, 32, 32);
  conv1x1_coord<<<dim3(4, 16, 4), 256, 0, stream>>>(pooled3, w3, b3, O3, 1024, 1024, 16, 16);

  // ---- output 1: PHI[:, :896] (resize where needed), 4 px/thread ----
  emit_phi_v<256, 256, 64><<<4096, 256, 0, stream>>>(O1, out_phi, 0);
  emit_phi_v<512, 512, 32><<<8192, 256, 0, stream>>>(O2, out_phi, 256);
  emit_phi_v<128, 1024, 16><<<2048, 256, 0, stream>>>(O3, out_phi, 768);

  // ---- A matrix (bf16, [b*4096+hw][1792]), 8 ch/thread ----
  emit_A_v<256, 64><<<2048, 256, 0, stream>>>(O1, Abf, 0);
  emit_A_v<512, 32><<<4096, 256, 0, stream>>>(O2, Abf, 256);
  emit_A_v<1024, 16><<<8192, 256, 0, stream>>>(O3, Abf, 768);

  // ---- C transpose + bf16 ----
  transpose_f32_bf16<<<dim3(128, 56), 256, 0, stream>>>(Cm, Ct, 1792, 4096);

  // ---- norms ----
  rownorm2<<<4096, 256, 0, stream>>>(Abf, feats, 1792);
  rownorm2<<<1024, 256, 0, stream>>>(Ct, cents, 1792);

  // ---- distance GEMM + top-200, chunked by batch image (S = 67 MB) ----
  for (int mc = 0; mc < 4; mc++) {
    gemm_dist<<<dim3(32, 32), 256, 0, stream>>>(Abf, Ct, feats, cents, S, mc * 4096);
    select_topk<<<4096, 256, 0, stream>>>(S, out_score, mc * 4096);
  }
}

// Round 4
// 900.880 us; speedup vs baseline: 1.2211x; 1.2103x over previous
//
#include <hip/hip_runtime.h>
#include <hip/hip_bf16.h>
#include <stdint.h>

typedef unsigned short u16;
typedef __attribute__((ext_vector_type(8))) short bf16x8;
typedef __attribute__((ext_vector_type(4))) float f32x4;

#define AS1 __attribute__((address_space(1)))
#define AS3 __attribute__((address_space(3)))

__device__ __forceinline__ u16 f2bf(float f) {
  uint32_t x = __float_as_uint(f);
  uint32_t r = (x + 0x7FFFu + ((x >> 16) & 1u)) >> 16;
  return (u16)r;
}
__device__ __forceinline__ float bf2f(u16 u) {
  return __uint_as_float(((uint32_t)u) << 16);
}

__device__ __forceinline__ void gload_lds16(const void* g, void* l) {
  __builtin_amdgcn_global_load_lds((const AS1 void*)g, (AS3 void*)l, 16, 0, 0);
}

// ---------------- 3x3 avg pool, stride 1, pad 1, /9 — 4 outputs/thread ----------------
template <int H, int W>
__global__ void pool3x3_v(const float* __restrict__ in, float* __restrict__ out) {
  constexpr int W4 = W / 4;
  int idx = blockIdx.x * 256 + threadIdx.x;  // over B*C*H*W/4
  int x0 = (idx % W4) * 4;
  int h = (idx / W4) % H;
  int p = idx / (W4 * H);  // b*C + c
  const float* pl = in + (size_t)p * H * W;
  float cs[6] = {0, 0, 0, 0, 0, 0};
  #pragma unroll
  for (int dy = -1; dy <= 1; dy++) {
    int yy = h + dy;
    if ((unsigned)yy < (unsigned)H) {
      const float* row = pl + yy * W;
      #pragma unroll
      for (int k = 0; k < 6; k++) {
        int xx = x0 - 1 + k;
        if ((unsigned)xx < (unsigned)W) cs[k] += row[xx];
      }
    }
  }
  f32x4 o;
  #pragma unroll
  for (int k = 0; k < 4; k++) o[k] = (cs[k] + cs[k + 1] + cs[k + 2]) * (1.0f / 9.0f);
  *(f32x4*)&out[(size_t)p * H * W + h * W + x0] = o;
}

// ---------------- CoordConv 1x1 ----------------
__global__ __launch_bounds__(256) void conv1x1_coord(
    const float* __restrict__ in,    // [B][K][HW]
    const float* __restrict__ w,     // [O][K+2]
    const float* __restrict__ bias,  // [O]
    float* __restrict__ out, int K, int O, int H, int W) {
  int HW = H * W;
  int b = blockIdx.z;
  int o0 = blockIdx.y * 64;
  int hw0 = blockIdx.x * 64;
  int tid = threadIdx.x;
  int tx = tid & 15;        // hw group
  int to = tid >> 4;        // o group
  __shared__ float in_t[16][64];
  __shared__ float w_t[16][64];
  float acc[4][4] = {};
  const float* inb = in + (size_t)b * K * HW;
  for (int c0 = 0; c0 < K; c0 += 16) {
    {
      int i = tid >> 4;
      int j = (tid & 15) * 4;
      *(f32x4*)&in_t[i][j] = *(const f32x4*)&inb[(size_t)(c0 + i) * HW + hw0 + j];
    }
    {
      int o = tid & 63;
      int ib = (tid >> 6) * 4;
      #pragma unroll
      for (int q = 0; q < 4; q++)
        w_t[ib + q][o] = w[(size_t)(o0 + o) * (K + 2) + c0 + ib + q];
    }
    __syncthreads();
    #pragma unroll
    for (int i = 0; i < 16; i++) {
      f32x4 wv = *(const f32x4*)&w_t[i][to * 4];
      f32x4 xv = *(const f32x4*)&in_t[i][tx * 4];
      #pragma unroll
      for (int oo = 0; oo < 4; oo++)
        #pragma unroll
        for (int xx = 0; xx < 4; xx++)
          acc[oo][xx] = fmaf(wv[oo], xv[xx], acc[oo][xx]);
    }
    __syncthreads();
  }
  float invW = 2.0f / (float)(W - 1);
  float invH = 2.0f / (float)(H - 1);
  int hwb = hw0 + tx * 4;
  int y = hwb / W;
  int xb = hwb % W;
  float yg = -1.0f + y * invH;
  #pragma unroll
  for (int oo = 0; oo < 4; oo++) {
    int o = o0 + to * 4 + oo;
    float wx = w[(size_t)o * (K + 2) + K];
    float wy = w[(size_t)o * (K + 2) + K + 1];
    float bb = bias[o];
    #pragma unroll
    for (int xx = 0; xx < 4; xx++) {
      float xg = -1.0f + (xb + xx) * invW;
      out[((size_t)b * O + o) * HW + hwb + xx] =
          acc[oo][xx] + wx * xg + wy * yg + bb;
    }
  }
}

// bilinear helpers (half-pixel, edge clamp)
template <int Hin>
__device__ __forceinline__ void bilin_coords(int v, int& i0, int& i1, float& wgt) {
  constexpr float scale = (float)Hin / 64.0f;
  float f = ((float)v + 0.5f) * scale - 0.5f;
  float f0 = floorf(f);
  wgt = f - f0;
  int i = (int)f0;
  i1 = min(i + 1, Hin - 1);
  i0 = max(i, 0);
}

// ---------------- emit out_phi (fp32, hw fastest) — 4 px/thread ----------------
template <int C, int Cin, int Hin>
__global__ void emit_phi_v(const float* __restrict__ in, float* __restrict__ outp,
                           int ch_off) {
  int idx = blockIdx.x * 256 + threadIdx.x;  // over B*C*1024
  int x0 = (idx & 15) * 4;
  int y = (idx >> 4) & 63;
  int c = (idx >> 10) % C;
  int b = idx / (C * 1024);
  const float* pl = in + (size_t)(b * Cin + c) * (Hin * Hin);
  int y0, y1; float wy;
  bilin_coords<Hin>(y, y0, y1, wy);
  const float* r0 = pl + y0 * Hin;
  const float* r1 = pl + y1 * Hin;
  f32x4 o;
  #pragma unroll
  for (int k = 0; k < 4; k++) {
    int xx0, xx1; float wx;
    bilin_coords<Hin>(x0 + k, xx0, xx1, wx);
    float top = (1.0f - wx) * r0[xx0] + wx * r0[xx1];
    float bot = (1.0f - wx) * r1[xx0] + wx * r1[xx1];
    o[k] = (1.0f - wy) * top + wy * bot;
  }
  *(f32x4*)&outp[((size_t)b * 896 + ch_off + c) * 4096 + (y << 6) + x0] = o;
}

// ---------------- level-1 out_phi: identity resize = plain copy ----------------
__global__ void copy_phi1(const float* __restrict__ in, float* __restrict__ outp) {
  int idx = blockIdx.x * 256 + threadIdx.x;  // over 4*256*1024 f32x4 units
  int x4 = (idx & 1023) * 4;
  int c = (idx >> 10) & 255;
  int b = idx >> 18;
  f32x4 v = *(const f32x4*)&in[((size_t)(b * 256 + c) << 12) + x4];
  *(f32x4*)&outp[((size_t)(b * 896 + c) << 12) + x4] = v;
}

// ---------------- fp32 [R][Cc] -> bf16 [c][r] transpose (strided out) ----------------
__global__ __launch_bounds__(256) void trans_f32_bf16(
    const float* __restrict__ in, u16* __restrict__ outT, int R, int Cc, int OS,
    size_t in_bstride, size_t out_bstride) {
  int b = blockIdx.z;
  in += (size_t)b * in_bstride;
  outT += (size_t)b * out_bstride;
  int r0 = blockIdx.y * 32, c0 = blockIdx.x * 32;
  __shared__ float t[32][33];
  int tid = threadIdx.x;
  int cl = tid & 31, rl = tid >> 5;  // rl 0..7
  #pragma unroll
  for (int q = 0; q < 4; q++)
    t[rl + q * 8][cl] = in[(size_t)(r0 + rl + q * 8) * Cc + c0 + cl];
  __syncthreads();
  #pragma unroll
  for (int q = 0; q < 4; q++) {
    int c = c0 + rl + q * 8;
    outT[(size_t)c * OS + r0 + cl] = f2bf(t[cl][rl + q * 8]);
  }
}

// ---------------- gather A from transposed OT[b][p][C] (bf16), 8 ch/thread ----------------
template <int C, int Hin, int L>  // L = log2(C/8)
__global__ void gather_A(const u16* __restrict__ OT, u16* __restrict__ A,
                         int ch_off) {
  int idx = blockIdx.x * 256 + threadIdx.x;  // over B*4096*(C/8)
  int co = (idx & ((C / 8) - 1)) * 8;
  int hw = (idx >> L) & 4095;
  int b = idx >> (L + 12);
  int x = hw & 63, y = hw >> 6;
  int y0, y1, x0, x1; float wy, wx;
  bilin_coords<Hin>(y, y0, y1, wy);
  bilin_coords<Hin>(x, x0, x1, wx);
  float w00 = (1.0f - wy) * (1.0f - wx), w01 = (1.0f - wy) * wx;
  float w10 = wy * (1.0f - wx), w11 = wy * wx;
  const u16* base = OT + (size_t)b * (Hin * Hin) * C + co;
  bf16x8 t00 = *(const bf16x8*)&base[(y0 * Hin + x0) * C];
  bf16x8 t01 = *(const bf16x8*)&base[(y0 * Hin + x1) * C];
  bf16x8 t10 = *(const bf16x8*)&base[(y1 * Hin + x0) * C];
  bf16x8 t11 = *(const bf16x8*)&base[(y1 * Hin + x1) * C];
  bf16x8 o;
  #pragma unroll
  for (int e = 0; e < 8; e++) {
    float v = w00 * bf2f((u16)t00[e]) + w01 * bf2f((u16)t01[e]) +
              w10 * bf2f((u16)t10[e]) + w11 * bf2f((u16)t11[e]);
    o[e] = (short)f2bf(v);
  }
  *(bf16x8*)&A[((size_t)b * 4096 + hw) * 1792 + ch_off + co] = o;
}

// ---------------- row sum of squares over bf16 rows ----------------
__global__ __launch_bounds__(256) void rownorm2(const u16* __restrict__ X,
                                                float* __restrict__ out, int ncols) {
  int row = blockIdx.x * 4 + (threadIdx.x >> 6);
  int lane = threadIdx.x & 63;
  const u16* xr = X + (size_t)row * ncols;
  int n8 = ncols >> 3;
  float s = 0.0f;
  for (int c8 = lane; c8 < n8; c8 += 64) {
    bf16x8 v = *(const bf16x8*)&xr[c8 * 8];
    #pragma unroll
    for (int e = 0; e < 8; e++) {
      float f = bf2f((u16)v[e]);
      s = fmaf(f, f, s);
    }
  }
  #pragma unroll
  for (int off = 32; off; off >>= 1) s += __shfl_down(s, off);
  if (lane == 0) out[row] = s;
}

// ---------------- bf16 GEMM: S[m][n] = feats[m] + cents[n] - 2 * A[m]·Bt[n] ----------------
__global__ __launch_bounds__(256) void gemm_dist(
    const u16* __restrict__ A,   // [16384][1792]
    const u16* __restrict__ Bt,  // [4096][1792]
    const float* __restrict__ feats, const float* __restrict__ cents,
    float* __restrict__ S, int m_base) {
  const int K = 1792, N = 4096;
  int m0 = blockIdx.y * 128, n0 = blockIdx.x * 128;
  int tid = threadIdx.x;
  int wid = tid >> 6, lane = tid & 63;
  int wm = wid >> 1, wn = wid & 1;
  __shared__ u16 As[128 * 64];
  __shared__ u16 Bs[128 * 64];
  f32x4 acc[4][4] = {};
  int lrow = tid >> 3;           // 0..31
  int lcol = (tid & 7) * 8;
  const u16* ga = A + (size_t)(m_base + m0 + lrow) * K + lcol;
  const u16* gb = Bt + (size_t)(n0 + lrow) * K + lcol;
  char* lbaseA = (char*)As + wid * 1024;
  char* lbaseB = (char*)Bs + wid * 1024;
  for (int k0 = 0; k0 < K; k0 += 64) {
    #pragma unroll
    for (int q = 0; q < 4; q++) {
      gload_lds16(ga + (size_t)q * 32 * K + k0, lbaseA + q * 4096);
      gload_lds16(gb + (size_t)q * 32 * K + k0, lbaseB + q * 4096);
    }
    __syncthreads();
    #pragma unroll
    for (int kk = 0; kk < 2; kk++) {
      bf16x8 af[4], bfr[4];
      int kb = kk * 32 + (lane >> 4) * 8;
      #pragma unroll
      for (int i = 0; i < 4; i++)
        af[i] = *(const bf16x8*)&As[(wm * 64 + i * 16 + (lane & 15)) * 64 + kb];
      #pragma unroll
      for (int j = 0; j < 4; j++)
        bfr[j] = *(const bf16x8*)&Bs[(wn * 64 + j * 16 + (lane & 15)) * 64 + kb];
      #pragma unroll
      for (int i = 0; i < 4; i++)
        #pragma unroll
        for (int j = 0; j < 4; j++)
          acc[i][j] = __builtin_amdgcn_mfma_f32_16x16x32_bf16(af[i], bfr[j], acc[i][j], 0, 0, 0);
    }
    __syncthreads();
  }
  int rq = lane >> 4;
  int cq = lane & 15;
  #pragma unroll
  for (int i = 0; i < 4; i++) {
    int lm = m0 + wm * 64 + i * 16 + rq * 4;  // row within chunk
    #pragma unroll
    for (int j = 0; j < 4; j++) {
      int gn = n0 + wn * 64 + j * 16 + cq;
      float cn = cents[gn];
      #pragma unroll
      for (int reg = 0; reg < 4; reg++) {
        int gm = m_base + lm + reg;
        S[(size_t)(lm + reg) * N + gn] = feats[gm] + cn - 2.0f * acc[i][j][reg];
      }
    }
  }
}

// ---------------- per-row top-200 smallest (sorted) of 4096, emit sqrt ----------------
__global__ __launch_bounds__(256) void select_topk(const float* __restrict__ S,
                                                   float* __restrict__ out,
                                                   int row_base) {
  int row_local = blockIdx.x;
  int tid = threadIdx.x;
  const float* Sr = S + (size_t)row_local * 4096;
  uint32_t ku[16];
  #pragma unroll
  for (int j = 0; j < 4; j++) {
    f32x4 v = *(const f32x4*)&Sr[(tid + 256 * j) * 4];
    #pragma unroll
    for (int e = 0; e < 4; e++) {
      uint32_t u = __float_as_uint(v[e]);
      u ^= (u & 0x80000000u) ? 0xFFFFFFFFu : 0x80000000u;  // order-preserving
      ku[j * 4 + e] = u;
    }
  }
  __shared__ uint32_t red[4];
  __shared__ uint32_t selv[256];
  __shared__ uint32_t cnt2[2];
  uint32_t lo = 0u, hi = 0xFFFFFFFFu;
  while (lo < hi) {
    uint32_t mid = lo + ((hi - lo) >> 1);
    int c = 0;
    #pragma unroll
    for (int j = 0; j < 16; j++) c += (ku[j] <= mid) ? 1 : 0;
    #pragma unroll
    for (int off = 32; off; off >>= 1) c += __shfl_down(c, off);
    if ((tid & 63) == 0) red[tid >> 6] = (uint32_t)c;
    __syncthreads();
    uint32_t total = red[0] + red[1] + red[2] + red[3];
    if (total >= 200u) hi = mid; else lo = mid + 1u;
    __syncthreads();
  }
  uint32_t T = lo;
  {
    int c = 0;
    #pragma unroll
    for (int j = 0; j < 16; j++) c += (ku[j] < T) ? 1 : 0;
    #pragma unroll
    for (int off = 32; off; off >>= 1) c += __shfl_down(c, off);
    if ((tid & 63) == 0) red[tid >> 6] = (uint32_t)c;
  }
  if (tid == 0) { cnt2[0] = 0; cnt2[1] = 0; }
  selv[tid] = 0xFFFFFFFFu;
  __syncthreads();
  uint32_t nless = red[0] + red[1] + red[2] + red[3];
  #pragma unroll
  for (int j = 0; j < 16; j++) {
    uint32_t u = ku[j];
    if (u < T) {
      uint32_t p = atomicAdd(&cnt2[0], 1u);
      selv[p] = u;
    } else if (u == T) {
      uint32_t p = atomicAdd(&cnt2[1], 1u);
      uint32_t d = nless + p;
      if (d < 200u) selv[d] = u;
    }
  }
  __syncthreads();
  for (int kk = 2; kk <= 256; kk <<= 1) {
    for (int jj = kk >> 1; jj > 0; jj >>= 1) {
      int ixj = tid ^ jj;
      if (ixj > tid) {
        uint32_t a = selv[tid], bb = selv[ixj];
        bool up = ((tid & kk) == 0);
        if ((a > bb) == up) { selv[tid] = bb; selv[ixj] = a; }
      }
      __syncthreads();
    }
  }
  if (tid < 200) {
    uint32_t u = selv[tid];
    u ^= (u & 0x80000000u) ? 0x80000000u : 0xFFFFFFFFu;
    float v = __uint_as_float(u);
    int grow = row_base + row_local;
    int b = grow >> 12, r = grow & 4095;
    out[((size_t)b * 200 + tid) * 4096 + r] = sqrtf(v);
  }
}

extern "C" void kernel_launch(void* const* d_in, const int* in_sizes, int n_in,
                              void* d_out, int out_size, void* d_ws, size_t ws_size,
                              hipStream_t stream) {
  const float* p0 = (const float*)d_in[0];   // (4,256,64,64)
  const float* p1 = (const float*)d_in[1];   // (4,512,32,32)
  const float* p2 = (const float*)d_in[2];   // (4,1024,16,16)
  const float* w1 = (const float*)d_in[5];   // (256,258)
  const float* b1 = (const float*)d_in[6];
  const float* w2 = (const float*)d_in[7];   // (512,514)
  const float* b2 = (const float*)d_in[8];
  const float* w3 = (const float*)d_in[9];   // (1024,1026)
  const float* b3 = (const float*)d_in[10];
  const float* Cm = (const float*)d_in[11];  // (1792,4096)

  float* out_score = (float*)d_out;                  // 4*200*4096 fp32
  float* out_phi = (float*)d_out + 3276800;          // 4*896*4096 fp32

  // workspace layout (peak ~140.6 MB)
  char* w = (char*)d_ws;
  u16* Abf = (u16*)w;                                //  58,720,256 B
  u16* Ct = (u16*)(w + 58720256);                    //  14,680,064 B
  float* feats = (float*)(w + 73400320);             //      65,536 B
  float* cents = (float*)(w + 73465856);             //      16,384 B
  float* S = (float*)(w + 73482240);                 //  67,108,864 B (per-chunk) -> ends 140,591,104
  // stage-A temps alias the S region (dead before first gemm)
  float* O1 = (float*)(w + 73482240);                //  16,777,216 B
  float* O2 = (float*)(w + 90259456);                //   8,388,608 B
  float* O3 = (float*)(w + 98648064);                //   4,194,304 B
  float* pooled1 = (float*)(w + 102842368);          //  16,777,216 B
  float* pooled2 = (float*)(w + 119619584);          //   8,388,608 B
  float* pooled3 = (float*)(w + 128008192);          //   4,194,304 B  -> ends 132,202,496
  u16* OT2 = (u16*)(w + 132202496);                  //   4,194,304 B  [4][1024][512]
  u16* OT3 = (u16*)(w + 136396800);                  //   2,097,152 B  [4][256][1024] -> ends 138,493,952

  // ---- stage A: pool (4 outputs/thread) ----
  pool3x3_v<64, 64><<<4096, 256, 0, stream>>>(p0, pooled1);
  pool3x3_v<32, 32><<<2048, 256, 0, stream>>>(p1, pooled2);
  pool3x3_v<16, 16><<<1024, 256, 0, stream>>>(p2, pooled3);

  // ---- stage A: coordconv 1x1 ----
  conv1x1_coord<<<dim3(64, 4, 4), 256, 0, stream>>>(pooled1, w1, b1, O1, 256, 256, 64, 64);
  conv1x1_coord<<<dim3(16, 8, 4), 256, 0, stream>>>(pooled2, w2, b2, O2, 512, 512, 32, 32);
  conv1x1_coord<<<dim3(4, 16, 4), 256, 0, stream>>>(pooled3, w3, b3, O3, 1024, 1024, 16, 16);

  // ---- output 1: PHI[:, :896] ----
  copy_phi1<<<4096, 256, 0, stream>>>(O1, out_phi);
  emit_phi_v<512, 512, 32><<<8192, 256, 0, stream>>>(O2, out_phi, 256);
  emit_phi_v<128, 1024, 16><<<2048, 256, 0, stream>>>(O3, out_phi, 768);

  // ---- A matrix: transpose-first, then coalesced gather ----
  // level 1: identity resize -> transpose straight into A cols [0,256)
  trans_f32_bf16<<<dim3(128, 8, 4), 256, 0, stream>>>(
      O1, Abf, 256, 4096, 1792, (size_t)256 * 4096, (size_t)4096 * 1792);
  // levels 2,3: O[b][C][p] -> OT[b][p][C] bf16
  trans_f32_bf16<<<dim3(32, 16, 4), 256, 0, stream>>>(
      O2, OT2, 512, 1024, 512, (size_t)512 * 1024, (size_t)1024 * 512);
  trans_f32_bf16<<<dim3(8, 32, 4), 256, 0, stream>>>(
      O3, OT3, 1024, 256, 1024, (size_t)1024 * 256, (size_t)256 * 1024);
  gather_A<512, 32, 6><<<4096, 256, 0, stream>>>(OT2, Abf, 256);
  gather_A<1024, 16, 7><<<8192, 256, 0, stream>>>(OT3, Abf, 768);

  // ---- C transpose + bf16 ----
  trans_f32_bf16<<<dim3(128, 56, 1), 256, 0, stream>>>(Cm, Ct, 1792, 4096, 1792, 0, 0);

  // ---- norms ----
  rownorm2<<<4096, 256, 0, stream>>>(Abf, feats, 1792);
  rownorm2<<<1024, 256, 0, stream>>>(Ct, cents, 1792);

  // ---- distance GEMM + top-200, chunked by batch image (S = 67 MB) ----
  for (int mc = 0; mc < 4; mc++) {
    gemm_dist<<<dim3(32, 32), 256, 0, stream>>>(Abf, Ct, feats, cents, S, mc * 4096);
    select_topk<<<4096, 256, 0, stream>>>(S, out_score, mc * 4096);
  }
}

// Round 5
// 765.746 us; speedup vs baseline: 1.4366x; 1.1765x over previous
//
#include <hip/hip_runtime.h>
#include <hip/hip_bf16.h>
#include <stdint.h>

typedef unsigned short u16;
typedef __attribute__((ext_vector_type(8))) short bf16x8;
typedef __attribute__((ext_vector_type(4))) float f32x4;

#define AS1 __attribute__((address_space(1)))
#define AS3 __attribute__((address_space(3)))

__device__ __forceinline__ u16 f2bf(float f) {
  uint32_t x = __float_as_uint(f);
  uint32_t r = (x + 0x7FFFu + ((x >> 16) & 1u)) >> 16;
  return (u16)r;
}
__device__ __forceinline__ float bf2f(u16 u) {
  return __uint_as_float(((uint32_t)u) << 16);
}

__device__ __forceinline__ void gload_lds16(const void* g, void* l) {
  __builtin_amdgcn_global_load_lds((const AS1 void*)g, (AS3 void*)l, 16, 0, 0);
}

// ---------------- 3x3 avg pool, stride 1, pad 1, /9 — 4 outputs/thread ----------------
template <int H, int W>
__global__ void pool3x3_v(const float* __restrict__ in, float* __restrict__ out) {
  constexpr int W4 = W / 4;
  int idx = blockIdx.x * 256 + threadIdx.x;  // over B*C*H*W/4
  int x0 = (idx % W4) * 4;
  int h = (idx / W4) % H;
  int p = idx / (W4 * H);  // b*C + c
  const float* pl = in + (size_t)p * H * W;
  float cs[6] = {0, 0, 0, 0, 0, 0};
  #pragma unroll
  for (int dy = -1; dy <= 1; dy++) {
    int yy = h + dy;
    if ((unsigned)yy < (unsigned)H) {
      const float* row = pl + yy * W;
      #pragma unroll
      for (int k = 0; k < 6; k++) {
        int xx = x0 - 1 + k;
        if ((unsigned)xx < (unsigned)W) cs[k] += row[xx];
      }
    }
  }
  f32x4 o;
  #pragma unroll
  for (int k = 0; k < 4; k++) o[k] = (cs[k] + cs[k + 1] + cs[k + 2]) * (1.0f / 9.0f);
  *(f32x4*)&out[(size_t)p * H * W + h * W + x0] = o;
}

// ---------------- CoordConv 1x1 ----------------
__global__ __launch_bounds__(256) void conv1x1_coord(
    const float* __restrict__ in,    // [B][K][HW]
    const float* __restrict__ w,     // [O][K+2]
    const float* __restrict__ bias,  // [O]
    float* __restrict__ out, int K, int O, int H, int W) {
  int HW = H * W;
  int b = blockIdx.z;
  int o0 = blockIdx.y * 64;
  int hw0 = blockIdx.x * 64;
  int tid = threadIdx.x;
  int tx = tid & 15;        // hw group
  int to = tid >> 4;        // o group
  __shared__ float in_t[16][64];
  __shared__ float w_t[16][64];
  float acc[4][4] = {};
  const float* inb = in + (size_t)b * K * HW;
  for (int c0 = 0; c0 < K; c0 += 16) {
    {
      int i = tid >> 4;
      int j = (tid & 15) * 4;
      *(f32x4*)&in_t[i][j] = *(const f32x4*)&inb[(size_t)(c0 + i) * HW + hw0 + j];
    }
    {
      int o = tid & 63;
      int ib = (tid >> 6) * 4;
      #pragma unroll
      for (int q = 0; q < 4; q++)
        w_t[ib + q][o] = w[(size_t)(o0 + o) * (K + 2) + c0 + ib + q];
    }
    __syncthreads();
    #pragma unroll
    for (int i = 0; i < 16; i++) {
      f32x4 wv = *(const f32x4*)&w_t[i][to * 4];
      f32x4 xv = *(const f32x4*)&in_t[i][tx * 4];
      #pragma unroll
      for (int oo = 0; oo < 4; oo++)
        #pragma unroll
        for (int xx = 0; xx < 4; xx++)
          acc[oo][xx] = fmaf(wv[oo], xv[xx], acc[oo][xx]);
    }
    __syncthreads();
  }
  float invW = 2.0f / (float)(W - 1);
  float invH = 2.0f / (float)(H - 1);
  int hwb = hw0 + tx * 4;
  int y = hwb / W;
  int xb = hwb % W;
  float yg = -1.0f + y * invH;
  #pragma unroll
  for (int oo = 0; oo < 4; oo++) {
    int o = o0 + to * 4 + oo;
    float wx = w[(size_t)o * (K + 2) + K];
    float wy = w[(size_t)o * (K + 2) + K + 1];
    float bb = bias[o];
    #pragma unroll
    for (int xx = 0; xx < 4; xx++) {
      float xg = -1.0f + (xb + xx) * invW;
      out[((size_t)b * O + o) * HW + hwb + xx] =
          acc[oo][xx] + wx * xg + wy * yg + bb;
    }
  }
}

// bilinear helpers (half-pixel, edge clamp)
template <int Hin>
__device__ __forceinline__ void bilin_coords(int v, int& i0, int& i1, float& wgt) {
  constexpr float scale = (float)Hin / 64.0f;
  float f = ((float)v + 0.5f) * scale - 0.5f;
  float f0 = floorf(f);
  wgt = f - f0;
  int i = (int)f0;
  i1 = min(i + 1, Hin - 1);
  i0 = max(i, 0);
}

// ---------------- emit out_phi (fp32, hw fastest) — 4 px/thread ----------------
template <int C, int Cin, int Hin>
__global__ void emit_phi_v(const float* __restrict__ in, float* __restrict__ outp,
                           int ch_off) {
  int idx = blockIdx.x * 256 + threadIdx.x;  // over B*C*1024
  int x0 = (idx & 15) * 4;
  int y = (idx >> 4) & 63;
  int c = (idx >> 10) % C;
  int b = idx / (C * 1024);
  const float* pl = in + (size_t)(b * Cin + c) * (Hin * Hin);
  int y0, y1; float wy;
  bilin_coords<Hin>(y, y0, y1, wy);
  const float* r0 = pl + y0 * Hin;
  const float* r1 = pl + y1 * Hin;
  f32x4 o;
  #pragma unroll
  for (int k = 0; k < 4; k++) {
    int xx0, xx1; float wx;
    bilin_coords<Hin>(x0 + k, xx0, xx1, wx);
    float top = (1.0f - wx) * r0[xx0] + wx * r0[xx1];
    float bot = (1.0f - wx) * r1[xx0] + wx * r1[xx1];
    o[k] = (1.0f - wy) * top + wy * bot;
  }
  *(f32x4*)&outp[((size_t)b * 896 + ch_off + c) * 4096 + (y << 6) + x0] = o;
}

// ---------------- level-1 out_phi: identity resize = plain copy ----------------
__global__ void copy_phi1(const float* __restrict__ in, float* __restrict__ outp) {
  int idx = blockIdx.x * 256 + threadIdx.x;  // over 4*256*1024 f32x4 units
  int x4 = (idx & 1023) * 4;
  int c = (idx >> 10) & 255;
  int b = idx >> 18;
  f32x4 v = *(const f32x4*)&in[((size_t)(b * 256 + c) << 12) + x4];
  *(f32x4*)&outp[((size_t)(b * 896 + c) << 12) + x4] = v;
}

// ---------------- fp32 [R][Cc] -> bf16 [c][r] transpose (strided out) ----------------
__global__ __launch_bounds__(256) void trans_f32_bf16(
    const float* __restrict__ in, u16* __restrict__ outT, int R, int Cc, int OS,
    size_t in_bstride, size_t out_bstride) {
  int b = blockIdx.z;
  in += (size_t)b * in_bstride;
  outT += (size_t)b * out_bstride;
  int r0 = blockIdx.y * 32, c0 = blockIdx.x * 32;
  __shared__ float t[32][33];
  int tid = threadIdx.x;
  int cl = tid & 31, rl = tid >> 5;  // rl 0..7
  #pragma unroll
  for (int q = 0; q < 4; q++)
    t[rl + q * 8][cl] = in[(size_t)(r0 + rl + q * 8) * Cc + c0 + cl];
  __syncthreads();
  #pragma unroll
  for (int q = 0; q < 4; q++) {
    int c = c0 + rl + q * 8;
    outT[(size_t)c * OS + r0 + cl] = f2bf(t[cl][rl + q * 8]);
  }
}

// ---------------- gather A from transposed OT[b][p][C] (bf16), 8 ch/thread ----------------
template <int C, int Hin, int L>  // L = log2(C/8)
__global__ void gather_A(const u16* __restrict__ OT, u16* __restrict__ A,
                         int ch_off) {
  int idx = blockIdx.x * 256 + threadIdx.x;  // over B*4096*(C/8)
  int co = (idx & ((C / 8) - 1)) * 8;
  int hw = (idx >> L) & 4095;
  int b = idx >> (L + 12);
  int x = hw & 63, y = hw >> 6;
  int y0, y1, x0, x1; float wy, wx;
  bilin_coords<Hin>(y, y0, y1, wy);
  bilin_coords<Hin>(x, x0, x1, wx);
  float w00 = (1.0f - wy) * (1.0f - wx), w01 = (1.0f - wy) * wx;
  float w10 = wy * (1.0f - wx), w11 = wy * wx;
  const u16* base = OT + (size_t)b * (Hin * Hin) * C + co;
  bf16x8 t00 = *(const bf16x8*)&base[(y0 * Hin + x0) * C];
  bf16x8 t01 = *(const bf16x8*)&base[(y0 * Hin + x1) * C];
  bf16x8 t10 = *(const bf16x8*)&base[(y1 * Hin + x0) * C];
  bf16x8 t11 = *(const bf16x8*)&base[(y1 * Hin + x1) * C];
  bf16x8 o;
  #pragma unroll
  for (int e = 0; e < 8; e++) {
    float v = w00 * bf2f((u16)t00[e]) + w01 * bf2f((u16)t01[e]) +
              w10 * bf2f((u16)t10[e]) + w11 * bf2f((u16)t11[e]);
    o[e] = (short)f2bf(v);
  }
  *(bf16x8*)&A[((size_t)b * 4096 + hw) * 1792 + ch_off + co] = o;
}

// ---------------- row sum of squares over bf16 rows ----------------
__global__ __launch_bounds__(256) void rownorm2(const u16* __restrict__ X,
                                                float* __restrict__ out, int ncols) {
  int row = blockIdx.x * 4 + (threadIdx.x >> 6);
  int lane = threadIdx.x & 63;
  const u16* xr = X + (size_t)row * ncols;
  int n8 = ncols >> 3;
  float s = 0.0f;
  for (int c8 = lane; c8 < n8; c8 += 64) {
    bf16x8 v = *(const bf16x8*)&xr[c8 * 8];
    #pragma unroll
    for (int e = 0; e < 8; e++) {
      float f = bf2f((u16)v[e]);
      s = fmaf(f, f, s);
    }
  }
  #pragma unroll
  for (int off = 32; off; off >>= 1) s += __shfl_down(s, off);
  if (lane == 0) out[row] = s;
}

// ======== 256x256-tile deep-pipelined distance GEMM ========
// BM=BN=256, BK=32, 512 thr (2x4 waves of 128x64), 4-deep LDS ring (128 KiB),
// stage tile t+3 during tile t, boundary s_waitcnt vmcnt(8) (never 0),
// 16B-slot XOR swizzle (slot ^= row&3) applied on global-src AND ds_read.
#define GD_NT 56  // K/32

__device__ __forceinline__ void stage16k(const u16* __restrict__ G, int row0,
                                         int k0, char* lds_wavebase, int lane) {
  const int K = 1792;
  int sub = lane >> 2;                       // row within 16-row group
  int colsw = 8 * ((lane & 3) ^ (sub & 3));  // pre-swizzled source column
  #pragma unroll
  for (int q = 0; q < 2; q++) {
    gload_lds16(G + (size_t)(row0 + q * 128 + sub) * K + k0 + colsw,
                lds_wavebase + q * 8192);
  }
}

__global__ __launch_bounds__(512, 2) void gemm_dist2(
    const u16* __restrict__ A,   // [16384][1792]
    const u16* __restrict__ Bt,  // [4096][1792]
    const float* __restrict__ feats, const float* __restrict__ cents,
    float* __restrict__ S, int m_base) {
  const int K = 1792, N = 4096;
  extern __shared__ u16 lds[];  // 4 bufs x (A 8192 + B 8192) elems = 128 KiB
  // XCD-aware swizzle (grid 256, 256%8==0 -> simple form is bijective)
  int bid = blockIdx.x;
  int swz = (bid & 7) * 32 + (bid >> 3);
  int m0 = (swz >> 4) * 256;
  int n0 = (swz & 15) * 256;
  int tid = threadIdx.x;
  int wid = tid >> 6, lane = tid & 63;
  int wr = wid >> 2, wc = wid & 3;  // wave -> 128x64 output sub-tile
  int ln15 = lane & 15;
  int fo = 8 * ((lane >> 4) ^ (lane & 3));  // swizzled frag column offset

  f32x4 acc[8][4] = {};

  // prologue: stage tiles 0,1,2 (12 loads/wave outstanding)
  #pragma unroll
  for (int t = 0; t < 3; t++) {
    char* bufb = (char*)lds + (t & 3) * 32768 + wid * 1024;
    stage16k(A, m_base + m0 + wid * 16, t * 32, bufb, lane);
    stage16k(Bt, n0 + wid * 16, t * 32, bufb + 16384, lane);
  }

  #pragma unroll 1
  for (int t = 0; t < GD_NT; t++) {
    // ---- tile boundary: tile t landed iff newest <=8 loads (tiles t+1,t+2) remain
    asm volatile("s_waitcnt vmcnt(8)" ::: "memory");
    __builtin_amdgcn_s_barrier();
    __builtin_amdgcn_sched_barrier(0);
    const u16* Ab = lds + (t & 3) * 16384;
    const u16* Bb = Ab + 8192;
    char* nbuf = (char*)lds + ((t + 3) & 3) * 32768 + wid * 1024;

    // ---- phase 0: stage A(t+3) | read B-frags + A-frags(0..3) | 16 MFMA
    if (t + 3 < GD_NT) stage16k(A, m_base + m0 + wid * 16, (t + 3) * 32, nbuf, lane);
    bf16x8 bq[4];
    #pragma unroll
    for (int ni = 0; ni < 4; ni++)
      bq[ni] = *(const bf16x8*)&Bb[(wc * 64 + ni * 16 + ln15) * 32 + fo];
    {
      bf16x8 af[4];
      #pragma unroll
      for (int mi = 0; mi < 4; mi++)
        af[mi] = *(const bf16x8*)&Ab[(wr * 128 + mi * 16 + ln15) * 32 + fo];
      __builtin_amdgcn_s_setprio(1);
      #pragma unroll
      for (int mi = 0; mi < 4; mi++)
        #pragma unroll
        for (int ni = 0; ni < 4; ni++)
          acc[mi][ni] = __builtin_amdgcn_mfma_f32_16x16x32_bf16(af[mi], bq[ni], acc[mi][ni], 0, 0, 0);
      __builtin_amdgcn_s_setprio(0);
    }
    __builtin_amdgcn_s_barrier();

    // ---- phase 1: stage B(t+3) | read A-frags(4..7) | 16 MFMA
    if (t + 3 < GD_NT) stage16k(Bt, n0 + wid * 16, (t + 3) * 32, nbuf + 16384, lane);
    {
      bf16x8 af[4];
      #pragma unroll
      for (int mi = 0; mi < 4; mi++)
        af[mi] = *(const bf16x8*)&Ab[(wr * 128 + (mi + 4) * 16 + ln15) * 32 + fo];
      __builtin_amdgcn_s_setprio(1);
      #pragma unroll
      for (int mi = 0; mi < 4; mi++)
        #pragma unroll
        for (int ni = 0; ni < 4; ni++)
          acc[mi + 4][ni] = __builtin_amdgcn_mfma_f32_16x16x32_bf16(af[mi], bq[ni], acc[mi + 4][ni], 0, 0, 0);
      __builtin_amdgcn_s_setprio(0);
    }
  }

  // ---- epilogue: S = feats + cents - 2*dot
  int rq = lane >> 4, cq = lane & 15;
  #pragma unroll
  for (int mi = 0; mi < 8; mi++) {
    int lm = m0 + wr * 128 + mi * 16 + rq * 4;
    #pragma unroll
    for (int ni = 0; ni < 4; ni++) {
      int gn = n0 + wc * 64 + ni * 16 + cq;
      float cn = cents[gn];
      #pragma unroll
      for (int r = 0; r < 4; r++)
        S[(size_t)(lm + r) * N + gn] = feats[m_base + lm + r] + cn - 2.0f * acc[mi][ni][r];
    }
  }
}

// ---------------- per-row top-200 smallest (sorted) of 4096, emit sqrt ----------------
__global__ __launch_bounds__(256) void select_topk(const float* __restrict__ S,
                                                   float* __restrict__ out,
                                                   int row_base) {
  int row_local = blockIdx.x;
  int tid = threadIdx.x;
  const float* Sr = S + (size_t)row_local * 4096;
  uint32_t ku[16];
  #pragma unroll
  for (int j = 0; j < 4; j++) {
    f32x4 v = *(const f32x4*)&Sr[(tid + 256 * j) * 4];
    #pragma unroll
    for (int e = 0; e < 4; e++) {
      uint32_t u = __float_as_uint(v[e]);
      u ^= (u & 0x80000000u) ? 0xFFFFFFFFu : 0x80000000u;  // order-preserving
      ku[j * 4 + e] = u;
    }
  }
  __shared__ uint32_t red[4];
  __shared__ uint32_t selv[256];
  __shared__ uint32_t cnt2[2];
  uint32_t lo = 0u, hi = 0xFFFFFFFFu;
  while (lo < hi) {
    uint32_t mid = lo + ((hi - lo) >> 1);
    int c = 0;
    #pragma unroll
    for (int j = 0; j < 16; j++) c += (ku[j] <= mid) ? 1 : 0;
    #pragma unroll
    for (int off = 32; off; off >>= 1) c += __shfl_down(c, off);
    if ((tid & 63) == 0) red[tid >> 6] = (uint32_t)c;
    __syncthreads();
    uint32_t total = red[0] + red[1] + red[2] + red[3];
    if (total >= 200u) hi = mid; else lo = mid + 1u;
    __syncthreads();
  }
  uint32_t T = lo;
  {
    int c = 0;
    #pragma unroll
    for (int j = 0; j < 16; j++) c += (ku[j] < T) ? 1 : 0;
    #pragma unroll
    for (int off = 32; off; off >>= 1) c += __shfl_down(c, off);
    if ((tid & 63) == 0) red[tid >> 6] = (uint32_t)c;
  }
  if (tid == 0) { cnt2[0] = 0; cnt2[1] = 0; }
  selv[tid] = 0xFFFFFFFFu;
  __syncthreads();
  uint32_t nless = red[0] + red[1] + red[2] + red[3];
  #pragma unroll
  for (int j = 0; j < 16; j++) {
    uint32_t u = ku[j];
    if (u < T) {
      uint32_t p = atomicAdd(&cnt2[0], 1u);
      selv[p] = u;
    } else if (u == T) {
      uint32_t p = atomicAdd(&cnt2[1], 1u);
      uint32_t d = nless + p;
      if (d < 200u) selv[d] = u;
    }
  }
  __syncthreads();
  for (int kk = 2; kk <= 256; kk <<= 1) {
    for (int jj = kk >> 1; jj > 0; jj >>= 1) {
      int ixj = tid ^ jj;
      if (ixj > tid) {
        uint32_t a = selv[tid], bb = selv[ixj];
        bool up = ((tid & kk) == 0);
        if ((a > bb) == up) { selv[tid] = bb; selv[ixj] = a; }
      }
      __syncthreads();
    }
  }
  if (tid < 200) {
    uint32_t u = selv[tid];
    u ^= (u & 0x80000000u) ? 0x80000000u : 0xFFFFFFFFu;
    float v = __uint_as_float(u);
    int grow = row_base + row_local;
    int b = grow >> 12, r = grow & 4095;
    out[((size_t)b * 200 + tid) * 4096 + r] = sqrtf(v);
  }
}

extern "C" void kernel_launch(void* const* d_in, const int* in_sizes, int n_in,
                              void* d_out, int out_size, void* d_ws, size_t ws_size,
                              hipStream_t stream) {
  const float* p0 = (const float*)d_in[0];   // (4,256,64,64)
  const float* p1 = (const float*)d_in[1];   // (4,512,32,32)
  const float* p2 = (const float*)d_in[2];   // (4,1024,16,16)
  const float* w1 = (const float*)d_in[5];   // (256,258)
  const float* b1 = (const float*)d_in[6];
  const float* w2 = (const float*)d_in[7];   // (512,514)
  const float* b2 = (const float*)d_in[8];
  const float* w3 = (const float*)d_in[9];   // (1024,1026)
  const float* b3 = (const float*)d_in[10];
  const float* Cm = (const float*)d_in[11];  // (1792,4096)

  float* out_score = (float*)d_out;                  // 4*200*4096 fp32
  float* out_phi = (float*)d_out + 3276800;          // 4*896*4096 fp32

  // workspace layout (peak ~140.6 MB)
  char* w = (char*)d_ws;
  u16* Abf = (u16*)w;                                //  58,720,256 B
  u16* Ct = (u16*)(w + 58720256);                    //  14,680,064 B
  float* feats = (float*)(w + 73400320);             //      65,536 B
  float* cents = (float*)(w + 73465856);             //      16,384 B
  float* S = (float*)(w + 73482240);                 //  67,108,864 B (per-chunk) -> ends 140,591,104
  // stage-A temps alias the S region (dead before first gemm)
  float* O1 = (float*)(w + 73482240);                //  16,777,216 B
  float* O2 = (float*)(w + 90259456);                //   8,388,608 B
  float* O3 = (float*)(w + 98648064);                //   4,194,304 B
  float* pooled1 = (float*)(w + 102842368);          //  16,777,216 B
  float* pooled2 = (float*)(w + 119619584);          //   8,388,608 B
  float* pooled3 = (float*)(w + 128008192);          //   4,194,304 B  -> ends 132,202,496
  u16* OT2 = (u16*)(w + 132202496);                  //   4,194,304 B  [4][1024][512]
  u16* OT3 = (u16*)(w + 136396800);                  //   2,097,152 B  [4][256][1024] -> ends 138,493,952

  // ---- stage A: pool (4 outputs/thread) ----
  pool3x3_v<64, 64><<<4096, 256, 0, stream>>>(p0, pooled1);
  pool3x3_v<32, 32><<<2048, 256, 0, stream>>>(p1, pooled2);
  pool3x3_v<16, 16><<<1024, 256, 0, stream>>>(p2, pooled3);

  // ---- stage A: coordconv 1x1 ----
  conv1x1_coord<<<dim3(64, 4, 4), 256, 0, stream>>>(pooled1, w1, b1, O1, 256, 256, 64, 64);
  conv1x1_coord<<<dim3(16, 8, 4), 256, 0, stream>>>(pooled2, w2, b2, O2, 512, 512, 32, 32);
  conv1x1_coord<<<dim3(4, 16, 4), 256, 0, stream>>>(pooled3, w3, b3, O3, 1024, 1024, 16, 16);

  // ---- output 1: PHI[:, :896] ----
  copy_phi1<<<4096, 256, 0, stream>>>(O1, out_phi);
  emit_phi_v<512, 512, 32><<<8192, 256, 0, stream>>>(O2, out_phi, 256);
  emit_phi_v<128, 1024, 16><<<2048, 256, 0, stream>>>(O3, out_phi, 768);

  // ---- A matrix: transpose-first, then coalesced gather ----
  trans_f32_bf16<<<dim3(128, 8, 4), 256, 0, stream>>>(
      O1, Abf, 256, 4096, 1792, (size_t)256 * 4096, (size_t)4096 * 1792);
  trans_f32_bf16<<<dim3(32, 16, 4), 256, 0, stream>>>(
      O2, OT2, 512, 1024, 512, (size_t)512 * 1024, (size_t)1024 * 512);
  trans_f32_bf16<<<dim3(8, 32, 4), 256, 0, stream>>>(
      O3, OT3, 1024, 256, 1024, (size_t)1024 * 256, (size_t)256 * 1024);
  gather_A<512, 32, 6><<<4096, 256, 0, stream>>>(OT2, Abf, 256);
  gather_A<1024, 16, 7><<<8192, 256, 0, stream>>>(OT3, Abf, 768);

  // ---- C transpose + bf16 ----
  trans_f32_bf16<<<dim3(128, 56, 1), 256, 0, stream>>>(Cm, Ct, 1792, 4096, 1792, 0, 0);

  // ---- norms ----
  rownorm2<<<4096, 256, 0, stream>>>(Abf, feats, 1792);
  rownorm2<<<1024, 256, 0, stream>>>(Ct, cents, 1792);

  // ---- distance GEMM (256^2 deep-pipelined) + top-200, chunked by batch image ----
  for (int mc = 0; mc < 4; mc++) {
    gemm_dist2<<<256, 512, 131072, stream>>>(Abf, Ct, feats, cents, S, mc * 4096);
    select_topk<<<4096, 256, 0, stream>>>(S, out_score, mc * 4096);
  }
}

// Round 6
// 687.768 us; speedup vs baseline: 1.5995x; 1.1134x over previous
//
#include <hip/hip_runtime.h>
#include <hip/hip_bf16.h>
#include <stdint.h>

typedef unsigned short u16;
typedef __attribute__((ext_vector_type(8))) short bf16x8;
typedef __attribute__((ext_vector_type(4))) float f32x4;

#define AS1 __attribute__((address_space(1)))
#define AS3 __attribute__((address_space(3)))

__device__ __forceinline__ u16 f2bf(float f) {
  uint32_t x = __float_as_uint(f);
  uint32_t r = (x + 0x7FFFu + ((x >> 16) & 1u)) >> 16;
  return (u16)r;
}
__device__ __forceinline__ float bf2f(u16 u) {
  return __uint_as_float(((uint32_t)u) << 16);
}

__device__ __forceinline__ void gload_lds16(const void* g, void* l) {
  __builtin_amdgcn_global_load_lds((const AS1 void*)g, (AS3 void*)l, 16, 0, 0);
}

// ---------------- 3x3 avg pool, stride 1, pad 1, /9 — 4 outputs/thread ----------------
template <int H, int W>
__global__ void pool3x3_v(const float* __restrict__ in, float* __restrict__ out) {
  constexpr int W4 = W / 4;
  int idx = blockIdx.x * 256 + threadIdx.x;  // over B*C*H*W/4
  int x0 = (idx % W4) * 4;
  int h = (idx / W4) % H;
  int p = idx / (W4 * H);  // b*C + c
  const float* pl = in + (size_t)p * H * W;
  float cs[6] = {0, 0, 0, 0, 0, 0};
  #pragma unroll
  for (int dy = -1; dy <= 1; dy++) {
    int yy = h + dy;
    if ((unsigned)yy < (unsigned)H) {
      const float* row = pl + yy * W;
      #pragma unroll
      for (int k = 0; k < 6; k++) {
        int xx = x0 - 1 + k;
        if ((unsigned)xx < (unsigned)W) cs[k] += row[xx];
      }
    }
  }
  f32x4 o;
  #pragma unroll
  for (int k = 0; k < 4; k++) o[k] = (cs[k] + cs[k + 1] + cs[k + 2]) * (1.0f / 9.0f);
  *(f32x4*)&out[(size_t)p * H * W + h * W + x0] = o;
}

// ---------------- CoordConv 1x1 ----------------
__global__ __launch_bounds__(256) void conv1x1_coord(
    const float* __restrict__ in,    // [B][K][HW]
    const float* __restrict__ w,     // [O][K+2]
    const float* __restrict__ bias,  // [O]
    float* __restrict__ out, int K, int O, int H, int W) {
  int HW = H * W;
  int b = blockIdx.z;
  int o0 = blockIdx.y * 64;
  int hw0 = blockIdx.x * 64;
  int tid = threadIdx.x;
  int tx = tid & 15;        // hw group
  int to = tid >> 4;        // o group
  __shared__ float in_t[16][64];
  __shared__ float w_t[16][64];
  float acc[4][4] = {};
  const float* inb = in + (size_t)b * K * HW;
  for (int c0 = 0; c0 < K; c0 += 16) {
    {
      int i = tid >> 4;
      int j = (tid & 15) * 4;
      *(f32x4*)&in_t[i][j] = *(const f32x4*)&inb[(size_t)(c0 + i) * HW + hw0 + j];
    }
    {
      int o = tid & 63;
      int ib = (tid >> 6) * 4;
      #pragma unroll
      for (int q = 0; q < 4; q++)
        w_t[ib + q][o] = w[(size_t)(o0 + o) * (K + 2) + c0 + ib + q];
    }
    __syncthreads();
    #pragma unroll
    for (int i = 0; i < 16; i++) {
      f32x4 wv = *(const f32x4*)&w_t[i][to * 4];
      f32x4 xv = *(const f32x4*)&in_t[i][tx * 4];
      #pragma unroll
      for (int oo = 0; oo < 4; oo++)
        #pragma unroll
        for (int xx = 0; xx < 4; xx++)
          acc[oo][xx] = fmaf(wv[oo], xv[xx], acc[oo][xx]);
    }
    __syncthreads();
  }
  float invW = 2.0f / (float)(W - 1);
  float invH = 2.0f / (float)(H - 1);
  int hwb = hw0 + tx * 4;
  int y = hwb / W;
  int xb = hwb % W;
  float yg = -1.0f + y * invH;
  #pragma unroll
  for (int oo = 0; oo < 4; oo++) {
    int o = o0 + to * 4 + oo;
    float wx = w[(size_t)o * (K + 2) + K];
    float wy = w[(size_t)o * (K + 2) + K + 1];
    float bb = bias[o];
    #pragma unroll
    for (int xx = 0; xx < 4; xx++) {
      float xg = -1.0f + (xb + xx) * invW;
      out[((size_t)b * O + o) * HW + hwb + xx] =
          acc[oo][xx] + wx * xg + wy * yg + bb;
    }
  }
}

// bilinear helpers (half-pixel, edge clamp)
template <int Hin>
__device__ __forceinline__ void bilin_coords(int v, int& i0, int& i1, float& wgt) {
  constexpr float scale = (float)Hin / 64.0f;
  float f = ((float)v + 0.5f) * scale - 0.5f;
  float f0 = floorf(f);
  wgt = f - f0;
  int i = (int)f0;
  i1 = min(i + 1, Hin - 1);
  i0 = max(i, 0);
}

// ---------------- emit out_phi (fp32, hw fastest) — 4 px/thread ----------------
template <int C, int Cin, int Hin>
__global__ void emit_phi_v(const float* __restrict__ in, float* __restrict__ outp,
                           int ch_off) {
  int idx = blockIdx.x * 256 + threadIdx.x;  // over B*C*1024
  int x0 = (idx & 15) * 4;
  int y = (idx >> 4) & 63;
  int c = (idx >> 10) % C;
  int b = idx / (C * 1024);
  const float* pl = in + (size_t)(b * Cin + c) * (Hin * Hin);
  int y0, y1; float wy;
  bilin_coords<Hin>(y, y0, y1, wy);
  const float* r0 = pl + y0 * Hin;
  const float* r1 = pl + y1 * Hin;
  f32x4 o;
  #pragma unroll
  for (int k = 0; k < 4; k++) {
    int xx0, xx1; float wx;
    bilin_coords<Hin>(x0 + k, xx0, xx1, wx);
    float top = (1.0f - wx) * r0[xx0] + wx * r0[xx1];
    float bot = (1.0f - wx) * r1[xx0] + wx * r1[xx1];
    o[k] = (1.0f - wy) * top + wy * bot;
  }
  *(f32x4*)&outp[((size_t)b * 896 + ch_off + c) * 4096 + (y << 6) + x0] = o;
}

// ---------------- level-1 out_phi: identity resize = plain copy ----------------
__global__ void copy_phi1(const float* __restrict__ in, float* __restrict__ outp) {
  int idx = blockIdx.x * 256 + threadIdx.x;  // over 4*256*1024 f32x4 units
  int x4 = (idx & 1023) * 4;
  int c = (idx >> 10) & 255;
  int b = idx >> 18;
  f32x4 v = *(const f32x4*)&in[((size_t)(b * 256 + c) << 12) + x4];
  *(f32x4*)&outp[((size_t)(b * 896 + c) << 12) + x4] = v;
}

// ---------------- fp32 [R][Cc] -> bf16 [c][r] transpose (strided out) ----------------
__global__ __launch_bounds__(256) void trans_f32_bf16(
    const float* __restrict__ in, u16* __restrict__ outT, int R, int Cc, int OS,
    size_t in_bstride, size_t out_bstride) {
  int b = blockIdx.z;
  in += (size_t)b * in_bstride;
  outT += (size_t)b * out_bstride;
  int r0 = blockIdx.y * 32, c0 = blockIdx.x * 32;
  __shared__ float t[32][33];
  int tid = threadIdx.x;
  int cl = tid & 31, rl = tid >> 5;  // rl 0..7
  #pragma unroll
  for (int q = 0; q < 4; q++)
    t[rl + q * 8][cl] = in[(size_t)(r0 + rl + q * 8) * Cc + c0 + cl];
  __syncthreads();
  #pragma unroll
  for (int q = 0; q < 4; q++) {
    int c = c0 + rl + q * 8;
    outT[(size_t)c * OS + r0 + cl] = f2bf(t[cl][rl + q * 8]);
  }
}

// ---------------- gather A from transposed OT[b][p][C] (bf16), 8 ch/thread ----------------
template <int C, int Hin, int L>  // L = log2(C/8)
__global__ void gather_A(const u16* __restrict__ OT, u16* __restrict__ A,
                         int ch_off) {
  int idx = blockIdx.x * 256 + threadIdx.x;  // over B*4096*(C/8)
  int co = (idx & ((C / 8) - 1)) * 8;
  int hw = (idx >> L) & 4095;
  int b = idx >> (L + 12);
  int x = hw & 63, y = hw >> 6;
  int y0, y1, x0, x1; float wy, wx;
  bilin_coords<Hin>(y, y0, y1, wy);
  bilin_coords<Hin>(x, x0, x1, wx);
  float w00 = (1.0f - wy) * (1.0f - wx), w01 = (1.0f - wy) * wx;
  float w10 = wy * (1.0f - wx), w11 = wy * wx;
  const u16* base = OT + (size_t)b * (Hin * Hin) * C + co;
  bf16x8 t00 = *(const bf16x8*)&base[(y0 * Hin + x0) * C];
  bf16x8 t01 = *(const bf16x8*)&base[(y0 * Hin + x1) * C];
  bf16x8 t10 = *(const bf16x8*)&base[(y1 * Hin + x0) * C];
  bf16x8 t11 = *(const bf16x8*)&base[(y1 * Hin + x1) * C];
  bf16x8 o;
  #pragma unroll
  for (int e = 0; e < 8; e++) {
    float v = w00 * bf2f((u16)t00[e]) + w01 * bf2f((u16)t01[e]) +
              w10 * bf2f((u16)t10[e]) + w11 * bf2f((u16)t11[e]);
    o[e] = (short)f2bf(v);
  }
  *(bf16x8*)&A[((size_t)b * 4096 + hw) * 1792 + ch_off + co] = o;
}

// ---------------- row sum of squares over bf16 rows ----------------
__global__ __launch_bounds__(256) void rownorm2(const u16* __restrict__ X,
                                                float* __restrict__ out, int ncols) {
  int row = blockIdx.x * 4 + (threadIdx.x >> 6);
  int lane = threadIdx.x & 63;
  const u16* xr = X + (size_t)row * ncols;
  int n8 = ncols >> 3;
  float s = 0.0f;
  for (int c8 = lane; c8 < n8; c8 += 64) {
    bf16x8 v = *(const bf16x8*)&xr[c8 * 8];
    #pragma unroll
    for (int e = 0; e < 8; e++) {
      float f = bf2f((u16)v[e]);
      s = fmaf(f, f, s);
    }
  }
  #pragma unroll
  for (int off = 32; off; off >>= 1) s += __shfl_down(s, off);
  if (lane == 0) out[row] = s;
}

// ======== 256x256-tile deep-pipelined distance GEMM ========
#define GD_NT 56  // K/32

__device__ __forceinline__ void stage16k(const u16* __restrict__ G, int row0,
                                         int k0, char* lds_wavebase, int lane) {
  const int K = 1792;
  int sub = lane >> 2;                       // row within 16-row group
  int colsw = 8 * ((lane & 3) ^ (sub & 3));  // pre-swizzled source column
  #pragma unroll
  for (int q = 0; q < 2; q++) {
    gload_lds16(G + (size_t)(row0 + q * 128 + sub) * K + k0 + colsw,
                lds_wavebase + q * 8192);
  }
}

__global__ __launch_bounds__(512, 2) void gemm_dist2(
    const u16* __restrict__ A,   // [16384][1792]
    const u16* __restrict__ Bt,  // [4096][1792]
    const float* __restrict__ feats, const float* __restrict__ cents,
    float* __restrict__ S, int m_base) {
  const int K = 1792, N = 4096;
  extern __shared__ u16 lds[];  // 4 bufs x (A 8192 + B 8192) elems = 128 KiB
  int bid = blockIdx.x;
  int swz = (bid & 7) * 32 + (bid >> 3);
  int m0 = (swz >> 4) * 256;
  int n0 = (swz & 15) * 256;
  int tid = threadIdx.x;
  int wid = tid >> 6, lane = tid & 63;
  int wr = wid >> 2, wc = wid & 3;  // wave -> 128x64 output sub-tile
  int ln15 = lane & 15;
  int fo = 8 * ((lane >> 4) ^ (lane & 3));  // swizzled frag column offset

  f32x4 acc[8][4] = {};

  #pragma unroll
  for (int t = 0; t < 3; t++) {
    char* bufb = (char*)lds + (t & 3) * 32768 + wid * 1024;
    stage16k(A, m_base + m0 + wid * 16, t * 32, bufb, lane);
    stage16k(Bt, n0 + wid * 16, t * 32, bufb + 16384, lane);
  }

  #pragma unroll 1
  for (int t = 0; t < GD_NT; t++) {
    asm volatile("s_waitcnt vmcnt(8)" ::: "memory");
    __builtin_amdgcn_s_barrier();
    __builtin_amdgcn_sched_barrier(0);
    const u16* Ab = lds + (t & 3) * 16384;
    const u16* Bb = Ab + 8192;
    char* nbuf = (char*)lds + ((t + 3) & 3) * 32768 + wid * 1024;

    if (t + 3 < GD_NT) stage16k(A, m_base + m0 + wid * 16, (t + 3) * 32, nbuf, lane);
    bf16x8 bq[4];
    #pragma unroll
    for (int ni = 0; ni < 4; ni++)
      bq[ni] = *(const bf16x8*)&Bb[(wc * 64 + ni * 16 + ln15) * 32 + fo];
    {
      bf16x8 af[4];
      #pragma unroll
      for (int mi = 0; mi < 4; mi++)
        af[mi] = *(const bf16x8*)&Ab[(wr * 128 + mi * 16 + ln15) * 32 + fo];
      __builtin_amdgcn_s_setprio(1);
      #pragma unroll
      for (int mi = 0; mi < 4; mi++)
        #pragma unroll
        for (int ni = 0; ni < 4; ni++)
          acc[mi][ni] = __builtin_amdgcn_mfma_f32_16x16x32_bf16(af[mi], bq[ni], acc[mi][ni], 0, 0, 0);
      __builtin_amdgcn_s_setprio(0);
    }
    __builtin_amdgcn_s_barrier();

    if (t + 3 < GD_NT) stage16k(Bt, n0 + wid * 16, (t + 3) * 32, nbuf + 16384, lane);
    {
      bf16x8 af[4];
      #pragma unroll
      for (int mi = 0; mi < 4; mi++)
        af[mi] = *(const bf16x8*)&Ab[(wr * 128 + (mi + 4) * 16 + ln15) * 32 + fo];
      __builtin_amdgcn_s_setprio(1);
      #pragma unroll
      for (int mi = 0; mi < 4; mi++)
        #pragma unroll
        for (int ni = 0; ni < 4; ni++)
          acc[mi + 4][ni] = __builtin_amdgcn_mfma_f32_16x16x32_bf16(af[mi], bq[ni], acc[mi + 4][ni], 0, 0, 0);
      __builtin_amdgcn_s_setprio(0);
    }
  }

  int rq = lane >> 4, cq = lane & 15;
  #pragma unroll
  for (int mi = 0; mi < 8; mi++) {
    int lm = m0 + wr * 128 + mi * 16 + rq * 4;
    #pragma unroll
    for (int ni = 0; ni < 4; ni++) {
      int gn = n0 + wc * 64 + ni * 16 + cq;
      float cn = cents[gn];
      #pragma unroll
      for (int r = 0; r < 4; r++)
        S[(size_t)(lm + r) * N + gn] = feats[m_base + lm + r] + cn - 2.0f * acc[mi][ni][r];
    }
  }
}

// ---------------- per-row top-200 smallest (sorted) of 4096, emit sqrt ----------------
// wave-per-row: 64 keys/lane, barrier-free (shfl reductions + wave-local bitonic)
__global__ __launch_bounds__(256, 2) void select_topk(const float* __restrict__ S,
                                                      float* __restrict__ out,
                                                      int row_base) {
  int wv = threadIdx.x >> 6, lane = threadIdx.x & 63;
  int row_local = blockIdx.x * 4 + wv;
  const float* Sr = S + (size_t)row_local * 4096;
  uint32_t ku[64];
  #pragma unroll
  for (int g = 0; g < 16; g++) {
    f32x4 v = *(const f32x4*)&Sr[g * 256 + lane * 4];
    #pragma unroll
    for (int e = 0; e < 4; e++) {
      uint32_t u = __float_as_uint(v[e]);
      u ^= (u & 0x80000000u) ? 0xFFFFFFFFu : 0x80000000u;  // order-preserving
      ku[g * 4 + e] = u;
    }
  }
  // wave min/max -> tight search bracket
  uint32_t mn = 0xFFFFFFFFu, mx = 0u;
  #pragma unroll
  for (int j = 0; j < 64; j++) {
    mn = min(mn, ku[j]);
    mx = max(mx, ku[j]);
  }
  #pragma unroll
  for (int off = 1; off < 64; off <<= 1) {
    mn = min(mn, (uint32_t)__shfl_xor((int)mn, off));
    mx = max(mx, (uint32_t)__shfl_xor((int)mx, off));
  }
  // binary search for the 200th smallest value T
  uint32_t lo = mn, hi = mx;
  while (lo < hi) {
    uint32_t mid = lo + ((hi - lo) >> 1);
    int c = 0;
    #pragma unroll
    for (int j = 0; j < 64; j++) c += (ku[j] <= mid) ? 1 : 0;
    #pragma unroll
    for (int off = 1; off < 64; off <<= 1) c += __shfl_xor(c, off);
    if (c >= 200) hi = mid; else lo = mid + 1;
  }
  uint32_t T = lo;
  // count-below + per-lane exclusive prefix
  int cl = 0;
  #pragma unroll
  for (int j = 0; j < 64; j++) cl += (ku[j] < T) ? 1 : 0;
  int incl = cl;
  #pragma unroll
  for (int off = 1; off < 64; off <<= 1) {
    int v = __shfl_up(incl, off);
    if (lane >= off) incl += v;
  }
  int nless = __shfl(incl, 63);  // < 200 by definition of T
  int pos = incl - cl;
  __shared__ uint32_t selv[4][256];
  uint32_t* sv = selv[wv];
  #pragma unroll
  for (int g = 0; g < 4; g++) sv[g * 64 + lane] = 0xFFFFFFFFu;
  // positions [nless,200) are exact copies of T
  for (int p = nless + lane; p < 200; p += 64) sv[p] = T;
  // scatter keys < T
  #pragma unroll
  for (int j = 0; j < 64; j++)
    if (ku[j] < T) sv[pos++] = ku[j];
  // wave-local bitonic sort of 256 entries (in-order LDS within a wave; no barriers)
  for (int kk = 2; kk <= 256; kk <<= 1) {
    for (int jj = kk >> 1; jj > 0; jj >>= 1) {
      #pragma unroll
      for (int base = 0; base < 256; base += 64) {
        int i = base + lane, ixj = i ^ jj;
        if (ixj > i) {
          uint32_t a = sv[i], b2 = sv[ixj];
          bool up = ((i & kk) == 0);
          if ((a > b2) == up) { sv[i] = b2; sv[ixj] = a; }
        }
      }
    }
  }
  int grow = row_base + row_local;
  int b = grow >> 12, r = grow & 4095;
  #pragma unroll
  for (int g = 0; g < 4; g++) {
    int i = g * 64 + lane;
    if (i < 200) {
      uint32_t u = sv[i];
      u ^= (u & 0x80000000u) ? 0x80000000u : 0xFFFFFFFFu;
      out[((size_t)b * 200 + i) * 4096 + r] = sqrtf(__uint_as_float(u));
    }
  }
}

extern "C" void kernel_launch(void* const* d_in, const int* in_sizes, int n_in,
                              void* d_out, int out_size, void* d_ws, size_t ws_size,
                              hipStream_t stream) {
  const float* p0 = (const float*)d_in[0];   // (4,256,64,64)
  const float* p1 = (const float*)d_in[1];   // (4,512,32,32)
  const float* p2 = (const float*)d_in[2];   // (4,1024,16,16)
  const float* w1 = (const float*)d_in[5];   // (256,258)
  const float* b1 = (const float*)d_in[6];
  const float* w2 = (const float*)d_in[7];   // (512,514)
  const float* b2 = (const float*)d_in[8];
  const float* w3 = (const float*)d_in[9];   // (1024,1026)
  const float* b3 = (const float*)d_in[10];
  const float* Cm = (const float*)d_in[11];  // (1792,4096)

  float* out_score = (float*)d_out;                  // 4*200*4096 fp32
  float* out_phi = (float*)d_out + 3276800;          // 4*896*4096 fp32

  // workspace layout (peak ~140.6 MB)
  char* w = (char*)d_ws;
  u16* Abf = (u16*)w;                                //  58,720,256 B
  u16* Ct = (u16*)(w + 58720256);                    //  14,680,064 B
  float* feats = (float*)(w + 73400320);             //      65,536 B
  float* cents = (float*)(w + 73465856);             //      16,384 B
  float* S = (float*)(w + 73482240);                 //  67,108,864 B (per-chunk) -> ends 140,591,104
  // stage-A temps alias the S region (dead before first gemm)
  float* O1 = (float*)(w + 73482240);                //  16,777,216 B
  float* O2 = (float*)(w + 90259456);                //   8,388,608 B
  float* O3 = (float*)(w + 98648064);                //   4,194,304 B
  float* pooled1 = (float*)(w + 102842368);          //  16,777,216 B
  float* pooled2 = (float*)(w + 119619584);          //   8,388,608 B
  float* pooled3 = (float*)(w + 128008192);          //   4,194,304 B  -> ends 132,202,496
  u16* OT2 = (u16*)(w + 132202496);                  //   4,194,304 B  [4][1024][512]
  u16* OT3 = (u16*)(w + 136396800);                  //   2,097,152 B  [4][256][1024] -> ends 138,493,952

  // ---- stage A: pool (4 outputs/thread) ----
  pool3x3_v<64, 64><<<4096, 256, 0, stream>>>(p0, pooled1);
  pool3x3_v<32, 32><<<2048, 256, 0, stream>>>(p1, pooled2);
  pool3x3_v<16, 16><<<1024, 256, 0, stream>>>(p2, pooled3);

  // ---- stage A: coordconv 1x1 ----
  conv1x1_coord<<<dim3(64, 4, 4), 256, 0, stream>>>(pooled1, w1, b1, O1, 256, 256, 64, 64);
  conv1x1_coord<<<dim3(16, 8, 4), 256, 0, stream>>>(pooled2, w2, b2, O2, 512, 512, 32, 32);
  conv1x1_coord<<<dim3(4, 16, 4), 256, 0, stream>>>(pooled3, w3, b3, O3, 1024, 1024, 16, 16);

  // ---- output 1: PHI[:, :896] ----
  copy_phi1<<<4096, 256, 0, stream>>>(O1, out_phi);
  emit_phi_v<512, 512, 32><<<8192, 256, 0, stream>>>(O2, out_phi, 256);
  emit_phi_v<128, 1024, 16><<<2048, 256, 0, stream>>>(O3, out_phi, 768);

  // ---- A matrix: transpose-first, then coalesced gather ----
  trans_f32_bf16<<<dim3(128, 8, 4), 256, 0, stream>>>(
      O1, Abf, 256, 4096, 1792, (size_t)256 * 4096, (size_t)4096 * 1792);
  trans_f32_bf16<<<dim3(32, 16, 4), 256, 0, stream>>>(
      O2, OT2, 512, 1024, 512, (size_t)512 * 1024, (size_t)1024 * 512);
  trans_f32_bf16<<<dim3(8, 32, 4), 256, 0, stream>>>(
      O3, OT3, 1024, 256, 1024, (size_t)1024 * 256, (size_t)256 * 1024);
  gather_A<512, 32, 6><<<4096, 256, 0, stream>>>(OT2, Abf, 256);
  gather_A<1024, 16, 7><<<8192, 256, 0, stream>>>(OT3, Abf, 768);

  // ---- C transpose + bf16 ----
  trans_f32_bf16<<<dim3(128, 56, 1), 256, 0, stream>>>(Cm, Ct, 1792, 4096, 1792, 0, 0);

  // ---- norms ----
  rownorm2<<<4096, 256, 0, stream>>>(Abf, feats, 1792);
  rownorm2<<<1024, 256, 0, stream>>>(Ct, cents, 1792);

  // ---- distance GEMM (256^2 deep-pipelined) + top-200, chunked by batch image ----
  for (int mc = 0; mc < 4; mc++) {
    gemm_dist2<<<256, 512, 131072, stream>>>(Abf, Ct, feats, cents, S, mc * 4096);
    select_topk<<<1024, 256, 0, stream>>>(S, out_score, mc * 4096);
  }
}

// Round 7
// 625.559 us; speedup vs baseline: 1.7586x; 1.0994x over previous
//
#include <hip/hip_runtime.h>
#include <hip/hip_bf16.h>
#include <stdint.h>

typedef unsigned short u16;
typedef __attribute__((ext_vector_type(8))) short bf16x8;
typedef __attribute__((ext_vector_type(4))) float f32x4;

#define AS1 __attribute__((address_space(1)))
#define AS3 __attribute__((address_space(3)))

__device__ __forceinline__ u16 f2bf(float f) {
  uint32_t x = __float_as_uint(f);
  uint32_t r = (x + 0x7FFFu + ((x >> 16) & 1u)) >> 16;
  return (u16)r;
}
__device__ __forceinline__ float bf2f(u16 u) {
  return __uint_as_float(((uint32_t)u) << 16);
}

__device__ __forceinline__ void gload_lds16(const void* g, void* l) {
  __builtin_amdgcn_global_load_lds((const AS1 void*)g, (AS3 void*)l, 16, 0, 0);
}

// ---------------- 3x3 avg pool, stride 1, pad 1, /9 — 4 outputs/thread ----------------
template <int H, int W>
__global__ void pool3x3_v(const float* __restrict__ in, float* __restrict__ out) {
  constexpr int W4 = W / 4;
  int idx = blockIdx.x * 256 + threadIdx.x;  // over B*C*H*W/4
  int x0 = (idx % W4) * 4;
  int h = (idx / W4) % H;
  int p = idx / (W4 * H);  // b*C + c
  const float* pl = in + (size_t)p * H * W;
  float cs[6] = {0, 0, 0, 0, 0, 0};
  #pragma unroll
  for (int dy = -1; dy <= 1; dy++) {
    int yy = h + dy;
    if ((unsigned)yy < (unsigned)H) {
      const float* row = pl + yy * W;
      #pragma unroll
      for (int k = 0; k < 6; k++) {
        int xx = x0 - 1 + k;
        if ((unsigned)xx < (unsigned)W) cs[k] += row[xx];
      }
    }
  }
  f32x4 o;
  #pragma unroll
  for (int k = 0; k < 4; k++) o[k] = (cs[k] + cs[k + 1] + cs[k + 2]) * (1.0f / 9.0f);
  *(f32x4*)&out[(size_t)p * H * W + h * W + x0] = o;
}

// ---------------- w[O][K+2] fp32 -> Wb[O][K] bf16 ----------------
__global__ void wconv_bf16(const float* __restrict__ wf, u16* __restrict__ wb,
                           int logk, int total) {
  int idx = blockIdx.x * 256 + threadIdx.x;
  if (idx >= total) return;
  int K = 1 << logk;
  int o = idx >> (logk - 3);
  int k0 = (idx & ((K >> 3) - 1)) * 8;
  const float* src = wf + (size_t)o * (K + 2) + k0;
  bf16x8 v;
  #pragma unroll
  for (int e = 0; e < 8; e++) v[e] = (short)f2bf(src[e]);
  *(bf16x8*)&wb[(size_t)o * K + k0] = v;
}

// ======== MFMA CoordConv GEMM: out[b][o][hw] = Wb[o]·PT[b*HW+hw] + coord ========
template <int K, int HW, int WD, int OC>
__global__ __launch_bounds__(256) void conv_gemm(
    const u16* __restrict__ Wb,   // [OC][K] bf16
    const u16* __restrict__ PT,   // [4*HW][K] bf16
    const float* __restrict__ wf, // [OC][K+2] fp32 (coord cols)
    const float* __restrict__ bias,
    float* __restrict__ outp) {   // [4][OC][HW] fp32
  constexpr int LOGW = (WD == 64) ? 6 : (WD == 32) ? 5 : 4;
  constexpr int LOGHW = 2 * LOGW;
  int n0 = blockIdx.x * 128, m0 = blockIdx.y * 128;
  int tid = threadIdx.x;
  int wid = tid >> 6, lane = tid & 63;
  int wm = wid >> 1, wn = wid & 1;
  __shared__ u16 As[128 * 64];
  __shared__ u16 Bs[128 * 64];
  f32x4 acc[4][4] = {};
  int lrow = tid >> 3;           // 0..31
  int lcol = (tid & 7) * 8;
  const u16* ga = Wb + (size_t)(m0 + lrow) * K + lcol;
  const u16* gb = PT + (size_t)(n0 + lrow) * K + lcol;
  char* lbaseA = (char*)As + wid * 1024;
  char* lbaseB = (char*)Bs + wid * 1024;
  for (int k0 = 0; k0 < K; k0 += 64) {
    #pragma unroll
    for (int q = 0; q < 4; q++) {
      gload_lds16(ga + (size_t)q * 32 * K + k0, lbaseA + q * 4096);
      gload_lds16(gb + (size_t)q * 32 * K + k0, lbaseB + q * 4096);
    }
    __syncthreads();
    #pragma unroll
    for (int kk = 0; kk < 2; kk++) {
      bf16x8 af[4], bfr[4];
      int kb = kk * 32 + (lane >> 4) * 8;
      #pragma unroll
      for (int i = 0; i < 4; i++)
        af[i] = *(const bf16x8*)&As[(wm * 64 + i * 16 + (lane & 15)) * 64 + kb];
      #pragma unroll
      for (int j = 0; j < 4; j++)
        bfr[j] = *(const bf16x8*)&Bs[(wn * 64 + j * 16 + (lane & 15)) * 64 + kb];
      #pragma unroll
      for (int i = 0; i < 4; i++)
        #pragma unroll
        for (int j = 0; j < 4; j++)
          acc[i][j] = __builtin_amdgcn_mfma_f32_16x16x32_bf16(af[i], bfr[j], acc[i][j], 0, 0, 0);
    }
    __syncthreads();
  }
  int rq = lane >> 4, cq = lane & 15;
  #pragma unroll
  for (int mi = 0; mi < 4; mi++) {
    int lm = m0 + wm * 64 + mi * 16 + rq * 4;
    float wxr[4], wyr[4], bbr[4];
    #pragma unroll
    for (int r = 0; r < 4; r++) {
      int o = lm + r;
      wxr[r] = wf[(size_t)o * (K + 2) + K];
      wyr[r] = wf[(size_t)o * (K + 2) + K + 1];
      bbr[r] = bias[o];
    }
    #pragma unroll
    for (int ni = 0; ni < 4; ni++) {
      int gn = n0 + wn * 64 + ni * 16 + cq;
      int b = gn >> LOGHW;
      int hw = gn & (HW - 1);
      int x = hw & (WD - 1), y = hw >> LOGW;
      float xg = -1.0f + x * (2.0f / (WD - 1));
      float yg = -1.0f + y * (2.0f / (WD - 1));
      #pragma unroll
      for (int r = 0; r < 4; r++) {
        outp[((size_t)b * OC + lm + r) * HW + hw] =
            acc[mi][ni][r] + wxr[r] * xg + wyr[r] * yg + bbr[r];
      }
    }
  }
}

// bilinear helpers (half-pixel, edge clamp)
template <int Hin>
__device__ __forceinline__ void bilin_coords(int v, int& i0, int& i1, float& wgt) {
  constexpr float scale = (float)Hin / 64.0f;
  float f = ((float)v + 0.5f) * scale - 0.5f;
  float f0 = floorf(f);
  wgt = f - f0;
  int i = (int)f0;
  i1 = min(i + 1, Hin - 1);
  i0 = max(i, 0);
}

// ---------------- emit out_phi (fp32, hw fastest) — 4 px/thread ----------------
template <int C, int Cin, int Hin>
__global__ void emit_phi_v(const float* __restrict__ in, float* __restrict__ outp,
                           int ch_off) {
  int idx = blockIdx.x * 256 + threadIdx.x;  // over B*C*1024
  int x0 = (idx & 15) * 4;
  int y = (idx >> 4) & 63;
  int c = (idx >> 10) % C;
  int b = idx / (C * 1024);
  const float* pl = in + (size_t)(b * Cin + c) * (Hin * Hin);
  int y0, y1; float wy;
  bilin_coords<Hin>(y, y0, y1, wy);
  const float* r0 = pl + y0 * Hin;
  const float* r1 = pl + y1 * Hin;
  f32x4 o;
  #pragma unroll
  for (int k = 0; k < 4; k++) {
    int xx0, xx1; float wx;
    bilin_coords<Hin>(x0 + k, xx0, xx1, wx);
    float top = (1.0f - wx) * r0[xx0] + wx * r0[xx1];
    float bot = (1.0f - wx) * r1[xx0] + wx * r1[xx1];
    o[k] = (1.0f - wy) * top + wy * bot;
  }
  *(f32x4*)&outp[((size_t)b * 896 + ch_off + c) * 4096 + (y << 6) + x0] = o;
}

// ---------------- level-1 out_phi: identity resize = plain copy ----------------
__global__ void copy_phi1(const float* __restrict__ in, float* __restrict__ outp) {
  int idx = blockIdx.x * 256 + threadIdx.x;  // over 4*256*1024 f32x4 units
  int x4 = (idx & 1023) * 4;
  int c = (idx >> 10) & 255;
  int b = idx >> 18;
  f32x4 v = *(const f32x4*)&in[((size_t)(b * 256 + c) << 12) + x4];
  *(f32x4*)&outp[((size_t)(b * 896 + c) << 12) + x4] = v;
}

// ---------------- fp32 [R][Cc] -> bf16 [c][r] transpose (strided out) ----------------
__global__ __launch_bounds__(256) void trans_f32_bf16(
    const float* __restrict__ in, u16* __restrict__ outT, int R, int Cc, int OS,
    size_t in_bstride, size_t out_bstride) {
  int b = blockIdx.z;
  in += (size_t)b * in_bstride;
  outT += (size_t)b * out_bstride;
  int r0 = blockIdx.y * 32, c0 = blockIdx.x * 32;
  __shared__ float t[32][33];
  int tid = threadIdx.x;
  int cl = tid & 31, rl = tid >> 5;  // rl 0..7
  #pragma unroll
  for (int q = 0; q < 4; q++)
    t[rl + q * 8][cl] = in[(size_t)(r0 + rl + q * 8) * Cc + c0 + cl];
  __syncthreads();
  #pragma unroll
  for (int q = 0; q < 4; q++) {
    int c = c0 + rl + q * 8;
    outT[(size_t)c * OS + r0 + cl] = f2bf(t[cl][rl + q * 8]);
  }
}

// ---------------- gather A from transposed OT[b][p][C] (bf16), 8 ch/thread ----------------
template <int C, int Hin, int L>  // L = log2(C/8)
__global__ void gather_A(const u16* __restrict__ OT, u16* __restrict__ A,
                         int ch_off) {
  int idx = blockIdx.x * 256 + threadIdx.x;  // over B*4096*(C/8)
  int co = (idx & ((C / 8) - 1)) * 8;
  int hw = (idx >> L) & 4095;
  int b = idx >> (L + 12);
  int x = hw & 63, y = hw >> 6;
  int y0, y1, x0, x1; float wy, wx;
  bilin_coords<Hin>(y, y0, y1, wy);
  bilin_coords<Hin>(x, x0, x1, wx);
  float w00 = (1.0f - wy) * (1.0f - wx), w01 = (1.0f - wy) * wx;
  float w10 = wy * (1.0f - wx), w11 = wy * wx;
  const u16* base = OT + (size_t)b * (Hin * Hin) * C + co;
  bf16x8 t00 = *(const bf16x8*)&base[(y0 * Hin + x0) * C];
  bf16x8 t01 = *(const bf16x8*)&base[(y0 * Hin + x1) * C];
  bf16x8 t10 = *(const bf16x8*)&base[(y1 * Hin + x0) * C];
  bf16x8 t11 = *(const bf16x8*)&base[(y1 * Hin + x1) * C];
  bf16x8 o;
  #pragma unroll
  for (int e = 0; e < 8; e++) {
    float v = w00 * bf2f((u16)t00[e]) + w01 * bf2f((u16)t01[e]) +
              w10 * bf2f((u16)t10[e]) + w11 * bf2f((u16)t11[e]);
    o[e] = (short)f2bf(v);
  }
  *(bf16x8*)&A[((size_t)b * 4096 + hw) * 1792 + ch_off + co] = o;
}

// ---------------- row sum of squares over bf16 rows ----------------
__global__ __launch_bounds__(256) void rownorm2(const u16* __restrict__ X,
                                                float* __restrict__ out, int ncols) {
  int row = blockIdx.x * 4 + (threadIdx.x >> 6);
  int lane = threadIdx.x & 63;
  const u16* xr = X + (size_t)row * ncols;
  int n8 = ncols >> 3;
  float s = 0.0f;
  for (int c8 = lane; c8 < n8; c8 += 64) {
    bf16x8 v = *(const bf16x8*)&xr[c8 * 8];
    #pragma unroll
    for (int e = 0; e < 8; e++) {
      float f = bf2f((u16)v[e]);
      s = fmaf(f, f, s);
    }
  }
  #pragma unroll
  for (int off = 32; off; off >>= 1) s += __shfl_down(s, off);
  if (lane == 0) out[row] = s;
}

// ======== 256x256-tile deep-pipelined distance GEMM ========
#define GD_NT 56  // K/32

__device__ __forceinline__ void stage16k(const u16* __restrict__ G, int row0,
                                         int k0, char* lds_wavebase, int lane) {
  const int K = 1792;
  int sub = lane >> 2;                       // row within 16-row group
  int colsw = 8 * ((lane & 3) ^ (sub & 3));  // pre-swizzled source column
  #pragma unroll
  for (int q = 0; q < 2; q++) {
    gload_lds16(G + (size_t)(row0 + q * 128 + sub) * K + k0 + colsw,
                lds_wavebase + q * 8192);
  }
}

__global__ __launch_bounds__(512, 2) void gemm_dist2(
    const u16* __restrict__ A,   // [16384][1792]
    const u16* __restrict__ Bt,  // [4096][1792]
    const float* __restrict__ feats, const float* __restrict__ cents,
    float* __restrict__ S, int m_base) {
  const int K = 1792, N = 4096;
  extern __shared__ u16 lds[];  // 4 bufs x (A 8192 + B 8192) elems = 128 KiB
  int bid = blockIdx.x;
  int swz = (bid & 7) * 32 + (bid >> 3);
  int m0 = (swz >> 4) * 256;
  int n0 = (swz & 15) * 256;
  int tid = threadIdx.x;
  int wid = tid >> 6, lane = tid & 63;
  int wr = wid >> 2, wc = wid & 3;  // wave -> 128x64 output sub-tile
  int ln15 = lane & 15;
  int fo = 8 * ((lane >> 4) ^ (lane & 3));  // swizzled frag column offset

  f32x4 acc[8][4] = {};

  #pragma unroll
  for (int t = 0; t < 3; t++) {
    char* bufb = (char*)lds + (t & 3) * 32768 + wid * 1024;
    stage16k(A, m_base + m0 + wid * 16, t * 32, bufb, lane);
    stage16k(Bt, n0 + wid * 16, t * 32, bufb + 16384, lane);
  }

  #pragma unroll 1
  for (int t = 0; t < GD_NT; t++) {
    asm volatile("s_waitcnt vmcnt(8)" ::: "memory");
    __builtin_amdgcn_s_barrier();
    __builtin_amdgcn_sched_barrier(0);
    const u16* Ab = lds + (t & 3) * 16384;
    const u16* Bb = Ab + 8192;
    char* nbuf = (char*)lds + ((t + 3) & 3) * 32768 + wid * 1024;

    if (t + 3 < GD_NT) stage16k(A, m_base + m0 + wid * 16, (t + 3) * 32, nbuf, lane);
    bf16x8 bq[4];
    #pragma unroll
    for (int ni = 0; ni < 4; ni++)
      bq[ni] = *(const bf16x8*)&Bb[(wc * 64 + ni * 16 + ln15) * 32 + fo];
    {
      bf16x8 af[4];
      #pragma unroll
      for (int mi = 0; mi < 4; mi++)
        af[mi] = *(const bf16x8*)&Ab[(wr * 128 + mi * 16 + ln15) * 32 + fo];
      __builtin_amdgcn_s_setprio(1);
      #pragma unroll
      for (int mi = 0; mi < 4; mi++)
        #pragma unroll
        for (int ni = 0; ni < 4; ni++)
          acc[mi][ni] = __builtin_amdgcn_mfma_f32_16x16x32_bf16(af[mi], bq[ni], acc[mi][ni], 0, 0, 0);
      __builtin_amdgcn_s_setprio(0);
    }
    __builtin_amdgcn_s_barrier();

    if (t + 3 < GD_NT) stage16k(Bt, n0 + wid * 16, (t + 3) * 32, nbuf + 16384, lane);
    {
      bf16x8 af[4];
      #pragma unroll
      for (int mi = 0; mi < 4; mi++)
        af[mi] = *(const bf16x8*)&Ab[(wr * 128 + (mi + 4) * 16 + ln15) * 32 + fo];
      __builtin_amdgcn_s_setprio(1);
      #pragma unroll
      for (int mi = 0; mi < 4; mi++)
        #pragma unroll
        for (int ni = 0; ni < 4; ni++)
          acc[mi + 4][ni] = __builtin_amdgcn_mfma_f32_16x16x32_bf16(af[mi], bq[ni], acc[mi + 4][ni], 0, 0, 0);
      __builtin_amdgcn_s_setprio(0);
    }
  }

  int rq = lane >> 4, cq = lane & 15;
  #pragma unroll
  for (int mi = 0; mi < 8; mi++) {
    int lm = m0 + wr * 128 + mi * 16 + rq * 4;
    #pragma unroll
    for (int ni = 0; ni < 4; ni++) {
      int gn = n0 + wc * 64 + ni * 16 + cq;
      float cn = cents[gn];
      #pragma unroll
      for (int r = 0; r < 4; r++)
        S[(size_t)(lm + r) * N + gn] = feats[m_base + lm + r] + cn - 2.0f * acc[mi][ni][r];
    }
  }
}

// ---------------- per-row top-200 smallest (sorted) of 4096, emit sqrt ----------------
// wave-per-row: 64 keys/lane, barrier-free (shfl reductions + wave-local bitonic)
__global__ __launch_bounds__(256, 2) void select_topk(const float* __restrict__ S,
                                                      float* __restrict__ out,
                                                      int row_base) {
  int wv = threadIdx.x >> 6, lane = threadIdx.x & 63;
  int row_local = blockIdx.x * 4 + wv;
  const float* Sr = S + (size_t)row_local * 4096;
  uint32_t ku[64];
  #pragma unroll
  for (int g = 0; g < 16; g++) {
    f32x4 v = *(const f32x4*)&Sr[g * 256 + lane * 4];
    #pragma unroll
    for (int e = 0; e < 4; e++) {
      uint32_t u = __float_as_uint(v[e]);
      u ^= (u & 0x80000000u) ? 0xFFFFFFFFu : 0x80000000u;  // order-preserving
      ku[g * 4 + e] = u;
    }
  }
  // wave min/max -> tight search bracket
  uint32_t mn = 0xFFFFFFFFu, mx = 0u;
  #pragma unroll
  for (int j = 0; j < 64; j++) {
    mn = min(mn, ku[j]);
    mx = max(mx, ku[j]);
  }
  #pragma unroll
  for (int off = 1; off < 64; off <<= 1) {
    mn = min(mn, (uint32_t)__shfl_xor((int)mn, off));
    mx = max(mx, (uint32_t)__shfl_xor((int)mx, off));
  }
  // binary search for the 200th smallest value T
  uint32_t lo = mn, hi = mx;
  while (lo < hi) {
    uint32_t mid = lo + ((hi - lo) >> 1);
    int c = 0;
    #pragma unroll
    for (int j = 0; j < 64; j++) c += (ku[j] <= mid) ? 1 : 0;
    #pragma unroll
    for (int off = 1; off < 64; off <<= 1) c += __shfl_xor(c, off);
    if (c >= 200) hi = mid; else lo = mid + 1;
  }
  uint32_t T = lo;
  // count-below + per-lane exclusive prefix
  int cl = 0;
  #pragma unroll
  for (int j = 0; j < 64; j++) cl += (ku[j] < T) ? 1 : 0;
  int incl = cl;
  #pragma unroll
  for (int off = 1; off < 64; off <<= 1) {
    int v = __shfl_up(incl, off);
    if (lane >= off) incl += v;
  }
  int nless = __shfl(incl, 63);  // < 200 by definition of T
  int pos = incl - cl;
  __shared__ uint32_t selv[4][256];
  uint32_t* sv = selv[wv];
  #pragma unroll
  for (int g = 0; g < 4; g++) sv[g * 64 + lane] = 0xFFFFFFFFu;
  // positions [nless,200) are exact copies of T
  for (int p = nless + lane; p < 200; p += 64) sv[p] = T;
  // scatter keys < T
  #pragma unroll
  for (int j = 0; j < 64; j++)
    if (ku[j] < T) sv[pos++] = ku[j];
  // wave-local bitonic sort of 256 entries (in-order LDS within a wave; no barriers)
  for (int kk = 2; kk <= 256; kk <<= 1) {
    for (int jj = kk >> 1; jj > 0; jj >>= 1) {
      #pragma unroll
      for (int base = 0; base < 256; base += 64) {
        int i = base + lane, ixj = i ^ jj;
        if (ixj > i) {
          uint32_t a = sv[i], b2 = sv[ixj];
          bool up = ((i & kk) == 0);
          if ((a > b2) == up) { sv[i] = b2; sv[ixj] = a; }
        }
      }
    }
  }
  int grow = row_base + row_local;
  int b = grow >> 12, r = grow & 4095;
  #pragma unroll
  for (int g = 0; g < 4; g++) {
    int i = g * 64 + lane;
    if (i < 200) {
      uint32_t u = sv[i];
      u ^= (u & 0x80000000u) ? 0x80000000u : 0xFFFFFFFFu;
      out[((size_t)b * 200 + i) * 4096 + r] = sqrtf(__uint_as_float(u));
    }
  }
}

extern "C" void kernel_launch(void* const* d_in, const int* in_sizes, int n_in,
                              void* d_out, int out_size, void* d_ws, size_t ws_size,
                              hipStream_t stream) {
  const float* p0 = (const float*)d_in[0];   // (4,256,64,64)
  const float* p1 = (const float*)d_in[1];   // (4,512,32,32)
  const float* p2 = (const float*)d_in[2];   // (4,1024,16,16)
  const float* w1 = (const float*)d_in[5];   // (256,258)
  const float* b1 = (const float*)d_in[6];
  const float* w2 = (const float*)d_in[7];   // (512,514)
  const float* b2 = (const float*)d_in[8];
  const float* w3 = (const float*)d_in[9];   // (1024,1026)
  const float* b3 = (const float*)d_in[10];
  const float* Cm = (const float*)d_in[11];  // (1792,4096)

  float* out_score = (float*)d_out;                  // 4*200*4096 fp32
  float* out_phi = (float*)d_out + 3276800;          // 4*896*4096 fp32

  // workspace layout (peak 140,591,104 B — proven)
  char* w = (char*)d_ws;
  u16* Abf = (u16*)w;                                //  58,720,256 B
  u16* Ct = (u16*)(w + 58720256);                    //  14,680,064 B
  float* feats = (float*)(w + 73400320);             //      65,536 B
  float* cents = (float*)(w + 73465856);             //      16,384 B
  float* S = (float*)(w + 73482240);                 //  67,108,864 B (per-chunk) -> ends 140,591,104
  // stage-A temps alias the S region (dead before first gemm)
  float* O1 = (float*)(w + 73482240);                //  16,777,216 B
  float* O2 = (float*)(w + 90259456);                //   8,388,608 B
  float* O3 = (float*)(w + 98648064);                //   4,194,304 B
  float* pooled1 = (float*)(w + 102842368);          //  16,777,216 B (dead after PT1 trans)
  float* pooled2 = (float*)(w + 119619584);          //   8,388,608 B
  float* pooled3 = (float*)(w + 128008192);          //   4,194,304 B  -> ends 132,202,496
  // conv-GEMM operands (aliased):
  u16* PT1 = (u16*)(w + 132202496);                  //   8,388,608 B [4*4096][256] (dead before OT2 write)
  u16* PT2 = (u16*)(w + 102842368);                  //   4,194,304 B [4*1024][512] (in dead pooled1)
  u16* PT3 = (u16*)(w + 107036672);                  //   2,097,152 B [4*256][1024]
  u16* Wbf1 = (u16*)(w + 109133824);                 //     131,072 B
  u16* Wbf2 = (u16*)(w + 109264896);                 //     524,288 B
  u16* Wbf3 = (u16*)(w + 109789184);                 //   2,097,152 B -> ends 111,886,336
  u16* OT2 = (u16*)(w + 132202496);                  //   4,194,304 B  [4][1024][512]
  u16* OT3 = (u16*)(w + 136396800);                  //   2,097,152 B  [4][256][1024] -> ends 138,493,952

  // ---- stage A: pool (4 outputs/thread) ----
  pool3x3_v<64, 64><<<4096, 256, 0, stream>>>(p0, pooled1);
  pool3x3_v<32, 32><<<2048, 256, 0, stream>>>(p1, pooled2);
  pool3x3_v<16, 16><<<1024, 256, 0, stream>>>(p2, pooled3);

  // ---- conv operands: pooled -> PT (bf16 [n][k]); w -> Wb (bf16 [o][k]) ----
  trans_f32_bf16<<<dim3(128, 8, 4), 256, 0, stream>>>(
      pooled1, PT1, 256, 4096, 256, (size_t)256 * 4096, (size_t)4096 * 256);
  trans_f32_bf16<<<dim3(32, 16, 4), 256, 0, stream>>>(
      pooled2, PT2, 512, 1024, 512, (size_t)512 * 1024, (size_t)1024 * 512);
  trans_f32_bf16<<<dim3(8, 32, 4), 256, 0, stream>>>(
      pooled3, PT3, 1024, 256, 1024, (size_t)1024 * 256, (size_t)256 * 1024);
  wconv_bf16<<<32, 256, 0, stream>>>(w1, Wbf1, 8, 8192);
  wconv_bf16<<<128, 256, 0, stream>>>(w2, Wbf2, 9, 32768);
  wconv_bf16<<<512, 256, 0, stream>>>(w3, Wbf3, 10, 131072);

  // ---- stage A: coordconv 1x1 via MFMA GEMM ----
  conv_gemm<256, 4096, 64, 256><<<dim3(128, 2), 256, 0, stream>>>(Wbf1, PT1, w1, b1, O1);
  conv_gemm<512, 1024, 32, 512><<<dim3(32, 4), 256, 0, stream>>>(Wbf2, PT2, w2, b2, O2);
  conv_gemm<1024, 256, 16, 1024><<<dim3(8, 8), 256, 0, stream>>>(Wbf3, PT3, w3, b3, O3);

  // ---- output 1: PHI[:, :896] ----
  copy_phi1<<<4096, 256, 0, stream>>>(O1, out_phi);
  emit_phi_v<512, 512, 32><<<8192, 256, 0, stream>>>(O2, out_phi, 256);
  emit_phi_v<128, 1024, 16><<<2048, 256, 0, stream>>>(O3, out_phi, 768);

  // ---- A matrix: transpose-first, then coalesced gather ----
  trans_f32_bf16<<<dim3(128, 8, 4), 256, 0, stream>>>(
      O1, Abf, 256, 4096, 1792, (size_t)256 * 4096, (size_t)4096 * 1792);
  trans_f32_bf16<<<dim3(32, 16, 4), 256, 0, stream>>>(
      O2, OT2, 512, 1024, 512, (size_t)512 * 1024, (size_t)1024 * 512);
  trans_f32_bf16<<<dim3(8, 32, 4), 256, 0, stream>>>(
      O3, OT3, 1024, 256, 1024, (size_t)1024 * 256, (size_t)256 * 1024);
  gather_A<512, 32, 6><<<4096, 256, 0, stream>>>(OT2, Abf, 256);
  gather_A<1024, 16, 7><<<8192, 256, 0, stream>>>(OT3, Abf, 768);

  // ---- C transpose + bf16 ----
  trans_f32_bf16<<<dim3(128, 56, 1), 256, 0, stream>>>(Cm, Ct, 1792, 4096, 1792, 0, 0);

  // ---- norms ----
  rownorm2<<<4096, 256, 0, stream>>>(Abf, feats, 1792);
  rownorm2<<<1024, 256, 0, stream>>>(Ct, cents, 1792);

  // ---- distance GEMM (256^2 deep-pipelined) + top-200, chunked by batch image ----
  for (int mc = 0; mc < 4; mc++) {
    gemm_dist2<<<256, 512, 131072, stream>>>(Abf, Ct, feats, cents, S, mc * 4096);
    select_topk<<<1024, 256, 0, stream>>>(S, out_score, mc * 4096);
  }
}

// Round 8
// 592.813 us; speedup vs baseline: 1.8557x; 1.0552x over previous
//
#include <hip/hip_runtime.h>
#include <hip/hip_bf16.h>
#include <stdint.h>

typedef unsigned short u16;
typedef __attribute__((ext_vector_type(8))) short bf16x8;
typedef __attribute__((ext_vector_type(4))) float f32x4;

#define AS1 __attribute__((address_space(1)))
#define AS3 __attribute__((address_space(3)))

__device__ __forceinline__ u16 f2bf(float f) {
  uint32_t x = __float_as_uint(f);
  uint32_t r = (x + 0x7FFFu + ((x >> 16) & 1u)) >> 16;
  return (u16)r;
}
__device__ __forceinline__ float bf2f(u16 u) {
  return __uint_as_float(((uint32_t)u) << 16);
}

__device__ __forceinline__ void gload_lds16(const void* g, void* l) {
  __builtin_amdgcn_global_load_lds((const AS1 void*)g, (AS3 void*)l, 16, 0, 0);
}

// ---------------- 3x3 avg pool, stride 1, pad 1, /9 — 4 outputs/thread ----------------
template <int H, int W>
__global__ void pool3x3_v(const float* __restrict__ in, float* __restrict__ out) {
  constexpr int W4 = W / 4;
  int idx = blockIdx.x * 256 + threadIdx.x;  // over B*C*H*W/4
  int x0 = (idx % W4) * 4;
  int h = (idx / W4) % H;
  int p = idx / (W4 * H);  // b*C + c
  const float* pl = in + (size_t)p * H * W;
  float cs[6] = {0, 0, 0, 0, 0, 0};
  #pragma unroll
  for (int dy = -1; dy <= 1; dy++) {
    int yy = h + dy;
    if ((unsigned)yy < (unsigned)H) {
      const float* row = pl + yy * W;
      #pragma unroll
      for (int k = 0; k < 6; k++) {
        int xx = x0 - 1 + k;
        if ((unsigned)xx < (unsigned)W) cs[k] += row[xx];
      }
    }
  }
  f32x4 o;
  #pragma unroll
  for (int k = 0; k < 4; k++) o[k] = (cs[k] + cs[k + 1] + cs[k + 2]) * (1.0f / 9.0f);
  *(f32x4*)&out[(size_t)p * H * W + h * W + x0] = o;
}

// ---------------- w[O][K+2] fp32 -> Wb[O][K] bf16 ----------------
__global__ void wconv_bf16(const float* __restrict__ wf, u16* __restrict__ wb,
                           int logk, int total) {
  int idx = blockIdx.x * 256 + threadIdx.x;
  if (idx >= total) return;
  int K = 1 << logk;
  int o = idx >> (logk - 3);
  int k0 = (idx & ((K >> 3) - 1)) * 8;
  const float* src = wf + (size_t)o * (K + 2) + k0;
  bf16x8 v;
  #pragma unroll
  for (int e = 0; e < 8; e++) v[e] = (short)f2bf(src[e]);
  *(bf16x8*)&wb[(size_t)o * K + k0] = v;
}

// ======== MFMA CoordConv GEMM: out[b][o][hw] = Wb[o]·PT[b*HW+hw] + coord ========
template <int K, int HW, int WD, int OC>
__global__ __launch_bounds__(256) void conv_gemm(
    const u16* __restrict__ Wb,   // [OC][K] bf16
    const u16* __restrict__ PT,   // [4*HW][K] bf16
    const float* __restrict__ wf, // [OC][K+2] fp32 (coord cols)
    const float* __restrict__ bias,
    float* __restrict__ outp) {   // [4][OC][HW] fp32
  constexpr int LOGW = (WD == 64) ? 6 : (WD == 32) ? 5 : 4;
  constexpr int LOGHW = 2 * LOGW;
  int n0 = blockIdx.x * 128, m0 = blockIdx.y * 128;
  int tid = threadIdx.x;
  int wid = tid >> 6, lane = tid & 63;
  int wm = wid >> 1, wn = wid & 1;
  __shared__ u16 As[128 * 64];
  __shared__ u16 Bs[128 * 64];
  f32x4 acc[4][4] = {};
  int lrow = tid >> 3;           // 0..31
  int lcol = (tid & 7) * 8;
  const u16* ga = Wb + (size_t)(m0 + lrow) * K + lcol;
  const u16* gb = PT + (size_t)(n0 + lrow) * K + lcol;
  char* lbaseA = (char*)As + wid * 1024;
  char* lbaseB = (char*)Bs + wid * 1024;
  for (int k0 = 0; k0 < K; k0 += 64) {
    #pragma unroll
    for (int q = 0; q < 4; q++) {
      gload_lds16(ga + (size_t)q * 32 * K + k0, lbaseA + q * 4096);
      gload_lds16(gb + (size_t)q * 32 * K + k0, lbaseB + q * 4096);
    }
    __syncthreads();
    #pragma unroll
    for (int kk = 0; kk < 2; kk++) {
      bf16x8 af[4], bfr[4];
      int kb = kk * 32 + (lane >> 4) * 8;
      #pragma unroll
      for (int i = 0; i < 4; i++)
        af[i] = *(const bf16x8*)&As[(wm * 64 + i * 16 + (lane & 15)) * 64 + kb];
      #pragma unroll
      for (int j = 0; j < 4; j++)
        bfr[j] = *(const bf16x8*)&Bs[(wn * 64 + j * 16 + (lane & 15)) * 64 + kb];
      #pragma unroll
      for (int i = 0; i < 4; i++)
        #pragma unroll
        for (int j = 0; j < 4; j++)
          acc[i][j] = __builtin_amdgcn_mfma_f32_16x16x32_bf16(af[i], bfr[j], acc[i][j], 0, 0, 0);
    }
    __syncthreads();
  }
  int rq = lane >> 4, cq = lane & 15;
  #pragma unroll
  for (int mi = 0; mi < 4; mi++) {
    int lm = m0 + wm * 64 + mi * 16 + rq * 4;
    float wxr[4], wyr[4], bbr[4];
    #pragma unroll
    for (int r = 0; r < 4; r++) {
      int o = lm + r;
      wxr[r] = wf[(size_t)o * (K + 2) + K];
      wyr[r] = wf[(size_t)o * (K + 2) + K + 1];
      bbr[r] = bias[o];
    }
    #pragma unroll
    for (int ni = 0; ni < 4; ni++) {
      int gn = n0 + wn * 64 + ni * 16 + cq;
      int b = gn >> LOGHW;
      int hw = gn & (HW - 1);
      int x = hw & (WD - 1), y = hw >> LOGW;
      float xg = -1.0f + x * (2.0f / (WD - 1));
      float yg = -1.0f + y * (2.0f / (WD - 1));
      #pragma unroll
      for (int r = 0; r < 4; r++) {
        outp[((size_t)b * OC + lm + r) * HW + hw] =
            acc[mi][ni][r] + wxr[r] * xg + wyr[r] * yg + bbr[r];
      }
    }
  }
}

// bilinear helpers (half-pixel, edge clamp)
template <int Hin>
__device__ __forceinline__ void bilin_coords(int v, int& i0, int& i1, float& wgt) {
  constexpr float scale = (float)Hin / 64.0f;
  float f = ((float)v + 0.5f) * scale - 0.5f;
  float f0 = floorf(f);
  wgt = f - f0;
  int i = (int)f0;
  i1 = min(i + 1, Hin - 1);
  i0 = max(i, 0);
}

// ---------------- emit out_phi (fp32, hw fastest) — 4 px/thread ----------------
template <int C, int Cin, int Hin>
__global__ void emit_phi_v(const float* __restrict__ in, float* __restrict__ outp,
                           int ch_off) {
  int idx = blockIdx.x * 256 + threadIdx.x;  // over B*C*1024
  int x0 = (idx & 15) * 4;
  int y = (idx >> 4) & 63;
  int c = (idx >> 10) % C;
  int b = idx / (C * 1024);
  const float* pl = in + (size_t)(b * Cin + c) * (Hin * Hin);
  int y0, y1; float wy;
  bilin_coords<Hin>(y, y0, y1, wy);
  const float* r0 = pl + y0 * Hin;
  const float* r1 = pl + y1 * Hin;
  f32x4 o;
  #pragma unroll
  for (int k = 0; k < 4; k++) {
    int xx0, xx1; float wx;
    bilin_coords<Hin>(x0 + k, xx0, xx1, wx);
    float top = (1.0f - wx) * r0[xx0] + wx * r0[xx1];
    float bot = (1.0f - wx) * r1[xx0] + wx * r1[xx1];
    o[k] = (1.0f - wy) * top + wy * bot;
  }
  *(f32x4*)&outp[((size_t)b * 896 + ch_off + c) * 4096 + (y << 6) + x0] = o;
}

// ---------------- level-1 out_phi: identity resize = plain copy ----------------
__global__ void copy_phi1(const float* __restrict__ in, float* __restrict__ outp) {
  int idx = blockIdx.x * 256 + threadIdx.x;  // over 4*256*1024 f32x4 units
  int x4 = (idx & 1023) * 4;
  int c = (idx >> 10) & 255;
  int b = idx >> 18;
  f32x4 v = *(const f32x4*)&in[((size_t)(b * 256 + c) << 12) + x4];
  *(f32x4*)&outp[((size_t)(b * 896 + c) << 12) + x4] = v;
}

// ---------------- fp32 [R][Cc] -> bf16 [c][r] transpose (strided out) ----------------
__global__ __launch_bounds__(256) void trans_f32_bf16(
    const float* __restrict__ in, u16* __restrict__ outT, int R, int Cc, int OS,
    size_t in_bstride, size_t out_bstride) {
  int b = blockIdx.z;
  in += (size_t)b * in_bstride;
  outT += (size_t)b * out_bstride;
  int r0 = blockIdx.y * 32, c0 = blockIdx.x * 32;
  __shared__ float t[32][33];
  int tid = threadIdx.x;
  int cl = tid & 31, rl = tid >> 5;  // rl 0..7
  #pragma unroll
  for (int q = 0; q < 4; q++)
    t[rl + q * 8][cl] = in[(size_t)(r0 + rl + q * 8) * Cc + c0 + cl];
  __syncthreads();
  #pragma unroll
  for (int q = 0; q < 4; q++) {
    int c = c0 + rl + q * 8;
    outT[(size_t)c * OS + r0 + cl] = f2bf(t[cl][rl + q * 8]);
  }
}

// ---------------- gather A from transposed OT[b][p][C] (bf16), 8 ch/thread ----------------
template <int C, int Hin, int L>  // L = log2(C/8)
__global__ void gather_A(const u16* __restrict__ OT, u16* __restrict__ A,
                         int ch_off) {
  int idx = blockIdx.x * 256 + threadIdx.x;  // over B*4096*(C/8)
  int co = (idx & ((C / 8) - 1)) * 8;
  int hw = (idx >> L) & 4095;
  int b = idx >> (L + 12);
  int x = hw & 63, y = hw >> 6;
  int y0, y1, x0, x1; float wy, wx;
  bilin_coords<Hin>(y, y0, y1, wy);
  bilin_coords<Hin>(x, x0, x1, wx);
  float w00 = (1.0f - wy) * (1.0f - wx), w01 = (1.0f - wy) * wx;
  float w10 = wy * (1.0f - wx), w11 = wy * wx;
  const u16* base = OT + (size_t)b * (Hin * Hin) * C + co;
  bf16x8 t00 = *(const bf16x8*)&base[(y0 * Hin + x0) * C];
  bf16x8 t01 = *(const bf16x8*)&base[(y0 * Hin + x1) * C];
  bf16x8 t10 = *(const bf16x8*)&base[(y1 * Hin + x0) * C];
  bf16x8 t11 = *(const bf16x8*)&base[(y1 * Hin + x1) * C];
  bf16x8 o;
  #pragma unroll
  for (int e = 0; e < 8; e++) {
    float v = w00 * bf2f((u16)t00[e]) + w01 * bf2f((u16)t01[e]) +
              w10 * bf2f((u16)t10[e]) + w11 * bf2f((u16)t11[e]);
    o[e] = (short)f2bf(v);
  }
  *(bf16x8*)&A[((size_t)b * 4096 + hw) * 1792 + ch_off + co] = o;
}

// ---------------- row sum of squares over bf16 rows ----------------
__global__ __launch_bounds__(256) void rownorm2(const u16* __restrict__ X,
                                                float* __restrict__ out, int ncols) {
  int row = blockIdx.x * 4 + (threadIdx.x >> 6);
  int lane = threadIdx.x & 63;
  const u16* xr = X + (size_t)row * ncols;
  int n8 = ncols >> 3;
  float s = 0.0f;
  for (int c8 = lane; c8 < n8; c8 += 64) {
    bf16x8 v = *(const bf16x8*)&xr[c8 * 8];
    #pragma unroll
    for (int e = 0; e < 8; e++) {
      float f = bf2f((u16)v[e]);
      s = fmaf(f, f, s);
    }
  }
  #pragma unroll
  for (int off = 32; off; off >>= 1) s += __shfl_down(s, off);
  if (lane == 0) out[row] = s;
}

// ======== 256x256-tile deep-pipelined distance GEMM ========
#define GD_NT 56  // K/32

__device__ __forceinline__ void stage16k(const u16* __restrict__ G, int row0,
                                         int k0, char* lds_wavebase, int lane) {
  const int K = 1792;
  int sub = lane >> 2;                       // row within 16-row group
  int colsw = 8 * ((lane & 3) ^ (sub & 3));  // pre-swizzled source column
  #pragma unroll
  for (int q = 0; q < 2; q++) {
    gload_lds16(G + (size_t)(row0 + q * 128 + sub) * K + k0 + colsw,
                lds_wavebase + q * 8192);
  }
}

__global__ __launch_bounds__(512, 2) void gemm_dist2(
    const u16* __restrict__ A,   // [16384][1792]
    const u16* __restrict__ Bt,  // [4096][1792]
    const float* __restrict__ feats, const float* __restrict__ cents,
    float* __restrict__ S, int m_base) {
  const int K = 1792, N = 4096;
  extern __shared__ u16 lds[];  // 4 bufs x (A 8192 + B 8192) elems = 128 KiB
  int bid = blockIdx.x;
  int swz = (bid & 7) * 32 + (bid >> 3);
  int m0 = (swz >> 4) * 256;
  int n0 = (swz & 15) * 256;
  int tid = threadIdx.x;
  int wid = tid >> 6, lane = tid & 63;
  int wr = wid >> 2, wc = wid & 3;  // wave -> 128x64 output sub-tile
  int ln15 = lane & 15;
  int fo = 8 * ((lane >> 4) ^ (lane & 3));  // swizzled frag column offset

  f32x4 acc[8][4] = {};

  #pragma unroll
  for (int t = 0; t < 3; t++) {
    char* bufb = (char*)lds + (t & 3) * 32768 + wid * 1024;
    stage16k(A, m_base + m0 + wid * 16, t * 32, bufb, lane);
    stage16k(Bt, n0 + wid * 16, t * 32, bufb + 16384, lane);
  }

  #pragma unroll 1
  for (int t = 0; t < GD_NT; t++) {
    asm volatile("s_waitcnt vmcnt(8)" ::: "memory");
    __builtin_amdgcn_s_barrier();
    __builtin_amdgcn_sched_barrier(0);
    const u16* Ab = lds + (t & 3) * 16384;
    const u16* Bb = Ab + 8192;
    char* nbuf = (char*)lds + ((t + 3) & 3) * 32768 + wid * 1024;

    if (t + 3 < GD_NT) stage16k(A, m_base + m0 + wid * 16, (t + 3) * 32, nbuf, lane);
    bf16x8 bq[4];
    #pragma unroll
    for (int ni = 0; ni < 4; ni++)
      bq[ni] = *(const bf16x8*)&Bb[(wc * 64 + ni * 16 + ln15) * 32 + fo];
    {
      bf16x8 af[4];
      #pragma unroll
      for (int mi = 0; mi < 4; mi++)
        af[mi] = *(const bf16x8*)&Ab[(wr * 128 + mi * 16 + ln15) * 32 + fo];
      __builtin_amdgcn_s_setprio(1);
      #pragma unroll
      for (int mi = 0; mi < 4; mi++)
        #pragma unroll
        for (int ni = 0; ni < 4; ni++)
          acc[mi][ni] = __builtin_amdgcn_mfma_f32_16x16x32_bf16(af[mi], bq[ni], acc[mi][ni], 0, 0, 0);
      __builtin_amdgcn_s_setprio(0);
    }
    __builtin_amdgcn_s_barrier();

    if (t + 3 < GD_NT) stage16k(Bt, n0 + wid * 16, (t + 3) * 32, nbuf + 16384, lane);
    {
      bf16x8 af[4];
      #pragma unroll
      for (int mi = 0; mi < 4; mi++)
        af[mi] = *(const bf16x8*)&Ab[(wr * 128 + (mi + 4) * 16 + ln15) * 32 + fo];
      __builtin_amdgcn_s_setprio(1);
      #pragma unroll
      for (int mi = 0; mi < 4; mi++)
        #pragma unroll
        for (int ni = 0; ni < 4; ni++)
          acc[mi + 4][ni] = __builtin_amdgcn_mfma_f32_16x16x32_bf16(af[mi], bq[ni], acc[mi + 4][ni], 0, 0, 0);
      __builtin_amdgcn_s_setprio(0);
    }
  }

  int rq = lane >> 4, cq = lane & 15;
  #pragma unroll
  for (int mi = 0; mi < 8; mi++) {
    int lm = m0 + wr * 128 + mi * 16 + rq * 4;
    #pragma unroll
    for (int ni = 0; ni < 4; ni++) {
      int gn = n0 + wc * 64 + ni * 16 + cq;
      float cn = cents[gn];
      #pragma unroll
      for (int r = 0; r < 4; r++)
        S[(size_t)(lm + r) * N + gn] = feats[m_base + lm + r] + cn - 2.0f * acc[mi][ni][r];
    }
  }
}

// ---------------- per-row top-200 smallest (sorted) of 4096, emit sqrt ----------------
// wave-per-row; LDS only for the data-dependent scatter; sort done as a
// 256-element bitonic network in registers (4 vals/lane, shfl_xor cross-lane).
__global__ __launch_bounds__(256) void select_topk(const float* __restrict__ S,
                                                   float* __restrict__ out,
                                                   int row_base) {
  int wv = threadIdx.x >> 6, lane = threadIdx.x & 63;
  int row_local = blockIdx.x * 4 + wv;
  const float* Sr = S + (size_t)row_local * 4096;
  uint32_t ku[64];
  #pragma unroll
  for (int g = 0; g < 16; g++) {
    f32x4 v = *(const f32x4*)&Sr[g * 256 + lane * 4];
    #pragma unroll
    for (int e = 0; e < 4; e++) {
      uint32_t u = __float_as_uint(v[e]);
      u ^= (u & 0x80000000u) ? 0xFFFFFFFFu : 0x80000000u;  // order-preserving
      ku[g * 4 + e] = u;
    }
  }
  // wave min/max -> tight search bracket
  uint32_t mn = 0xFFFFFFFFu, mx = 0u;
  #pragma unroll
  for (int j = 0; j < 64; j++) {
    mn = min(mn, ku[j]);
    mx = max(mx, ku[j]);
  }
  #pragma unroll
  for (int off = 1; off < 64; off <<= 1) {
    mn = min(mn, (uint32_t)__shfl_xor((int)mn, off));
    mx = max(mx, (uint32_t)__shfl_xor((int)mx, off));
  }
  // binary search for the 200th smallest value T
  uint32_t lo = mn, hi = mx;
  while (lo < hi) {
    uint32_t mid = lo + ((hi - lo) >> 1);
    int c = 0;
    #pragma unroll
    for (int j = 0; j < 64; j++) c += (ku[j] <= mid) ? 1 : 0;
    #pragma unroll
    for (int off = 1; off < 64; off <<= 1) c += __shfl_xor(c, off);
    if (c >= 200) hi = mid; else lo = mid + 1;
  }
  uint32_t T = lo;
  // count-below + per-lane exclusive prefix
  int cl = 0;
  #pragma unroll
  for (int j = 0; j < 64; j++) cl += (ku[j] < T) ? 1 : 0;
  int incl = cl;
  #pragma unroll
  for (int off = 1; off < 64; off <<= 1) {
    int v = __shfl_up(incl, off);
    if (lane >= off) incl += v;
  }
  int nless = __shfl(incl, 63);  // < 200 by definition of T
  int pos = incl - cl;
  __shared__ uint32_t selv[4][256];
  uint32_t* sv = selv[wv];
  #pragma unroll
  for (int g = 0; g < 4; g++) sv[g * 64 + lane] = 0xFFFFFFFFu;
  // positions [nless,200) are exact copies of T
  for (int p = nless + lane; p < 200; p += 64) sv[p] = T;
  // scatter keys < T (wave-local LDS, in program order)
  #pragma unroll
  for (int j = 0; j < 64; j++)
    if (ku[j] < T) sv[pos++] = ku[j];
  // load candidates into registers: element i = q*64 + lane
  uint32_t v[4];
  #pragma unroll
  for (int q = 0; q < 4; q++) v[q] = sv[q * 64 + lane];
  // 256-element bitonic sort in registers
  #pragma unroll
  for (int kk = 2; kk <= 256; kk <<= 1) {
    #pragma unroll
    for (int jj = kk >> 1; jj > 0; jj >>= 1) {
      if (jj >= 64) {
        int qb = jj >> 6;  // 1 or 2
        #pragma unroll
        for (int q = 0; q < 4; q++) {
          if ((q & qb) == 0) {
            int q2 = q | qb;
            // up = ((i & kk) == 0), i = q*64+lane; kk>=128 here
            bool up = (kk == 256) ? true : ((q & (kk >> 6)) == 0);
            uint32_t a = v[q], b2 = v[q2];
            uint32_t lo2 = min(a, b2), hi2 = max(a, b2);
            v[q] = up ? lo2 : hi2;
            v[q2] = up ? hi2 : lo2;
          }
        }
      } else {
        #pragma unroll
        for (int q = 0; q < 4; q++) {
          bool up;
          if (kk == 256) up = true;
          else if (kk == 128) up = ((q & 2) == 0);
          else if (kk == 64) up = ((q & 1) == 0);
          else up = ((lane & kk) == 0);
          uint32_t other = (uint32_t)__shfl_xor((int)v[q], jj);
          bool lower = ((lane & jj) == 0);
          uint32_t lo2 = min(v[q], other), hi2 = max(v[q], other);
          v[q] = (up == lower) ? lo2 : hi2;
        }
      }
    }
  }
  int grow = row_base + row_local;
  int b = grow >> 12, r = grow & 4095;
  #pragma unroll
  for (int q = 0; q < 4; q++) {
    int i = q * 64 + lane;
    if (i < 200) {
      uint32_t u = v[q];
      u ^= (u & 0x80000000u) ? 0x80000000u : 0xFFFFFFFFu;
      out[((size_t)b * 200 + i) * 4096 + r] = sqrtf(__uint_as_float(u));
    }
  }
}

extern "C" void kernel_launch(void* const* d_in, const int* in_sizes, int n_in,
                              void* d_out, int out_size, void* d_ws, size_t ws_size,
                              hipStream_t stream) {
  const float* p0 = (const float*)d_in[0];   // (4,256,64,64)
  const float* p1 = (const float*)d_in[1];   // (4,512,32,32)
  const float* p2 = (const float*)d_in[2];   // (4,1024,16,16)
  const float* w1 = (const float*)d_in[5];   // (256,258)
  const float* b1 = (const float*)d_in[6];
  const float* w2 = (const float*)d_in[7];   // (512,514)
  const float* b2 = (const float*)d_in[8];
  const float* w3 = (const float*)d_in[9];   // (1024,1026)
  const float* b3 = (const float*)d_in[10];
  const float* Cm = (const float*)d_in[11];  // (1792,4096)

  float* out_score = (float*)d_out;                  // 4*200*4096 fp32
  float* out_phi = (float*)d_out + 3276800;          // 4*896*4096 fp32

  // workspace layout (peak 140,591,104 B — proven)
  char* w = (char*)d_ws;
  u16* Abf = (u16*)w;                                //  58,720,256 B
  u16* Ct = (u16*)(w + 58720256);                    //  14,680,064 B
  float* feats = (float*)(w + 73400320);             //      65,536 B
  float* cents = (float*)(w + 73465856);             //      16,384 B
  float* S = (float*)(w + 73482240);                 //  67,108,864 B (per-chunk) -> ends 140,591,104
  // stage-A temps alias the S region (dead before first gemm)
  float* O1 = (float*)(w + 73482240);                //  16,777,216 B
  float* O2 = (float*)(w + 90259456);                //   8,388,608 B
  float* O3 = (float*)(w + 98648064);                //   4,194,304 B
  float* pooled1 = (float*)(w + 102842368);          //  16,777,216 B (dead after PT1 trans)
  float* pooled2 = (float*)(w + 119619584);          //   8,388,608 B
  float* pooled3 = (float*)(w + 128008192);          //   4,194,304 B  -> ends 132,202,496
  // conv-GEMM operands (aliased):
  u16* PT1 = (u16*)(w + 132202496);                  //   8,388,608 B [4*4096][256] (dead before OT2 write)
  u16* PT2 = (u16*)(w + 102842368);                  //   4,194,304 B [4*1024][512] (in dead pooled1)
  u16* PT3 = (u16*)(w + 107036672);                  //   2,097,152 B [4*256][1024]
  u16* Wbf1 = (u16*)(w + 109133824);                 //     131,072 B
  u16* Wbf2 = (u16*)(w + 109264896);                 //     524,288 B
  u16* Wbf3 = (u16*)(w + 109789184);                 //   2,097,152 B -> ends 111,886,336
  u16* OT2 = (u16*)(w + 132202496);                  //   4,194,304 B  [4][1024][512]
  u16* OT3 = (u16*)(w + 136396800);                  //   2,097,152 B  [4][256][1024] -> ends 138,493,952

  // ---- stage A: pool (4 outputs/thread) ----
  pool3x3_v<64, 64><<<4096, 256, 0, stream>>>(p0, pooled1);
  pool3x3_v<32, 32><<<2048, 256, 0, stream>>>(p1, pooled2);
  pool3x3_v<16, 16><<<1024, 256, 0, stream>>>(p2, pooled3);

  // ---- conv operands: pooled -> PT (bf16 [n][k]); w -> Wb (bf16 [o][k]) ----
  trans_f32_bf16<<<dim3(128, 8, 4), 256, 0, stream>>>(
      pooled1, PT1, 256, 4096, 256, (size_t)256 * 4096, (size_t)4096 * 256);
  trans_f32_bf16<<<dim3(32, 16, 4), 256, 0, stream>>>(
      pooled2, PT2, 512, 1024, 512, (size_t)512 * 1024, (size_t)1024 * 512);
  trans_f32_bf16<<<dim3(8, 32, 4), 256, 0, stream>>>(
      pooled3, PT3, 1024, 256, 1024, (size_t)1024 * 256, (size_t)256 * 1024);
  wconv_bf16<<<32, 256, 0, stream>>>(w1, Wbf1, 8, 8192);
  wconv_bf16<<<128, 256, 0, stream>>>(w2, Wbf2, 9, 32768);
  wconv_bf16<<<512, 256, 0, stream>>>(w3, Wbf3, 10, 131072);

  // ---- stage A: coordconv 1x1 via MFMA GEMM ----
  conv_gemm<256, 4096, 64, 256><<<dim3(128, 2), 256, 0, stream>>>(Wbf1, PT1, w1, b1, O1);
  conv_gemm<512, 1024, 32, 512><<<dim3(32, 4), 256, 0, stream>>>(Wbf2, PT2, w2, b2, O2);
  conv_gemm<1024, 256, 16, 1024><<<dim3(8, 8), 256, 0, stream>>>(Wbf3, PT3, w3, b3, O3);

  // ---- output 1: PHI[:, :896] ----
  copy_phi1<<<4096, 256, 0, stream>>>(O1, out_phi);
  emit_phi_v<512, 512, 32><<<8192, 256, 0, stream>>>(O2, out_phi, 256);
  emit_phi_v<128, 1024, 16><<<2048, 256, 0, stream>>>(O3, out_phi, 768);

  // ---- A matrix: transpose-first, then coalesced gather ----
  trans_f32_bf16<<<dim3(128, 8, 4), 256, 0, stream>>>(
      O1, Abf, 256, 4096, 1792, (size_t)256 * 4096, (size_t)4096 * 1792);
  trans_f32_bf16<<<dim3(32, 16, 4), 256, 0, stream>>>(
      O2, OT2, 512, 1024, 512, (size_t)512 * 1024, (size_t)1024 * 512);
  trans_f32_bf16<<<dim3(8, 32, 4), 256, 0, stream>>>(
      O3, OT3, 1024, 256, 1024, (size_t)1024 * 256, (size_t)256 * 1024);
  gather_A<512, 32, 6><<<4096, 256, 0, stream>>>(OT2, Abf, 256);
  gather_A<1024, 16, 7><<<8192, 256, 0, stream>>>(OT3, Abf, 768);

  // ---- C transpose + bf16 ----
  trans_f32_bf16<<<dim3(128, 56, 1), 256, 0, stream>>>(Cm, Ct, 1792, 4096, 1792, 0, 0);

  // ---- norms ----
  rownorm2<<<4096, 256, 0, stream>>>(Abf, feats, 1792);
  rownorm2<<<1024, 256, 0, stream>>>(Ct, cents, 1792);

  // ---- distance GEMM (256^2 deep-pipelined) + top-200, chunked by batch image ----
  for (int mc = 0; mc < 4; mc++) {
    gemm_dist2<<<256, 512, 131072, stream>>>(Abf, Ct, feats, cents, S, mc * 4096);
    select_topk<<<1024, 256, 0, stream>>>(S, out_score, mc * 4096);
  }
}

// Round 9
// 567.738 us; speedup vs baseline: 1.9377x; 1.0442x over previous
//
#include <hip/hip_runtime.h>
#include <hip/hip_bf16.h>
#include <stdint.h>

typedef unsigned short u16;
typedef __attribute__((ext_vector_type(8))) short bf16x8;
typedef __attribute__((ext_vector_type(4))) unsigned short u16x4;
typedef __attribute__((ext_vector_type(4))) float f32x4;

#define AS1 __attribute__((address_space(1)))
#define AS3 __attribute__((address_space(3)))

__device__ __forceinline__ u16 f2bf(float f) {
  uint32_t x = __float_as_uint(f);
  uint32_t r = (x + 0x7FFFu + ((x >> 16) & 1u)) >> 16;
  return (u16)r;
}
__device__ __forceinline__ float bf2f(u16 u) {
  return __uint_as_float(((uint32_t)u) << 16);
}

__device__ __forceinline__ void gload_lds16(const void* g, void* l) {
  __builtin_amdgcn_global_load_lds((const AS1 void*)g, (AS3 void*)l, 16, 0, 0);
}

// ---- fused 3x3 avg pool + transpose + bf16: in[b][c][hw] -> PT[(b,hw)][C] ----
template <int C, int H, int W>
__global__ __launch_bounds__(256) void pool_trans(const float* __restrict__ in,
                                                  u16* __restrict__ PT) {
  constexpr int HW = H * W;
  int hwt = blockIdx.x, ct = blockIdx.y, b = blockIdx.z;
  int tid = threadIdx.x;
  __shared__ float t[32][33];
  {
    int c_l = tid >> 3;          // 0..31
    int hw_l = (tid & 7) * 4;    // 0,4,...,28
    int c = ct * 32 + c_l;
    int hw = hwt * 32 + hw_l;
    int y = hw / W;
    int x0 = hw % W;
    const float* pl = in + ((size_t)b * C + c) * HW;
    float cs[6] = {0, 0, 0, 0, 0, 0};
    #pragma unroll
    for (int dy = -1; dy <= 1; dy++) {
      int yy = y + dy;
      if ((unsigned)yy < (unsigned)H) {
        const float* row = pl + yy * W;
        #pragma unroll
        for (int k = 0; k < 6; k++) {
          int xx = x0 - 1 + k;
          if ((unsigned)xx < (unsigned)W) cs[k] += row[xx];
        }
      }
    }
    #pragma unroll
    for (int k = 0; k < 4; k++)
      t[c_l][hw_l + k] = (cs[k] + cs[k + 1] + cs[k + 2]) * (1.0f / 9.0f);
  }
  __syncthreads();
  int hw_w = tid >> 3;           // 0..31
  int c_w = (tid & 7) * 4;       // 0,4,...,28
  u16x4 o;
  #pragma unroll
  for (int j = 0; j < 4; j++) o[j] = f2bf(t[c_w + j][hw_w]);
  *(u16x4*)&PT[((size_t)b * HW + hwt * 32 + hw_w) * C + ct * 32 + c_w] = o;
}

// ---------------- w[O][K+2] fp32 -> Wb[O][K] bf16 ----------------
__global__ void wconv_bf16(const float* __restrict__ wf, u16* __restrict__ wb,
                           int logk, int total) {
  int idx = blockIdx.x * 256 + threadIdx.x;
  if (idx >= total) return;
  int K = 1 << logk;
  int o = idx >> (logk - 3);
  int k0 = (idx & ((K >> 3) - 1)) * 8;
  const float* src = wf + (size_t)o * (K + 2) + k0;
  bf16x8 v;
  #pragma unroll
  for (int e = 0; e < 8; e++) v[e] = (short)f2bf(src[e]);
  *(bf16x8*)&wb[(size_t)o * K + k0] = v;
}

// ======== MFMA CoordConv GEMM, dual-layout epilogue ========
// outHW[(b)*outHW_bstride + o*HW + hw] fp32 for o < PHIC
// outCM[((b*HW)+hw)*CST + o]           bf16 for all o
template <int K, int HW, int WD, int OC, int PHIC, int CST>
__global__ __launch_bounds__(256) void conv_gemm(
    const u16* __restrict__ Wb,   // [OC][K] bf16
    const u16* __restrict__ PT,   // [4*HW][K] bf16
    const float* __restrict__ wf, // [OC][K+2] fp32 (coord cols)
    const float* __restrict__ bias,
    float* __restrict__ outHW, size_t outHW_bstride,
    u16* __restrict__ outCM) {
  constexpr int LOGW = (WD == 64) ? 6 : (WD == 32) ? 5 : 4;
  constexpr int LOGHW = 2 * LOGW;
  int n0 = blockIdx.x * 128, m0 = blockIdx.y * 128;
  int tid = threadIdx.x;
  int wid = tid >> 6, lane = tid & 63;
  int wm = wid >> 1, wn = wid & 1;
  __shared__ u16 As[128 * 64];
  __shared__ u16 Bs[128 * 64];
  f32x4 acc[4][4] = {};
  int lrow = tid >> 3;           // 0..31
  int lcol = (tid & 7) * 8;
  const u16* ga = Wb + (size_t)(m0 + lrow) * K + lcol;
  const u16* gb = PT + (size_t)(n0 + lrow) * K + lcol;
  char* lbaseA = (char*)As + wid * 1024;
  char* lbaseB = (char*)Bs + wid * 1024;
  for (int k0 = 0; k0 < K; k0 += 64) {
    #pragma unroll
    for (int q = 0; q < 4; q++) {
      gload_lds16(ga + (size_t)q * 32 * K + k0, lbaseA + q * 4096);
      gload_lds16(gb + (size_t)q * 32 * K + k0, lbaseB + q * 4096);
    }
    __syncthreads();
    #pragma unroll
    for (int kk = 0; kk < 2; kk++) {
      bf16x8 af[4], bfr[4];
      int kb = kk * 32 + (lane >> 4) * 8;
      #pragma unroll
      for (int i = 0; i < 4; i++)
        af[i] = *(const bf16x8*)&As[(wm * 64 + i * 16 + (lane & 15)) * 64 + kb];
      #pragma unroll
      for (int j = 0; j < 4; j++)
        bfr[j] = *(const bf16x8*)&Bs[(wn * 64 + j * 16 + (lane & 15)) * 64 + kb];
      #pragma unroll
      for (int i = 0; i < 4; i++)
        #pragma unroll
        for (int j = 0; j < 4; j++)
          acc[i][j] = __builtin_amdgcn_mfma_f32_16x16x32_bf16(af[i], bfr[j], acc[i][j], 0, 0, 0);
    }
    __syncthreads();
  }
  int rq = lane >> 4, cq = lane & 15;
  #pragma unroll
  for (int mi = 0; mi < 4; mi++) {
    int lm = m0 + wm * 64 + mi * 16 + rq * 4;
    float wxr[4], wyr[4], bbr[4];
    #pragma unroll
    for (int r = 0; r < 4; r++) {
      int o = lm + r;
      wxr[r] = wf[(size_t)o * (K + 2) + K];
      wyr[r] = wf[(size_t)o * (K + 2) + K + 1];
      bbr[r] = bias[o];
    }
    #pragma unroll
    for (int ni = 0; ni < 4; ni++) {
      int gn = n0 + wn * 64 + ni * 16 + cq;
      int b = gn >> LOGHW;
      int hw = gn & (HW - 1);
      int x = hw & (WD - 1), y = hw >> LOGW;
      float xg = -1.0f + x * (2.0f / (WD - 1));
      float yg = -1.0f + y * (2.0f / (WD - 1));
      float vals[4];
      #pragma unroll
      for (int r = 0; r < 4; r++)
        vals[r] = acc[mi][ni][r] + wxr[r] * xg + wyr[r] * yg + bbr[r];
      if (lm < PHIC) {
        #pragma unroll
        for (int r = 0; r < 4; r++)
          outHW[(size_t)b * outHW_bstride + (size_t)(lm + r) * HW + hw] = vals[r];
      }
      u16x4 pk;
      #pragma unroll
      for (int r = 0; r < 4; r++) pk[r] = f2bf(vals[r]);
      *(u16x4*)&outCM[((size_t)b * HW + hw) * CST + lm] = pk;
    }
  }
}

// bilinear helpers (half-pixel, edge clamp)
template <int Hin>
__device__ __forceinline__ void bilin_coords(int v, int& i0, int& i1, float& wgt) {
  constexpr float scale = (float)Hin / 64.0f;
  float f = ((float)v + 0.5f) * scale - 0.5f;
  float f0 = floorf(f);
  wgt = f - f0;
  int i = (int)f0;
  i1 = min(i + 1, Hin - 1);
  i0 = max(i, 0);
}

// ---------------- emit out_phi (fp32, hw fastest) — 4 px/thread ----------------
template <int C, int Cin, int Hin>
__global__ void emit_phi_v(const float* __restrict__ in, float* __restrict__ outp,
                           int ch_off) {
  int idx = blockIdx.x * 256 + threadIdx.x;  // over B*C*1024
  int x0 = (idx & 15) * 4;
  int y = (idx >> 4) & 63;
  int c = (idx >> 10) % C;
  int b = idx / (C * 1024);
  const float* pl = in + (size_t)(b * Cin + c) * (Hin * Hin);
  int y0, y1; float wy;
  bilin_coords<Hin>(y, y0, y1, wy);
  const float* r0 = pl + y0 * Hin;
  const float* r1 = pl + y1 * Hin;
  f32x4 o;
  #pragma unroll
  for (int k = 0; k < 4; k++) {
    int xx0, xx1; float wx;
    bilin_coords<Hin>(x0 + k, xx0, xx1, wx);
    float top = (1.0f - wx) * r0[xx0] + wx * r0[xx1];
    float bot = (1.0f - wx) * r1[xx0] + wx * r1[xx1];
    o[k] = (1.0f - wy) * top + wy * bot;
  }
  *(f32x4*)&outp[((size_t)b * 896 + ch_off + c) * 4096 + (y << 6) + x0] = o;
}

// ---------------- fp32 [R][Cc] -> bf16 [c][r] transpose (strided out) ----------------
__global__ __launch_bounds__(256) void trans_f32_bf16(
    const float* __restrict__ in, u16* __restrict__ outT, int R, int Cc, int OS,
    size_t in_bstride, size_t out_bstride) {
  int b = blockIdx.z;
  in += (size_t)b * in_bstride;
  outT += (size_t)b * out_bstride;
  int r0 = blockIdx.y * 32, c0 = blockIdx.x * 32;
  __shared__ float t[32][33];
  int tid = threadIdx.x;
  int cl = tid & 31, rl = tid >> 5;  // rl 0..7
  #pragma unroll
  for (int q = 0; q < 4; q++)
    t[rl + q * 8][cl] = in[(size_t)(r0 + rl + q * 8) * Cc + c0 + cl];
  __syncthreads();
  #pragma unroll
  for (int q = 0; q < 4; q++) {
    int c = c0 + rl + q * 8;
    outT[(size_t)c * OS + r0 + cl] = f2bf(t[cl][rl + q * 8]);
  }
}

// ---------------- gather A from transposed OT[b][p][C] (bf16), 8 ch/thread ----------------
template <int C, int Hin, int L>  // L = log2(C/8)
__global__ void gather_A(const u16* __restrict__ OT, u16* __restrict__ A,
                         int ch_off) {
  int idx = blockIdx.x * 256 + threadIdx.x;  // over B*4096*(C/8)
  int co = (idx & ((C / 8) - 1)) * 8;
  int hw = (idx >> L) & 4095;
  int b = idx >> (L + 12);
  int x = hw & 63, y = hw >> 6;
  int y0, y1, x0, x1; float wy, wx;
  bilin_coords<Hin>(y, y0, y1, wy);
  bilin_coords<Hin>(x, x0, x1, wx);
  float w00 = (1.0f - wy) * (1.0f - wx), w01 = (1.0f - wy) * wx;
  float w10 = wy * (1.0f - wx), w11 = wy * wx;
  const u16* base = OT + (size_t)b * (Hin * Hin) * C + co;
  bf16x8 t00 = *(const bf16x8*)&base[(y0 * Hin + x0) * C];
  bf16x8 t01 = *(const bf16x8*)&base[(y0 * Hin + x1) * C];
  bf16x8 t10 = *(const bf16x8*)&base[(y1 * Hin + x0) * C];
  bf16x8 t11 = *(const bf16x8*)&base[(y1 * Hin + x1) * C];
  bf16x8 o;
  #pragma unroll
  for (int e = 0; e < 8; e++) {
    float v = w00 * bf2f((u16)t00[e]) + w01 * bf2f((u16)t01[e]) +
              w10 * bf2f((u16)t10[e]) + w11 * bf2f((u16)t11[e]);
    o[e] = (short)f2bf(v);
  }
  *(bf16x8*)&A[((size_t)b * 4096 + hw) * 1792 + ch_off + co] = o;
}

// ---------------- row sum of squares over bf16 rows ----------------
__global__ __launch_bounds__(256) void rownorm2(const u16* __restrict__ X,
                                                float* __restrict__ out, int ncols) {
  int row = blockIdx.x * 4 + (threadIdx.x >> 6);
  int lane = threadIdx.x & 63;
  const u16* xr = X + (size_t)row * ncols;
  int n8 = ncols >> 3;
  float s = 0.0f;
  for (int c8 = lane; c8 < n8; c8 += 64) {
    bf16x8 v = *(const bf16x8*)&xr[c8 * 8];
    #pragma unroll
    for (int e = 0; e < 8; e++) {
      float f = bf2f((u16)v[e]);
      s = fmaf(f, f, s);
    }
  }
  #pragma unroll
  for (int off = 32; off; off >>= 1) s += __shfl_down(s, off);
  if (lane == 0) out[row] = s;
}

// ======== 256x256-tile deep-pipelined distance GEMM ========
#define GD_NT 56  // K/32

__device__ __forceinline__ void stage16k(const u16* __restrict__ G, int row0,
                                         int k0, char* lds_wavebase, int lane) {
  const int K = 1792;
  int sub = lane >> 2;                       // row within 16-row group
  int colsw = 8 * ((lane & 3) ^ (sub & 3));  // pre-swizzled source column
  #pragma unroll
  for (int q = 0; q < 2; q++) {
    gload_lds16(G + (size_t)(row0 + q * 128 + sub) * K + k0 + colsw,
                lds_wavebase + q * 8192);
  }
}

__global__ __launch_bounds__(512, 2) void gemm_dist2(
    const u16* __restrict__ A,   // [16384][1792]
    const u16* __restrict__ Bt,  // [4096][1792]
    const float* __restrict__ feats, const float* __restrict__ cents,
    float* __restrict__ S, int m_base) {
  const int K = 1792, N = 4096;
  extern __shared__ u16 lds[];  // 4 bufs x (A 8192 + B 8192) elems = 128 KiB
  int bid = blockIdx.x;
  int swz = (bid & 7) * 32 + (bid >> 3);
  int m0 = (swz >> 4) * 256;
  int n0 = (swz & 15) * 256;
  int tid = threadIdx.x;
  int wid = tid >> 6, lane = tid & 63;
  int wr = wid >> 2, wc = wid & 3;  // wave -> 128x64 output sub-tile
  int ln15 = lane & 15;
  int fo = 8 * ((lane >> 4) ^ (lane & 3));  // swizzled frag column offset

  f32x4 acc[8][4] = {};

  #pragma unroll
  for (int t = 0; t < 3; t++) {
    char* bufb = (char*)lds + (t & 3) * 32768 + wid * 1024;
    stage16k(A, m_base + m0 + wid * 16, t * 32, bufb, lane);
    stage16k(Bt, n0 + wid * 16, t * 32, bufb + 16384, lane);
  }

  #pragma unroll 1
  for (int t = 0; t < GD_NT; t++) {
    asm volatile("s_waitcnt vmcnt(8)" ::: "memory");
    __builtin_amdgcn_s_barrier();
    __builtin_amdgcn_sched_barrier(0);
    const u16* Ab = lds + (t & 3) * 16384;
    const u16* Bb = Ab + 8192;
    char* nbuf = (char*)lds + ((t + 3) & 3) * 32768 + wid * 1024;

    if (t + 3 < GD_NT) stage16k(A, m_base + m0 + wid * 16, (t + 3) * 32, nbuf, lane);
    bf16x8 bq[4];
    #pragma unroll
    for (int ni = 0; ni < 4; ni++)
      bq[ni] = *(const bf16x8*)&Bb[(wc * 64 + ni * 16 + ln15) * 32 + fo];
    {
      bf16x8 af[4];
      #pragma unroll
      for (int mi = 0; mi < 4; mi++)
        af[mi] = *(const bf16x8*)&Ab[(wr * 128 + mi * 16 + ln15) * 32 + fo];
      __builtin_amdgcn_s_setprio(1);
      #pragma unroll
      for (int mi = 0; mi < 4; mi++)
        #pragma unroll
        for (int ni = 0; ni < 4; ni++)
          acc[mi][ni] = __builtin_amdgcn_mfma_f32_16x16x32_bf16(af[mi], bq[ni], acc[mi][ni], 0, 0, 0);
      __builtin_amdgcn_s_setprio(0);
    }
    __builtin_amdgcn_s_barrier();

    if (t + 3 < GD_NT) stage16k(Bt, n0 + wid * 16, (t + 3) * 32, nbuf + 16384, lane);
    {
      bf16x8 af[4];
      #pragma unroll
      for (int mi = 0; mi < 4; mi++)
        af[mi] = *(const bf16x8*)&Ab[(wr * 128 + (mi + 4) * 16 + ln15) * 32 + fo];
      __builtin_amdgcn_s_setprio(1);
      #pragma unroll
      for (int mi = 0; mi < 4; mi++)
        #pragma unroll
        for (int ni = 0; ni < 4; ni++)
          acc[mi + 4][ni] = __builtin_amdgcn_mfma_f32_16x16x32_bf16(af[mi], bq[ni], acc[mi + 4][ni], 0, 0, 0);
      __builtin_amdgcn_s_setprio(0);
    }
  }

  int rq = lane >> 4, cq = lane & 15;
  #pragma unroll
  for (int mi = 0; mi < 8; mi++) {
    int lm = m0 + wr * 128 + mi * 16 + rq * 4;
    #pragma unroll
    for (int ni = 0; ni < 4; ni++) {
      int gn = n0 + wc * 64 + ni * 16 + cq;
      float cn = cents[gn];
      #pragma unroll
      for (int r = 0; r < 4; r++)
        S[(size_t)(lm + r) * N + gn] = feats[m_base + lm + r] + cn - 2.0f * acc[mi][ni][r];
    }
  }
}

// ---------------- per-row top-200 smallest (sorted) of 4096, emit sqrt ----------------
__global__ __launch_bounds__(256) void select_topk(const float* __restrict__ S,
                                                   float* __restrict__ out,
                                                   int row_base) {
  int wv = threadIdx.x >> 6, lane = threadIdx.x & 63;
  int row_local = blockIdx.x * 4 + wv;
  const float* Sr = S + (size_t)row_local * 4096;
  uint32_t ku[64];
  #pragma unroll
  for (int g = 0; g < 16; g++) {
    f32x4 v = *(const f32x4*)&Sr[g * 256 + lane * 4];
    #pragma unroll
    for (int e = 0; e < 4; e++) {
      uint32_t u = __float_as_uint(v[e]);
      u ^= (u & 0x80000000u) ? 0xFFFFFFFFu : 0x80000000u;  // order-preserving
      ku[g * 4 + e] = u;
    }
  }
  uint32_t mn = 0xFFFFFFFFu, mx = 0u;
  #pragma unroll
  for (int j = 0; j < 64; j++) {
    mn = min(mn, ku[j]);
    mx = max(mx, ku[j]);
  }
  #pragma unroll
  for (int off = 1; off < 64; off <<= 1) {
    mn = min(mn, (uint32_t)__shfl_xor((int)mn, off));
    mx = max(mx, (uint32_t)__shfl_xor((int)mx, off));
  }
  uint32_t lo = mn, hi = mx;
  while (lo < hi) {
    uint32_t mid = lo + ((hi - lo) >> 1);
    int c = 0;
    #pragma unroll
    for (int j = 0; j < 64; j++) c += (ku[j] <= mid) ? 1 : 0;
    #pragma unroll
    for (int off = 1; off < 64; off <<= 1) c += __shfl_xor(c, off);
    if (c >= 200) hi = mid; else lo = mid + 1;
  }
  uint32_t T = lo;
  int cl = 0;
  #pragma unroll
  for (int j = 0; j < 64; j++) cl += (ku[j] < T) ? 1 : 0;
  int incl = cl;
  #pragma unroll
  for (int off = 1; off < 64; off <<= 1) {
    int v = __shfl_up(incl, off);
    if (lane >= off) incl += v;
  }
  int nless = __shfl(incl, 63);
  int pos = incl - cl;
  __shared__ uint32_t selv[4][256];
  uint32_t* sv = selv[wv];
  #pragma unroll
  for (int g = 0; g < 4; g++) sv[g * 64 + lane] = 0xFFFFFFFFu;
  for (int p = nless + lane; p < 200; p += 64) sv[p] = T;
  #pragma unroll
  for (int j = 0; j < 64; j++)
    if (ku[j] < T) sv[pos++] = ku[j];
  uint32_t v[4];
  #pragma unroll
  for (int q = 0; q < 4; q++) v[q] = sv[q * 64 + lane];
  #pragma unroll
  for (int kk = 2; kk <= 256; kk <<= 1) {
    #pragma unroll
    for (int jj = kk >> 1; jj > 0; jj >>= 1) {
      if (jj >= 64) {
        int qb = jj >> 6;
        #pragma unroll
        for (int q = 0; q < 4; q++) {
          if ((q & qb) == 0) {
            int q2 = q | qb;
            bool up = (kk == 256) ? true : ((q & (kk >> 6)) == 0);
            uint32_t a = v[q], b2 = v[q2];
            uint32_t lo2 = min(a, b2), hi2 = max(a, b2);
            v[q] = up ? lo2 : hi2;
            v[q2] = up ? hi2 : lo2;
          }
        }
      } else {
        #pragma unroll
        for (int q = 0; q < 4; q++) {
          bool up;
          if (kk == 256) up = true;
          else if (kk == 128) up = ((q & 2) == 0);
          else if (kk == 64) up = ((q & 1) == 0);
          else up = ((lane & kk) == 0);
          uint32_t other = (uint32_t)__shfl_xor((int)v[q], jj);
          bool lower = ((lane & jj) == 0);
          uint32_t lo2 = min(v[q], other), hi2 = max(v[q], other);
          v[q] = (up == lower) ? lo2 : hi2;
        }
      }
    }
  }
  int grow = row_base + row_local;
  int b = grow >> 12, r = grow & 4095;
  #pragma unroll
  for (int q = 0; q < 4; q++) {
    int i = q * 64 + lane;
    if (i < 200) {
      uint32_t u = v[q];
      u ^= (u & 0x80000000u) ? 0x80000000u : 0xFFFFFFFFu;
      out[((size_t)b * 200 + i) * 4096 + r] = sqrtf(__uint_as_float(u));
    }
  }
}

extern "C" void kernel_launch(void* const* d_in, const int* in_sizes, int n_in,
                              void* d_out, int out_size, void* d_ws, size_t ws_size,
                              hipStream_t stream) {
  const float* p0 = (const float*)d_in[0];   // (4,256,64,64)
  const float* p1 = (const float*)d_in[1];   // (4,512,32,32)
  const float* p2 = (const float*)d_in[2];   // (4,1024,16,16)
  const float* w1 = (const float*)d_in[5];   // (256,258)
  const float* b1 = (const float*)d_in[6];
  const float* w2 = (const float*)d_in[7];   // (512,514)
  const float* b2 = (const float*)d_in[8];
  const float* w3 = (const float*)d_in[9];   // (1024,1026)
  const float* b3 = (const float*)d_in[10];
  const float* Cm = (const float*)d_in[11];  // (1792,4096)

  float* out_score = (float*)d_out;                  // 4*200*4096 fp32
  float* out_phi = (float*)d_out + 3276800;          // 4*896*4096 fp32

  // workspace layout (peak 140,591,104 B — proven)
  char* w = (char*)d_ws;
  u16* Abf = (u16*)w;                                //  58,720,256 B
  u16* Ct = (u16*)(w + 58720256);                    //  14,680,064 B
  float* feats = (float*)(w + 73400320);             //      65,536 B
  float* cents = (float*)(w + 73465856);             //      16,384 B
  float* S = (float*)(w + 73482240);                 //  67,108,864 B (per-chunk) -> ends 140,591,104
  // stage-A temps all alias the S region (dead before first gemm_dist2):
  u16* PT1 = (u16*)(w + 73482240);                   //   8,388,608 B [16384][256]
  u16* PT2 = (u16*)(w + 81870848);                   //   4,194,304 B [4096][512]
  u16* PT3 = (u16*)(w + 86065152);                   //   2,097,152 B [1024][1024]
  u16* Wbf1 = (u16*)(w + 88162304);                  //     131,072 B
  u16* Wbf2 = (u16*)(w + 88293376);                  //     524,288 B
  u16* Wbf3 = (u16*)(w + 88817664);                  //   2,097,152 B
  float* O2 = (float*)(w + 90914816);                //   8,388,608 B [4][512][1024]
  float* O3 = (float*)(w + 99303424);                //     524,288 B [4][128][256]
  u16* OT2 = (u16*)(w + 99827712);                   //   4,194,304 B [4][1024][512]
  u16* OT3 = (u16*)(w + 104022016);                  //   2,097,152 B [4][256][1024] -> ends 106,119,168

  // ---- fused pool + transpose + bf16 -> PT ----
  pool_trans<256, 64, 64><<<dim3(128, 8, 4), 256, 0, stream>>>(p0, PT1);
  pool_trans<512, 32, 32><<<dim3(32, 16, 4), 256, 0, stream>>>(p1, PT2);
  pool_trans<1024, 16, 16><<<dim3(8, 32, 4), 256, 0, stream>>>(p2, PT3);

  // ---- weights -> bf16 ----
  wconv_bf16<<<32, 256, 0, stream>>>(w1, Wbf1, 8, 8192);
  wconv_bf16<<<128, 256, 0, stream>>>(w2, Wbf2, 9, 32768);
  wconv_bf16<<<512, 256, 0, stream>>>(w3, Wbf3, 10, 131072);

  // ---- coordconv via MFMA GEMM, dual-layout epilogue ----
  // L1: fp32 -> out_phi[:, 0:256];  bf16 c-major -> Abf cols [0,256)
  conv_gemm<256, 4096, 64, 256, 256, 1792><<<dim3(128, 2), 256, 0, stream>>>(
      Wbf1, PT1, w1, b1, out_phi, (size_t)896 * 4096, Abf);
  // L2: fp32 -> O2 (for emit_phi); bf16 -> OT2 (for gather)
  conv_gemm<512, 1024, 32, 512, 512, 512><<<dim3(32, 4), 256, 0, stream>>>(
      Wbf2, PT2, w2, b2, O2, (size_t)512 * 1024, OT2);
  // L3: fp32 -> O3 first 128 ch only; bf16 -> OT3 (all 1024)
  conv_gemm<1024, 256, 16, 1024, 128, 1024><<<dim3(8, 8), 256, 0, stream>>>(
      Wbf3, PT3, w3, b3, O3, (size_t)128 * 256, OT3);

  // ---- out_phi levels 2,3 (bilinear resize) ----
  emit_phi_v<512, 512, 32><<<8192, 256, 0, stream>>>(O2, out_phi, 256);
  emit_phi_v<128, 128, 16><<<2048, 256, 0, stream>>>(O3, out_phi, 768);

  // ---- A matrix cols [256,1792): coalesced gather from OT ----
  gather_A<512, 32, 6><<<4096, 256, 0, stream>>>(OT2, Abf, 256);
  gather_A<1024, 16, 7><<<8192, 256, 0, stream>>>(OT3, Abf, 768);

  // ---- C transpose + bf16 ----
  trans_f32_bf16<<<dim3(128, 56, 1), 256, 0, stream>>>(Cm, Ct, 1792, 4096, 1792, 0, 0);

  // ---- norms ----
  rownorm2<<<4096, 256, 0, stream>>>(Abf, feats, 1792);
  rownorm2<<<1024, 256, 0, stream>>>(Ct, cents, 1792);

  // ---- distance GEMM (256^2 deep-pipelined) + top-200, chunked by batch image ----
  for (int mc = 0; mc < 4; mc++) {
    gemm_dist2<<<256, 512, 131072, stream>>>(Abf, Ct, feats, cents, S, mc * 4096);
    select_topk<<<1024, 256, 0, stream>>>(S, out_score, mc * 4096);
  }
}

// Round 10
// 558.918 us; speedup vs baseline: 1.9682x; 1.0158x over previous
//
#include <hip/hip_runtime.h>
#include <hip/hip_bf16.h>
#include <stdint.h>

typedef unsigned short u16;
typedef __attribute__((ext_vector_type(8))) short bf16x8;
typedef __attribute__((ext_vector_type(4))) unsigned short u16x4;
typedef __attribute__((ext_vector_type(4))) float f32x4;

#define AS1 __attribute__((address_space(1)))
#define AS3 __attribute__((address_space(3)))

__device__ __forceinline__ u16 f2bf(float f) {
  uint32_t x = __float_as_uint(f);
  uint32_t r = (x + 0x7FFFu + ((x >> 16) & 1u)) >> 16;
  return (u16)r;
}
__device__ __forceinline__ float bf2f(u16 u) {
  return __uint_as_float(((uint32_t)u) << 16);
}

__device__ __forceinline__ void gload_lds16(const void* g, void* l) {
  __builtin_amdgcn_global_load_lds((const AS1 void*)g, (AS3 void*)l, 16, 0, 0);
}

// ---- fused 3x3 avg pool + transpose + bf16: in[b][c][hw] -> PT[(b,hw)][C] ----
template <int C, int H, int W>
__global__ __launch_bounds__(256) void pool_trans(const float* __restrict__ in,
                                                  u16* __restrict__ PT) {
  constexpr int HW = H * W;
  int hwt = blockIdx.x, ct = blockIdx.y, b = blockIdx.z;
  int tid = threadIdx.x;
  __shared__ float t[32][33];
  {
    int c_l = tid >> 3;          // 0..31
    int hw_l = (tid & 7) * 4;    // 0,4,...,28
    int c = ct * 32 + c_l;
    int hw = hwt * 32 + hw_l;
    int y = hw / W;
    int x0 = hw % W;
    const float* pl = in + ((size_t)b * C + c) * HW;
    float cs[6] = {0, 0, 0, 0, 0, 0};
    #pragma unroll
    for (int dy = -1; dy <= 1; dy++) {
      int yy = y + dy;
      if ((unsigned)yy < (unsigned)H) {
        const float* row = pl + yy * W;
        #pragma unroll
        for (int k = 0; k < 6; k++) {
          int xx = x0 - 1 + k;
          if ((unsigned)xx < (unsigned)W) cs[k] += row[xx];
        }
      }
    }
    #pragma unroll
    for (int k = 0; k < 4; k++)
      t[c_l][hw_l + k] = (cs[k] + cs[k + 1] + cs[k + 2]) * (1.0f / 9.0f);
  }
  __syncthreads();
  int hw_w = tid >> 3;           // 0..31
  int c_w = (tid & 7) * 4;       // 0,4,...,28
  u16x4 o;
  #pragma unroll
  for (int j = 0; j < 4; j++) o[j] = f2bf(t[c_w + j][hw_w]);
  *(u16x4*)&PT[((size_t)b * HW + hwt * 32 + hw_w) * C + ct * 32 + c_w] = o;
}

// ---------------- w[O][K+2] fp32 -> Wb[O][K] bf16 ----------------
__global__ void wconv_bf16(const float* __restrict__ wf, u16* __restrict__ wb,
                           int logk, int total) {
  int idx = blockIdx.x * 256 + threadIdx.x;
  if (idx >= total) return;
  int K = 1 << logk;
  int o = idx >> (logk - 3);
  int k0 = (idx & ((K >> 3) - 1)) * 8;
  const float* src = wf + (size_t)o * (K + 2) + k0;
  bf16x8 v;
  #pragma unroll
  for (int e = 0; e < 8; e++) v[e] = (short)f2bf(src[e]);
  *(bf16x8*)&wb[(size_t)o * K + k0] = v;
}

// ======== MFMA CoordConv GEMM, dual-layout epilogue ========
template <int K, int HW, int WD, int OC, int PHIC, int CST>
__global__ __launch_bounds__(256) void conv_gemm(
    const u16* __restrict__ Wb,   // [OC][K] bf16
    const u16* __restrict__ PT,   // [4*HW][K] bf16
    const float* __restrict__ wf, // [OC][K+2] fp32 (coord cols)
    const float* __restrict__ bias,
    float* __restrict__ outHW, size_t outHW_bstride,
    u16* __restrict__ outCM) {
  constexpr int LOGW = (WD == 64) ? 6 : (WD == 32) ? 5 : 4;
  constexpr int LOGHW = 2 * LOGW;
  int n0 = blockIdx.x * 128, m0 = blockIdx.y * 128;
  int tid = threadIdx.x;
  int wid = tid >> 6, lane = tid & 63;
  int wm = wid >> 1, wn = wid & 1;
  __shared__ u16 As[128 * 64];
  __shared__ u16 Bs[128 * 64];
  f32x4 acc[4][4] = {};
  int lrow = tid >> 3;           // 0..31
  int lcol = (tid & 7) * 8;
  const u16* ga = Wb + (size_t)(m0 + lrow) * K + lcol;
  const u16* gb = PT + (size_t)(n0 + lrow) * K + lcol;
  char* lbaseA = (char*)As + wid * 1024;
  char* lbaseB = (char*)Bs + wid * 1024;
  for (int k0 = 0; k0 < K; k0 += 64) {
    #pragma unroll
    for (int q = 0; q < 4; q++) {
      gload_lds16(ga + (size_t)q * 32 * K + k0, lbaseA + q * 4096);
      gload_lds16(gb + (size_t)q * 32 * K + k0, lbaseB + q * 4096);
    }
    __syncthreads();
    #pragma unroll
    for (int kk = 0; kk < 2; kk++) {
      bf16x8 af[4], bfr[4];
      int kb = kk * 32 + (lane >> 4) * 8;
      #pragma unroll
      for (int i = 0; i < 4; i++)
        af[i] = *(const bf16x8*)&As[(wm * 64 + i * 16 + (lane & 15)) * 64 + kb];
      #pragma unroll
      for (int j = 0; j < 4; j++)
        bfr[j] = *(const bf16x8*)&Bs[(wn * 64 + j * 16 + (lane & 15)) * 64 + kb];
      #pragma unroll
      for (int i = 0; i < 4; i++)
        #pragma unroll
        for (int j = 0; j < 4; j++)
          acc[i][j] = __builtin_amdgcn_mfma_f32_16x16x32_bf16(af[i], bfr[j], acc[i][j], 0, 0, 0);
    }
    __syncthreads();
  }
  int rq = lane >> 4, cq = lane & 15;
  #pragma unroll
  for (int mi = 0; mi < 4; mi++) {
    int lm = m0 + wm * 64 + mi * 16 + rq * 4;
    float wxr[4], wyr[4], bbr[4];
    #pragma unroll
    for (int r = 0; r < 4; r++) {
      int o = lm + r;
      wxr[r] = wf[(size_t)o * (K + 2) + K];
      wyr[r] = wf[(size_t)o * (K + 2) + K + 1];
      bbr[r] = bias[o];
    }
    #pragma unroll
    for (int ni = 0; ni < 4; ni++) {
      int gn = n0 + wn * 64 + ni * 16 + cq;
      int b = gn >> LOGHW;
      int hw = gn & (HW - 1);
      int x = hw & (WD - 1), y = hw >> LOGW;
      float xg = -1.0f + x * (2.0f / (WD - 1));
      float yg = -1.0f + y * (2.0f / (WD - 1));
      float vals[4];
      #pragma unroll
      for (int r = 0; r < 4; r++)
        vals[r] = acc[mi][ni][r] + wxr[r] * xg + wyr[r] * yg + bbr[r];
      if (lm < PHIC) {
        #pragma unroll
        for (int r = 0; r < 4; r++)
          outHW[(size_t)b * outHW_bstride + (size_t)(lm + r) * HW + hw] = vals[r];
      }
      u16x4 pk;
      #pragma unroll
      for (int r = 0; r < 4; r++) pk[r] = f2bf(vals[r]);
      *(u16x4*)&outCM[((size_t)b * HW + hw) * CST + lm] = pk;
    }
  }
}

// bilinear helpers (half-pixel, edge clamp)
template <int Hin>
__device__ __forceinline__ void bilin_coords(int v, int& i0, int& i1, float& wgt) {
  constexpr float scale = (float)Hin / 64.0f;
  float f = ((float)v + 0.5f) * scale - 0.5f;
  float f0 = floorf(f);
  wgt = f - f0;
  int i = (int)f0;
  i1 = min(i + 1, Hin - 1);
  i0 = max(i, 0);
}

// ---------------- emit out_phi (fp32, hw fastest) — 4 px/thread ----------------
template <int C, int Cin, int Hin>
__global__ void emit_phi_v(const float* __restrict__ in, float* __restrict__ outp,
                           int ch_off) {
  int idx = blockIdx.x * 256 + threadIdx.x;  // over B*C*1024
  int x0 = (idx & 15) * 4;
  int y = (idx >> 4) & 63;
  int c = (idx >> 10) % C;
  int b = idx / (C * 1024);
  const float* pl = in + (size_t)(b * Cin + c) * (Hin * Hin);
  int y0, y1; float wy;
  bilin_coords<Hin>(y, y0, y1, wy);
  const float* r0 = pl + y0 * Hin;
  const float* r1 = pl + y1 * Hin;
  f32x4 o;
  #pragma unroll
  for (int k = 0; k < 4; k++) {
    int xx0, xx1; float wx;
    bilin_coords<Hin>(x0 + k, xx0, xx1, wx);
    float top = (1.0f - wx) * r0[xx0] + wx * r0[xx1];
    float bot = (1.0f - wx) * r1[xx0] + wx * r1[xx1];
    o[k] = (1.0f - wy) * top + wy * bot;
  }
  *(f32x4*)&outp[((size_t)b * 896 + ch_off + c) * 4096 + (y << 6) + x0] = o;
}

// ---------------- fp32 [R][Cc] -> bf16 [c][r] transpose (strided out) ----------------
__global__ __launch_bounds__(256) void trans_f32_bf16(
    const float* __restrict__ in, u16* __restrict__ outT, int R, int Cc, int OS,
    size_t in_bstride, size_t out_bstride) {
  int b = blockIdx.z;
  in += (size_t)b * in_bstride;
  outT += (size_t)b * out_bstride;
  int r0 = blockIdx.y * 32, c0 = blockIdx.x * 32;
  __shared__ float t[32][33];
  int tid = threadIdx.x;
  int cl = tid & 31, rl = tid >> 5;  // rl 0..7
  #pragma unroll
  for (int q = 0; q < 4; q++)
    t[rl + q * 8][cl] = in[(size_t)(r0 + rl + q * 8) * Cc + c0 + cl];
  __syncthreads();
  #pragma unroll
  for (int q = 0; q < 4; q++) {
    int c = c0 + rl + q * 8;
    outT[(size_t)c * OS + r0 + cl] = f2bf(t[cl][rl + q * 8]);
  }
}

// ---------------- gather A from transposed OT[b][p][C] (bf16), 8 ch/thread ----------------
template <int C, int Hin, int L>  // L = log2(C/8)
__global__ void gather_A(const u16* __restrict__ OT, u16* __restrict__ A,
                         int ch_off) {
  int idx = blockIdx.x * 256 + threadIdx.x;  // over B*4096*(C/8)
  int co = (idx & ((C / 8) - 1)) * 8;
  int hw = (idx >> L) & 4095;
  int b = idx >> (L + 12);
  int x = hw & 63, y = hw >> 6;
  int y0, y1, x0, x1; float wy, wx;
  bilin_coords<Hin>(y, y0, y1, wy);
  bilin_coords<Hin>(x, x0, x1, wx);
  float w00 = (1.0f - wy) * (1.0f - wx), w01 = (1.0f - wy) * wx;
  float w10 = wy * (1.0f - wx), w11 = wy * wx;
  const u16* base = OT + (size_t)b * (Hin * Hin) * C + co;
  bf16x8 t00 = *(const bf16x8*)&base[(y0 * Hin + x0) * C];
  bf16x8 t01 = *(const bf16x8*)&base[(y0 * Hin + x1) * C];
  bf16x8 t10 = *(const bf16x8*)&base[(y1 * Hin + x0) * C];
  bf16x8 t11 = *(const bf16x8*)&base[(y1 * Hin + x1) * C];
  bf16x8 o;
  #pragma unroll
  for (int e = 0; e < 8; e++) {
    float v = w00 * bf2f((u16)t00[e]) + w01 * bf2f((u16)t01[e]) +
              w10 * bf2f((u16)t10[e]) + w11 * bf2f((u16)t11[e]);
    o[e] = (short)f2bf(v);
  }
  *(bf16x8*)&A[((size_t)b * 4096 + hw) * 1792 + ch_off + co] = o;
}

// ---------------- row sum of squares over bf16 rows ----------------
__global__ __launch_bounds__(256) void rownorm2(const u16* __restrict__ X,
                                                float* __restrict__ out, int ncols) {
  int row = blockIdx.x * 4 + (threadIdx.x >> 6);
  int lane = threadIdx.x & 63;
  const u16* xr = X + (size_t)row * ncols;
  int n8 = ncols >> 3;
  float s = 0.0f;
  for (int c8 = lane; c8 < n8; c8 += 64) {
    bf16x8 v = *(const bf16x8*)&xr[c8 * 8];
    #pragma unroll
    for (int e = 0; e < 8; e++) {
      float f = bf2f((u16)v[e]);
      s = fmaf(f, f, s);
    }
  }
  #pragma unroll
  for (int off = 32; off; off >>= 1) s += __shfl_down(s, off);
  if (lane == 0) out[row] = s;
}

// ======== 256x256-tile deep-pipelined distance GEMM ========
#define GD_NT 56  // K/32

// LDS row stride is 64B (16 banks) -> bank cycle repeats every 2 rows.
// Correct conflict-free 16B-slot swizzle: physical_slot = logical ^ ((row>>1)&3).
// (Old row&3 variant left a 4-way conflict: rows 0,4,8,12 aliased.)
__device__ __forceinline__ void stage16k(const u16* __restrict__ G, int row0,
                                         int k0, char* lds_wavebase, int lane) {
  const int K = 1792;
  int sub = lane >> 2;                            // row within 16-row group
  int colsw = 8 * ((lane & 3) ^ ((lane >> 3) & 3));  // logical col for phys slot lane&3
  #pragma unroll
  for (int q = 0; q < 2; q++) {
    gload_lds16(G + (size_t)(row0 + q * 128 + sub) * K + k0 + colsw,
                lds_wavebase + q * 8192);
  }
}

__global__ __launch_bounds__(512, 2) void gemm_dist2(
    const u16* __restrict__ A,   // [16384][1792]
    const u16* __restrict__ Bt,  // [4096][1792]
    const float* __restrict__ feats, const float* __restrict__ cents,
    float* __restrict__ S, int m_base) {
  const int K = 1792, N = 4096;
  extern __shared__ u16 lds[];  // 4 bufs x (A 8192 + B 8192) elems = 128 KiB
  int bid = blockIdx.x;
  int swz = (bid & 7) * 32 + (bid >> 3);
  int m0 = (swz >> 4) * 256;
  int n0 = (swz & 15) * 256;
  int tid = threadIdx.x;
  int wid = tid >> 6, lane = tid & 63;
  int wr = wid >> 2, wc = wid & 3;  // wave -> 128x64 output sub-tile
  int ln15 = lane & 15;
  int fo = 8 * ((lane >> 4) ^ ((lane >> 1) & 3));  // phys slot for row=ln15, logical=lane>>4

  f32x4 acc[8][4] = {};

  #pragma unroll
  for (int t = 0; t < 3; t++) {
    char* bufb = (char*)lds + (t & 3) * 32768 + wid * 1024;
    stage16k(A, m_base + m0 + wid * 16, t * 32, bufb, lane);
    stage16k(Bt, n0 + wid * 16, t * 32, bufb + 16384, lane);
  }

  #pragma unroll 1
  for (int t = 0; t < GD_NT; t++) {
    asm volatile("s_waitcnt vmcnt(8)" ::: "memory");
    __builtin_amdgcn_s_barrier();
    __builtin_amdgcn_sched_barrier(0);
    const u16* Ab = lds + (t & 3) * 16384;
    const u16* Bb = Ab + 8192;
    char* nbuf = (char*)lds + ((t + 3) & 3) * 32768 + wid * 1024;

    if (t + 3 < GD_NT) stage16k(A, m_base + m0 + wid * 16, (t + 3) * 32, nbuf, lane);
    bf16x8 bq[4];
    #pragma unroll
    for (int ni = 0; ni < 4; ni++)
      bq[ni] = *(const bf16x8*)&Bb[(wc * 64 + ni * 16 + ln15) * 32 + fo];
    {
      bf16x8 af[4];
      #pragma unroll
      for (int mi = 0; mi < 4; mi++)
        af[mi] = *(const bf16x8*)&Ab[(wr * 128 + mi * 16 + ln15) * 32 + fo];
      __builtin_amdgcn_s_setprio(1);
      #pragma unroll
      for (int mi = 0; mi < 4; mi++)
        #pragma unroll
        for (int ni = 0; ni < 4; ni++)
          acc[mi][ni] = __builtin_amdgcn_mfma_f32_16x16x32_bf16(af[mi], bq[ni], acc[mi][ni], 0, 0, 0);
      __builtin_amdgcn_s_setprio(0);
    }
    __builtin_amdgcn_s_barrier();

    if (t + 3 < GD_NT) stage16k(Bt, n0 + wid * 16, (t + 3) * 32, nbuf + 16384, lane);
    {
      bf16x8 af[4];
      #pragma unroll
      for (int mi = 0; mi < 4; mi++)
        af[mi] = *(const bf16x8*)&Ab[(wr * 128 + (mi + 4) * 16 + ln15) * 32 + fo];
      __builtin_amdgcn_s_setprio(1);
      #pragma unroll
      for (int mi = 0; mi < 4; mi++)
        #pragma unroll
        for (int ni = 0; ni < 4; ni++)
          acc[mi + 4][ni] = __builtin_amdgcn_mfma_f32_16x16x32_bf16(af[mi], bq[ni], acc[mi + 4][ni], 0, 0, 0);
      __builtin_amdgcn_s_setprio(0);
    }
  }

  int rq = lane >> 4, cq = lane & 15;
  #pragma unroll
  for (int mi = 0; mi < 8; mi++) {
    int lm = m0 + wr * 128 + mi * 16 + rq * 4;
    #pragma unroll
    for (int ni = 0; ni < 4; ni++) {
      int gn = n0 + wc * 64 + ni * 16 + cq;
      float cn = cents[gn];
      #pragma unroll
      for (int r = 0; r < 4; r++)
        S[(size_t)(lm + r) * N + gn] = feats[m_base + lm + r] + cn - 2.0f * acc[mi][ni][r];
    }
  }
}

// ---------------- per-row top-200 smallest (sorted) of 4096, emit sqrt ----------------
__global__ __launch_bounds__(256) void select_topk(const float* __restrict__ S,
                                                   float* __restrict__ out,
                                                   int row_base) {
  int wv = threadIdx.x >> 6, lane = threadIdx.x & 63;
  int row_local = blockIdx.x * 4 + wv;
  const float* Sr = S + (size_t)row_local * 4096;
  uint32_t ku[64];
  #pragma unroll
  for (int g = 0; g < 16; g++) {
    f32x4 v = *(const f32x4*)&Sr[g * 256 + lane * 4];
    #pragma unroll
    for (int e = 0; e < 4; e++) {
      uint32_t u = __float_as_uint(v[e]);
      u ^= (u & 0x80000000u) ? 0xFFFFFFFFu : 0x80000000u;  // order-preserving
      ku[g * 4 + e] = u;
    }
  }
  uint32_t mn = 0xFFFFFFFFu, mx = 0u;
  #pragma unroll
  for (int j = 0; j < 64; j++) {
    mn = min(mn, ku[j]);
    mx = max(mx, ku[j]);
  }
  #pragma unroll
  for (int off = 1; off < 64; off <<= 1) {
    mn = min(mn, (uint32_t)__shfl_xor((int)mn, off));
    mx = max(mx, (uint32_t)__shfl_xor((int)mx, off));
  }
  uint32_t lo = mn, hi = mx;
  while (lo < hi) {
    uint32_t mid = lo + ((hi - lo) >> 1);
    int c = 0;
    #pragma unroll
    for (int j = 0; j < 64; j++) c += (ku[j] <= mid) ? 1 : 0;
    #pragma unroll
    for (int off = 1; off < 64; off <<= 1) c += __shfl_xor(c, off);
    if (c >= 200) hi = mid; else lo = mid + 1;
  }
  uint32_t T = lo;
  int cl = 0;
  #pragma unroll
  for (int j = 0; j < 64; j++) cl += (ku[j] < T) ? 1 : 0;
  int incl = cl;
  #pragma unroll
  for (int off = 1; off < 64; off <<= 1) {
    int v = __shfl_up(incl, off);
    if (lane >= off) incl += v;
  }
  int nless = __shfl(incl, 63);
  int pos = incl - cl;
  __shared__ uint32_t selv[4][256];
  uint32_t* sv = selv[wv];
  #pragma unroll
  for (int g = 0; g < 4; g++) sv[g * 64 + lane] = 0xFFFFFFFFu;
  for (int p = nless + lane; p < 200; p += 64) sv[p] = T;
  #pragma unroll
  for (int j = 0; j < 64; j++)
    if (ku[j] < T) sv[pos++] = ku[j];
  uint32_t v[4];
  #pragma unroll
  for (int q = 0; q < 4; q++) v[q] = sv[q * 64 + lane];
  #pragma unroll
  for (int kk = 2; kk <= 256; kk <<= 1) {
    #pragma unroll
    for (int jj = kk >> 1; jj > 0; jj >>= 1) {
      if (jj >= 64) {
        int qb = jj >> 6;
        #pragma unroll
        for (int q = 0; q < 4; q++) {
          if ((q & qb) == 0) {
            int q2 = q | qb;
            bool up = (kk == 256) ? true : ((q & (kk >> 6)) == 0);
            uint32_t a = v[q], b2 = v[q2];
            uint32_t lo2 = min(a, b2), hi2 = max(a, b2);
            v[q] = up ? lo2 : hi2;
            v[q2] = up ? hi2 : lo2;
          }
        }
      } else {
        #pragma unroll
        for (int q = 0; q < 4; q++) {
          bool up;
          if (kk == 256) up = true;
          else if (kk == 128) up = ((q & 2) == 0);
          else if (kk == 64) up = ((q & 1) == 0);
          else up = ((lane & kk) == 0);
          uint32_t other = (uint32_t)__shfl_xor((int)v[q], jj);
          bool lower = ((lane & jj) == 0);
          uint32_t lo2 = min(v[q], other), hi2 = max(v[q], other);
          v[q] = (up == lower) ? lo2 : hi2;
        }
      }
    }
  }
  int grow = row_base + row_local;
  int b = grow >> 12, r = grow & 4095;
  #pragma unroll
  for (int q = 0; q < 4; q++) {
    int i = q * 64 + lane;
    if (i < 200) {
      uint32_t u = v[q];
      u ^= (u & 0x80000000u) ? 0x80000000u : 0xFFFFFFFFu;
      out[((size_t)b * 200 + i) * 4096 + r] = sqrtf(__uint_as_float(u));
    }
  }
}

extern "C" void kernel_launch(void* const* d_in, const int* in_sizes, int n_in,
                              void* d_out, int out_size, void* d_ws, size_t ws_size,
                              hipStream_t stream) {
  const float* p0 = (const float*)d_in[0];   // (4,256,64,64)
  const float* p1 = (const float*)d_in[1];   // (4,512,32,32)
  const float* p2 = (const float*)d_in[2];   // (4,1024,16,16)
  const float* w1 = (const float*)d_in[5];   // (256,258)
  const float* b1 = (const float*)d_in[6];
  const float* w2 = (const float*)d_in[7];   // (512,514)
  const float* b2 = (const float*)d_in[8];
  const float* w3 = (const float*)d_in[9];   // (1024,1026)
  const float* b3 = (const float*)d_in[10];
  const float* Cm = (const float*)d_in[11];  // (1792,4096)

  float* out_score = (float*)d_out;                  // 4*200*4096 fp32
  float* out_phi = (float*)d_out + 3276800;          // 4*896*4096 fp32

  // workspace layout (peak 140,591,104 B — proven)
  char* w = (char*)d_ws;
  u16* Abf = (u16*)w;                                //  58,720,256 B
  u16* Ct = (u16*)(w + 58720256);                    //  14,680,064 B
  float* feats = (float*)(w + 73400320);             //      65,536 B
  float* cents = (float*)(w + 73465856);             //      16,384 B
  float* S = (float*)(w + 73482240);                 //  67,108,864 B (per-chunk) -> ends 140,591,104
  // stage-A temps all alias the S region (dead before first gemm_dist2):
  u16* PT1 = (u16*)(w + 73482240);                   //   8,388,608 B [16384][256]
  u16* PT2 = (u16*)(w + 81870848);                   //   4,194,304 B [4096][512]
  u16* PT3 = (u16*)(w + 86065152);                   //   2,097,152 B [1024][1024]
  u16* Wbf1 = (u16*)(w + 88162304);                  //     131,072 B
  u16* Wbf2 = (u16*)(w + 88293376);                  //     524,288 B
  u16* Wbf3 = (u16*)(w + 88817664);                  //   2,097,152 B
  float* O2 = (float*)(w + 90914816);                //   8,388,608 B [4][512][1024]
  float* O3 = (float*)(w + 99303424);                //     524,288 B [4][128][256]
  u16* OT2 = (u16*)(w + 99827712);                   //   4,194,304 B [4][1024][512]
  u16* OT3 = (u16*)(w + 104022016);                  //   2,097,152 B [4][256][1024] -> ends 106,119,168

  // ---- fused pool + transpose + bf16 -> PT ----
  pool_trans<256, 64, 64><<<dim3(128, 8, 4), 256, 0, stream>>>(p0, PT1);
  pool_trans<512, 32, 32><<<dim3(32, 16, 4), 256, 0, stream>>>(p1, PT2);
  pool_trans<1024, 16, 16><<<dim3(8, 32, 4), 256, 0, stream>>>(p2, PT3);

  // ---- weights -> bf16 ----
  wconv_bf16<<<32, 256, 0, stream>>>(w1, Wbf1, 8, 8192);
  wconv_bf16<<<128, 256, 0, stream>>>(w2, Wbf2, 9, 32768);
  wconv_bf16<<<512, 256, 0, stream>>>(w3, Wbf3, 10, 131072);

  // ---- coordconv via MFMA GEMM, dual-layout epilogue ----
  conv_gemm<256, 4096, 64, 256, 256, 1792><<<dim3(128, 2), 256, 0, stream>>>(
      Wbf1, PT1, w1, b1, out_phi, (size_t)896 * 4096, Abf);
  conv_gemm<512, 1024, 32, 512, 512, 512><<<dim3(32, 4), 256, 0, stream>>>(
      Wbf2, PT2, w2, b2, O2, (size_t)512 * 1024, OT2);
  conv_gemm<1024, 256, 16, 1024, 128, 1024><<<dim3(8, 8), 256, 0, stream>>>(
      Wbf3, PT3, w3, b3, O3, (size_t)128 * 256, OT3);

  // ---- out_phi levels 2,3 (bilinear resize) ----
  emit_phi_v<512, 512, 32><<<8192, 256, 0, stream>>>(O2, out_phi, 256);
  emit_phi_v<128, 128, 16><<<2048, 256, 0, stream>>>(O3, out_phi, 768);

  // ---- A matrix cols [256,1792): coalesced gather from OT ----
  gather_A<512, 32, 6><<<4096, 256, 0, stream>>>(OT2, Abf, 256);
  gather_A<1024, 16, 7><<<8192, 256, 0, stream>>>(OT3, Abf, 768);

  // ---- C transpose + bf16 ----
  trans_f32_bf16<<<dim3(128, 56, 1), 256, 0, stream>>>(Cm, Ct, 1792, 4096, 1792, 0, 0);

  // ---- norms ----
  rownorm2<<<4096, 256, 0, stream>>>(Abf, feats, 1792);
  rownorm2<<<1024, 256, 0, stream>>>(Ct, cents, 1792);

  // ---- distance GEMM (256^2 deep-pipelined) + top-200, chunked by batch image ----
  for (int mc = 0; mc < 4; mc++) {
    gemm_dist2<<<256, 512, 131072, stream>>>(Abf, Ct, feats, cents, S, mc * 4096);
    select_topk<<<1024, 256, 0, stream>>>(S, out_score, mc * 4096);
  }
}

// Round 11
// 555.553 us; speedup vs baseline: 1.9802x; 1.0061x over previous
//
#include <hip/hip_runtime.h>
#include <hip/hip_bf16.h>
#include <stdint.h>

typedef unsigned short u16;
typedef __attribute__((ext_vector_type(8))) short bf16x8;
typedef __attribute__((ext_vector_type(4))) unsigned short u16x4;
typedef __attribute__((ext_vector_type(4))) float f32x4;

#define AS1 __attribute__((address_space(1)))
#define AS3 __attribute__((address_space(3)))

__device__ __forceinline__ u16 f2bf(float f) {
  uint32_t x = __float_as_uint(f);
  uint32_t r = (x + 0x7FFFu + ((x >> 16) & 1u)) >> 16;
  return (u16)r;
}
__device__ __forceinline__ float bf2f(u16 u) {
  return __uint_as_float(((uint32_t)u) << 16);
}

__device__ __forceinline__ void gload_lds16(const void* g, void* l) {
  __builtin_amdgcn_global_load_lds((const AS1 void*)g, (AS3 void*)l, 16, 0, 0);
}

// ---- fused 3x3 avg pool + transpose + bf16: in[b][c][hw] -> PT[(b,hw)][C] ----
template <int C, int H, int W>
__global__ __launch_bounds__(256) void pool_trans(const float* __restrict__ in,
                                                  u16* __restrict__ PT) {
  constexpr int HW = H * W;
  int hwt = blockIdx.x, ct = blockIdx.y, b = blockIdx.z;
  int tid = threadIdx.x;
  __shared__ float t[32][33];
  {
    int c_l = tid >> 3;          // 0..31
    int hw_l = (tid & 7) * 4;    // 0,4,...,28
    int c = ct * 32 + c_l;
    int hw = hwt * 32 + hw_l;
    int y = hw / W;
    int x0 = hw % W;
    const float* pl = in + ((size_t)b * C + c) * HW;
    float cs[6] = {0, 0, 0, 0, 0, 0};
    #pragma unroll
    for (int dy = -1; dy <= 1; dy++) {
      int yy = y + dy;
      if ((unsigned)yy < (unsigned)H) {
        const float* row = pl + yy * W;
        #pragma unroll
        for (int k = 0; k < 6; k++) {
          int xx = x0 - 1 + k;
          if ((unsigned)xx < (unsigned)W) cs[k] += row[xx];
        }
      }
    }
    #pragma unroll
    for (int k = 0; k < 4; k++)
      t[c_l][hw_l + k] = (cs[k] + cs[k + 1] + cs[k + 2]) * (1.0f / 9.0f);
  }
  __syncthreads();
  int hw_w = tid >> 3;           // 0..31
  int c_w = (tid & 7) * 4;       // 0,4,...,28
  u16x4 o;
  #pragma unroll
  for (int j = 0; j < 4; j++) o[j] = f2bf(t[c_w + j][hw_w]);
  *(u16x4*)&PT[((size_t)b * HW + hwt * 32 + hw_w) * C + ct * 32 + c_w] = o;
}

// ---------------- w[O][K+2] fp32 -> Wb[O][K] bf16 ----------------
__global__ void wconv_bf16(const float* __restrict__ wf, u16* __restrict__ wb,
                           int logk, int total) {
  int idx = blockIdx.x * 256 + threadIdx.x;
  if (idx >= total) return;
  int K = 1 << logk;
  int o = idx >> (logk - 3);
  int k0 = (idx & ((K >> 3) - 1)) * 8;
  const float* src = wf + (size_t)o * (K + 2) + k0;
  bf16x8 v;
  #pragma unroll
  for (int e = 0; e < 8; e++) v[e] = (short)f2bf(src[e]);
  *(bf16x8*)&wb[(size_t)o * K + k0] = v;
}

// ======== MFMA CoordConv GEMM, dual-layout epilogue ========
template <int K, int HW, int WD, int OC, int PHIC, int CST>
__global__ __launch_bounds__(256) void conv_gemm(
    const u16* __restrict__ Wb,   // [OC][K] bf16
    const u16* __restrict__ PT,   // [4*HW][K] bf16
    const float* __restrict__ wf, // [OC][K+2] fp32 (coord cols)
    const float* __restrict__ bias,
    float* __restrict__ outHW, size_t outHW_bstride,
    u16* __restrict__ outCM) {
  constexpr int LOGW = (WD == 64) ? 6 : (WD == 32) ? 5 : 4;
  constexpr int LOGHW = 2 * LOGW;
  int n0 = blockIdx.x * 128, m0 = blockIdx.y * 128;
  int tid = threadIdx.x;
  int wid = tid >> 6, lane = tid & 63;
  int wm = wid >> 1, wn = wid & 1;
  __shared__ u16 As[128 * 64];
  __shared__ u16 Bs[128 * 64];
  f32x4 acc[4][4] = {};
  int lrow = tid >> 3;           // 0..31
  int lcol = (tid & 7) * 8;
  const u16* ga = Wb + (size_t)(m0 + lrow) * K + lcol;
  const u16* gb = PT + (size_t)(n0 + lrow) * K + lcol;
  char* lbaseA = (char*)As + wid * 1024;
  char* lbaseB = (char*)Bs + wid * 1024;
  for (int k0 = 0; k0 < K; k0 += 64) {
    #pragma unroll
    for (int q = 0; q < 4; q++) {
      gload_lds16(ga + (size_t)q * 32 * K + k0, lbaseA + q * 4096);
      gload_lds16(gb + (size_t)q * 32 * K + k0, lbaseB + q * 4096);
    }
    __syncthreads();
    #pragma unroll
    for (int kk = 0; kk < 2; kk++) {
      bf16x8 af[4], bfr[4];
      int kb = kk * 32 + (lane >> 4) * 8;
      #pragma unroll
      for (int i = 0; i < 4; i++)
        af[i] = *(const bf16x8*)&As[(wm * 64 + i * 16 + (lane & 15)) * 64 + kb];
      #pragma unroll
      for (int j = 0; j < 4; j++)
        bfr[j] = *(const bf16x8*)&Bs[(wn * 64 + j * 16 + (lane & 15)) * 64 + kb];
      #pragma unroll
      for (int i = 0; i < 4; i++)
        #pragma unroll
        for (int j = 0; j < 4; j++)
          acc[i][j] = __builtin_amdgcn_mfma_f32_16x16x32_bf16(af[i], bfr[j], acc[i][j], 0, 0, 0);
    }
    __syncthreads();
  }
  int rq = lane >> 4, cq = lane & 15;
  #pragma unroll
  for (int mi = 0; mi < 4; mi++) {
    int lm = m0 + wm * 64 + mi * 16 + rq * 4;
    float wxr[4], wyr[4], bbr[4];
    #pragma unroll
    for (int r = 0; r < 4; r++) {
      int o = lm + r;
      wxr[r] = wf[(size_t)o * (K + 2) + K];
      wyr[r] = wf[(size_t)o * (K + 2) + K + 1];
      bbr[r] = bias[o];
    }
    #pragma unroll
    for (int ni = 0; ni < 4; ni++) {
      int gn = n0 + wn * 64 + ni * 16 + cq;
      int b = gn >> LOGHW;
      int hw = gn & (HW - 1);
      int x = hw & (WD - 1), y = hw >> LOGW;
      float xg = -1.0f + x * (2.0f / (WD - 1));
      float yg = -1.0f + y * (2.0f / (WD - 1));
      float vals[4];
      #pragma unroll
      for (int r = 0; r < 4; r++)
        vals[r] = acc[mi][ni][r] + wxr[r] * xg + wyr[r] * yg + bbr[r];
      if (lm < PHIC) {
        #pragma unroll
        for (int r = 0; r < 4; r++)
          outHW[(size_t)b * outHW_bstride + (size_t)(lm + r) * HW + hw] = vals[r];
      }
      u16x4 pk;
      #pragma unroll
      for (int r = 0; r < 4; r++) pk[r] = f2bf(vals[r]);
      *(u16x4*)&outCM[((size_t)b * HW + hw) * CST + lm] = pk;
    }
  }
}

// bilinear helpers (half-pixel, edge clamp)
template <int Hin>
__device__ __forceinline__ void bilin_coords(int v, int& i0, int& i1, float& wgt) {
  constexpr float scale = (float)Hin / 64.0f;
  float f = ((float)v + 0.5f) * scale - 0.5f;
  float f0 = floorf(f);
  wgt = f - f0;
  int i = (int)f0;
  i1 = min(i + 1, Hin - 1);
  i0 = max(i, 0);
}

// ---------------- emit out_phi (fp32, hw fastest) — 4 px/thread ----------------
template <int C, int Cin, int Hin>
__global__ void emit_phi_v(const float* __restrict__ in, float* __restrict__ outp,
                           int ch_off) {
  int idx = blockIdx.x * 256 + threadIdx.x;  // over B*C*1024
  int x0 = (idx & 15) * 4;
  int y = (idx >> 4) & 63;
  int c = (idx >> 10) % C;
  int b = idx / (C * 1024);
  const float* pl = in + (size_t)(b * Cin + c) * (Hin * Hin);
  int y0, y1; float wy;
  bilin_coords<Hin>(y, y0, y1, wy);
  const float* r0 = pl + y0 * Hin;
  const float* r1 = pl + y1 * Hin;
  f32x4 o;
  #pragma unroll
  for (int k = 0; k < 4; k++) {
    int xx0, xx1; float wx;
    bilin_coords<Hin>(x0 + k, xx0, xx1, wx);
    float top = (1.0f - wx) * r0[xx0] + wx * r0[xx1];
    float bot = (1.0f - wx) * r1[xx0] + wx * r1[xx1];
    o[k] = (1.0f - wy) * top + wy * bot;
  }
  *(f32x4*)&outp[((size_t)b * 896 + ch_off + c) * 4096 + (y << 6) + x0] = o;
}

// ---------------- fp32 [R][Cc] -> bf16 [c][r] transpose (strided out) ----------------
__global__ __launch_bounds__(256) void trans_f32_bf16(
    const float* __restrict__ in, u16* __restrict__ outT, int R, int Cc, int OS,
    size_t in_bstride, size_t out_bstride) {
  int b = blockIdx.z;
  in += (size_t)b * in_bstride;
  outT += (size_t)b * out_bstride;
  int r0 = blockIdx.y * 32, c0 = blockIdx.x * 32;
  __shared__ float t[32][33];
  int tid = threadIdx.x;
  int cl = tid & 31, rl = tid >> 5;  // rl 0..7
  #pragma unroll
  for (int q = 0; q < 4; q++)
    t[rl + q * 8][cl] = in[(size_t)(r0 + rl + q * 8) * Cc + c0 + cl];
  __syncthreads();
  #pragma unroll
  for (int q = 0; q < 4; q++) {
    int c = c0 + rl + q * 8;
    outT[(size_t)c * OS + r0 + cl] = f2bf(t[cl][rl + q * 8]);
  }
}

// ---------------- gather A from transposed OT[b][p][C] (bf16), 8 ch/thread ----------------
template <int C, int Hin, int L>  // L = log2(C/8)
__global__ void gather_A(const u16* __restrict__ OT, u16* __restrict__ A,
                         int ch_off) {
  int idx = blockIdx.x * 256 + threadIdx.x;  // over B*4096*(C/8)
  int co = (idx & ((C / 8) - 1)) * 8;
  int hw = (idx >> L) & 4095;
  int b = idx >> (L + 12);
  int x = hw & 63, y = hw >> 6;
  int y0, y1, x0, x1; float wy, wx;
  bilin_coords<Hin>(y, y0, y1, wy);
  bilin_coords<Hin>(x, x0, x1, wx);
  float w00 = (1.0f - wy) * (1.0f - wx), w01 = (1.0f - wy) * wx;
  float w10 = wy * (1.0f - wx), w11 = wy * wx;
  const u16* base = OT + (size_t)b * (Hin * Hin) * C + co;
  bf16x8 t00 = *(const bf16x8*)&base[(y0 * Hin + x0) * C];
  bf16x8 t01 = *(const bf16x8*)&base[(y0 * Hin + x1) * C];
  bf16x8 t10 = *(const bf16x8*)&base[(y1 * Hin + x0) * C];
  bf16x8 t11 = *(const bf16x8*)&base[(y1 * Hin + x1) * C];
  bf16x8 o;
  #pragma unroll
  for (int e = 0; e < 8; e++) {
    float v = w00 * bf2f((u16)t00[e]) + w01 * bf2f((u16)t01[e]) +
              w10 * bf2f((u16)t10[e]) + w11 * bf2f((u16)t11[e]);
    o[e] = (short)f2bf(v);
  }
  *(bf16x8*)&A[((size_t)b * 4096 + hw) * 1792 + ch_off + co] = o;
}

// ---------------- row sum of squares over bf16 rows ----------------
__global__ __launch_bounds__(256) void rownorm2(const u16* __restrict__ X,
                                                float* __restrict__ out, int ncols) {
  int row = blockIdx.x * 4 + (threadIdx.x >> 6);
  int lane = threadIdx.x & 63;
  const u16* xr = X + (size_t)row * ncols;
  int n8 = ncols >> 3;
  float s = 0.0f;
  for (int c8 = lane; c8 < n8; c8 += 64) {
    bf16x8 v = *(const bf16x8*)&xr[c8 * 8];
    #pragma unroll
    for (int e = 0; e < 8; e++) {
      float f = bf2f((u16)v[e]);
      s = fmaf(f, f, s);
    }
  }
  #pragma unroll
  for (int off = 32; off; off >>= 1) s += __shfl_down(s, off);
  if (lane == 0) out[row] = s;
}

// ======== 256x256-tile deep-pipelined distance GEMM ========
#define GD_NT 56  // K/32

// LDS row stride 64B -> conflict-free 16B-slot swizzle: phys = logical ^ ((row>>1)&3).
__device__ __forceinline__ void stage16k(const u16* __restrict__ G, int row0,
                                         int k0, char* lds_wavebase, int lane) {
  const int K = 1792;
  int sub = lane >> 2;                            // row within 16-row group
  int colsw = 8 * ((lane & 3) ^ ((lane >> 3) & 3));  // logical col for phys slot lane&3
  #pragma unroll
  for (int q = 0; q < 2; q++) {
    gload_lds16(G + (size_t)(row0 + q * 128 + sub) * K + k0 + colsw,
                lds_wavebase + q * 8192);
  }
}

__global__ __launch_bounds__(512, 2) void gemm_dist2(
    const u16* __restrict__ A,   // [16384][1792]
    const u16* __restrict__ Bt,  // [4096][1792]
    const float* __restrict__ feats, const float* __restrict__ cents,
    float* __restrict__ S, int m_base) {
  const int K = 1792, N = 4096;
  extern __shared__ u16 lds[];  // 4 bufs x (A 8192 + B 8192) elems = 128 KiB
  int bid = blockIdx.x;
  int swz = (bid & 7) * 32 + (bid >> 3);
  int m0 = (swz >> 4) * 256;
  int n0 = (swz & 15) * 256;
  int tid = threadIdx.x;
  int wid = tid >> 6, lane = tid & 63;
  int wr = wid >> 2, wc = wid & 3;  // wave -> 128x64 output sub-tile
  int ln15 = lane & 15;
  int fo = 8 * ((lane >> 4) ^ ((lane >> 1) & 3));  // phys slot for row=ln15

  f32x4 acc[8][4] = {};

  #pragma unroll
  for (int t = 0; t < 3; t++) {
    char* bufb = (char*)lds + (t & 3) * 32768 + wid * 1024;
    stage16k(A, m_base + m0 + wid * 16, t * 32, bufb, lane);
    stage16k(Bt, n0 + wid * 16, t * 32, bufb + 16384, lane);
  }

  // single barrier per K-tile: {vmcnt(8); barrier; 12 ds_reads; 4 stage loads;
  // 32 MFMA with compiler-fine lgkmcnt}. Mid-tile barrier removed (proven
  // redundant: stage buffer (t+3)&3 == (t-1)&3, retired before this barrier;
  // cross-wave visibility of tile t ensured by per-wave vmcnt(8) THEN barrier).
  #pragma unroll 1
  for (int t = 0; t < GD_NT; t++) {
    asm volatile("s_waitcnt vmcnt(8)" ::: "memory");
    __builtin_amdgcn_s_barrier();
    __builtin_amdgcn_sched_barrier(0);
    const u16* Ab = lds + (t & 3) * 16384;
    const u16* Bb = Ab + 8192;
    char* nbuf = (char*)lds + ((t + 3) & 3) * 32768 + wid * 1024;

    // issue ALL fragment reads up front
    bf16x8 bq[4], af[8];
    #pragma unroll
    for (int ni = 0; ni < 4; ni++)
      bq[ni] = *(const bf16x8*)&Bb[(wc * 64 + ni * 16 + ln15) * 32 + fo];
    #pragma unroll
    for (int mi = 0; mi < 8; mi++)
      af[mi] = *(const bf16x8*)&Ab[(wr * 128 + mi * 16 + ln15) * 32 + fo];

    // issue next-tile stages (landing checked 3 tiles later)
    if (t + 3 < GD_NT) {
      stage16k(A, m_base + m0 + wid * 16, (t + 3) * 32, nbuf, lane);
      stage16k(Bt, n0 + wid * 16, (t + 3) * 32, nbuf + 16384, lane);
    }

    __builtin_amdgcn_s_setprio(1);
    #pragma unroll
    for (int mi = 0; mi < 8; mi++)
      #pragma unroll
      for (int ni = 0; ni < 4; ni++)
        acc[mi][ni] = __builtin_amdgcn_mfma_f32_16x16x32_bf16(af[mi], bq[ni], acc[mi][ni], 0, 0, 0);
    __builtin_amdgcn_s_setprio(0);
  }

  int rq = lane >> 4, cq = lane & 15;
  #pragma unroll
  for (int mi = 0; mi < 8; mi++) {
    int lm = m0 + wr * 128 + mi * 16 + rq * 4;
    #pragma unroll
    for (int ni = 0; ni < 4; ni++) {
      int gn = n0 + wc * 64 + ni * 16 + cq;
      float cn = cents[gn];
      #pragma unroll
      for (int r = 0; r < 4; r++)
        S[(size_t)(lm + r) * N + gn] = feats[m_base + lm + r] + cn - 2.0f * acc[mi][ni][r];
    }
  }
}

// ---------------- per-row top-200 smallest (sorted) of 4096, emit sqrt ----------------
__global__ __launch_bounds__(256) void select_topk(const float* __restrict__ S,
                                                   float* __restrict__ out,
                                                   int row_base) {
  int wv = threadIdx.x >> 6, lane = threadIdx.x & 63;
  int row_local = blockIdx.x * 4 + wv;
  const float* Sr = S + (size_t)row_local * 4096;
  uint32_t ku[64];
  #pragma unroll
  for (int g = 0; g < 16; g++) {
    f32x4 v = *(const f32x4*)&Sr[g * 256 + lane * 4];
    #pragma unroll
    for (int e = 0; e < 4; e++) {
      uint32_t u = __float_as_uint(v[e]);
      u ^= (u & 0x80000000u) ? 0xFFFFFFFFu : 0x80000000u;  // order-preserving
      ku[g * 4 + e] = u;
    }
  }
  uint32_t mn = 0xFFFFFFFFu, mx = 0u;
  #pragma unroll
  for (int j = 0; j < 64; j++) {
    mn = min(mn, ku[j]);
    mx = max(mx, ku[j]);
  }
  #pragma unroll
  for (int off = 1; off < 64; off <<= 1) {
    mn = min(mn, (uint32_t)__shfl_xor((int)mn, off));
    mx = max(mx, (uint32_t)__shfl_xor((int)mx, off));
  }
  uint32_t lo = mn, hi = mx;
  while (lo < hi) {
    uint32_t mid = lo + ((hi - lo) >> 1);
    int c = 0;
    #pragma unroll
    for (int j = 0; j < 64; j++) c += (ku[j] <= mid) ? 1 : 0;
    #pragma unroll
    for (int off = 1; off < 64; off <<= 1) c += __shfl_xor(c, off);
    if (c >= 200) hi = mid; else lo = mid + 1;
  }
  uint32_t T = lo;
  int cl = 0;
  #pragma unroll
  for (int j = 0; j < 64; j++) cl += (ku[j] < T) ? 1 : 0;
  int incl = cl;
  #pragma unroll
  for (int off = 1; off < 64; off <<= 1) {
    int v = __shfl_up(incl, off);
    if (lane >= off) incl += v;
  }
  int nless = __shfl(incl, 63);
  int pos = incl - cl;
  __shared__ uint32_t selv[4][256];
  uint32_t* sv = selv[wv];
  #pragma unroll
  for (int g = 0; g < 4; g++) sv[g * 64 + lane] = 0xFFFFFFFFu;
  for (int p = nless + lane; p < 200; p += 64) sv[p] = T;
  #pragma unroll
  for (int j = 0; j < 64; j++)
    if (ku[j] < T) sv[pos++] = ku[j];
  uint32_t v[4];
  #pragma unroll
  for (int q = 0; q < 4; q++) v[q] = sv[q * 64 + lane];
  #pragma unroll
  for (int kk = 2; kk <= 256; kk <<= 1) {
    #pragma unroll
    for (int jj = kk >> 1; jj > 0; jj >>= 1) {
      if (jj >= 64) {
        int qb = jj >> 6;
        #pragma unroll
        for (int q = 0; q < 4; q++) {
          if ((q & qb) == 0) {
            int q2 = q | qb;
            bool up = (kk == 256) ? true : ((q & (kk >> 6)) == 0);
            uint32_t a = v[q], b2 = v[q2];
            uint32_t lo2 = min(a, b2), hi2 = max(a, b2);
            v[q] = up ? lo2 : hi2;
            v[q2] = up ? hi2 : lo2;
          }
        }
      } else {
        #pragma unroll
        for (int q = 0; q < 4; q++) {
          bool up;
          if (kk == 256) up = true;
          else if (kk == 128) up = ((q & 2) == 0);
          else if (kk == 64) up = ((q & 1) == 0);
          else up = ((lane & kk) == 0);
          uint32_t other = (uint32_t)__shfl_xor((int)v[q], jj);
          bool lower = ((lane & jj) == 0);
          uint32_t lo2 = min(v[q], other), hi2 = max(v[q], other);
          v[q] = (up == lower) ? lo2 : hi2;
        }
      }
    }
  }
  int grow = row_base + row_local;
  int b = grow >> 12, r = grow & 4095;
  #pragma unroll
  for (int q = 0; q < 4; q++) {
    int i = q * 64 + lane;
    if (i < 200) {
      uint32_t u = v[q];
      u ^= (u & 0x80000000u) ? 0x80000000u : 0xFFFFFFFFu;
      out[((size_t)b * 200 + i) * 4096 + r] = sqrtf(__uint_as_float(u));
    }
  }
}

extern "C" void kernel_launch(void* const* d_in, const int* in_sizes, int n_in,
                              void* d_out, int out_size, void* d_ws, size_t ws_size,
                              hipStream_t stream) {
  const float* p0 = (const float*)d_in[0];   // (4,256,64,64)
  const float* p1 = (const float*)d_in[1];   // (4,512,32,32)
  const float* p2 = (const float*)d_in[2];   // (4,1024,16,16)
  const float* w1 = (const float*)d_in[5];   // (256,258)
  const float* b1 = (const float*)d_in[6];
  const float* w2 = (const float*)d_in[7];   // (512,514)
  const float* b2 = (const float*)d_in[8];
  const float* w3 = (const float*)d_in[9];   // (1024,1026)
  const float* b3 = (const float*)d_in[10];
  const float* Cm = (const float*)d_in[11];  // (1792,4096)

  float* out_score = (float*)d_out;                  // 4*200*4096 fp32
  float* out_phi = (float*)d_out + 3276800;          // 4*896*4096 fp32

  // workspace layout (peak 140,591,104 B — proven)
  char* w = (char*)d_ws;
  u16* Abf = (u16*)w;                                //  58,720,256 B
  u16* Ct = (u16*)(w + 58720256);                    //  14,680,064 B
  float* feats = (float*)(w + 73400320);             //      65,536 B
  float* cents = (float*)(w + 73465856);             //      16,384 B
  float* S = (float*)(w + 73482240);                 //  67,108,864 B (per-chunk) -> ends 140,591,104
  // stage-A temps all alias the S region (dead before first gemm_dist2):
  u16* PT1 = (u16*)(w + 73482240);                   //   8,388,608 B [16384][256]
  u16* PT2 = (u16*)(w + 81870848);                   //   4,194,304 B [4096][512]
  u16* PT3 = (u16*)(w + 86065152);                   //   2,097,152 B [1024][1024]
  u16* Wbf1 = (u16*)(w + 88162304);                  //     131,072 B
  u16* Wbf2 = (u16*)(w + 88293376);                  //     524,288 B
  u16* Wbf3 = (u16*)(w + 88817664);                  //   2,097,152 B
  float* O2 = (float*)(w + 90914816);                //   8,388,608 B [4][512][1024]
  float* O3 = (float*)(w + 99303424);                //     524,288 B [4][128][256]
  u16* OT2 = (u16*)(w + 99827712);                   //   4,194,304 B [4][1024][512]
  u16* OT3 = (u16*)(w + 104022016);                  //   2,097,152 B [4][256][1024] -> ends 106,119,168

  // ---- fused pool + transpose + bf16 -> PT ----
  pool_trans<256, 64, 64><<<dim3(128, 8, 4), 256, 0, stream>>>(p0, PT1);
  pool_trans<512, 32, 32><<<dim3(32, 16, 4), 256, 0, stream>>>(p1, PT2);
  pool_trans<1024, 16, 16><<<dim3(8, 32, 4), 256, 0, stream>>>(p2, PT3);

  // ---- weights -> bf16 ----
  wconv_bf16<<<32, 256, 0, stream>>>(w1, Wbf1, 8, 8192);
  wconv_bf16<<<128, 256, 0, stream>>>(w2, Wbf2, 9, 32768);
  wconv_bf16<<<512, 256, 0, stream>>>(w3, Wbf3, 10, 131072);

  // ---- coordconv via MFMA GEMM, dual-layout epilogue ----
  conv_gemm<256, 4096, 64, 256, 256, 1792><<<dim3(128, 2), 256, 0, stream>>>(
      Wbf1, PT1, w1, b1, out_phi, (size_t)896 * 4096, Abf);
  conv_gemm<512, 1024, 32, 512, 512, 512><<<dim3(32, 4), 256, 0, stream>>>(
      Wbf2, PT2, w2, b2, O2, (size_t)512 * 1024, OT2);
  conv_gemm<1024, 256, 16, 1024, 128, 1024><<<dim3(8, 8), 256, 0, stream>>>(
      Wbf3, PT3, w3, b3, O3, (size_t)128 * 256, OT3);

  // ---- out_phi levels 2,3 (bilinear resize) ----
  emit_phi_v<512, 512, 32><<<8192, 256, 0, stream>>>(O2, out_phi, 256);
  emit_phi_v<128, 128, 16><<<2048, 256, 0, stream>>>(O3, out_phi, 768);

  // ---- A matrix cols [256,1792): coalesced gather from OT ----
  gather_A<512, 32, 6><<<4096, 256, 0, stream>>>(OT2, Abf, 256);
  gather_A<1024, 16, 7><<<8192, 256, 0, stream>>>(OT3, Abf, 768);

  // ---- C transpose + bf16 ----
  trans_f32_bf16<<<dim3(128, 56, 1), 256, 0, stream>>>(Cm, Ct, 1792, 4096, 1792, 0, 0);

  // ---- norms ----
  rownorm2<<<4096, 256, 0, stream>>>(Abf, feats, 1792);
  rownorm2<<<1024, 256, 0, stream>>>(Ct, cents, 1792);

  // ---- distance GEMM (256^2 deep-pipelined) + top-200, chunked by batch image ----
  for (int mc = 0; mc < 4; mc++) {
    gemm_dist2<<<256, 512, 131072, stream>>>(Abf, Ct, feats, cents, S, mc * 4096);
    select_topk<<<1024, 256, 0, stream>>>(S, out_score, mc * 4096);
  }
}

// Round 12
// 460.501 us; speedup vs baseline: 2.3889x; 1.2064x over previous
//
#include <hip/hip_runtime.h>
#include <hip/hip_bf16.h>
#include <stdint.h>

typedef unsigned short u16;
typedef __attribute__((ext_vector_type(8))) short bf16x8;
typedef __attribute__((ext_vector_type(4))) unsigned short u16x4;
typedef __attribute__((ext_vector_type(4))) float f32x4;

#define AS1 __attribute__((address_space(1)))
#define AS3 __attribute__((address_space(3)))

__device__ __forceinline__ u16 f2bf(float f) {
  uint32_t x = __float_as_uint(f);
  uint32_t r = (x + 0x7FFFu + ((x >> 16) & 1u)) >> 16;
  return (u16)r;
}
__device__ __forceinline__ float bf2f(u16 u) {
  return __uint_as_float(((uint32_t)u) << 16);
}

__device__ __forceinline__ void gload_lds16(const void* g, void* l) {
  __builtin_amdgcn_global_load_lds((const AS1 void*)g, (AS3 void*)l, 16, 0, 0);
}

// ---- fused 3x3 avg pool + transpose + bf16: in[b][c][hw] -> PT[(b,hw)][C] ----
template <int C, int H, int W>
__global__ __launch_bounds__(256) void pool_trans(const float* __restrict__ in,
                                                  u16* __restrict__ PT) {
  constexpr int HW = H * W;
  int hwt = blockIdx.x, ct = blockIdx.y, b = blockIdx.z;
  int tid = threadIdx.x;
  __shared__ float t[32][33];
  {
    int c_l = tid >> 3;          // 0..31
    int hw_l = (tid & 7) * 4;    // 0,4,...,28
    int c = ct * 32 + c_l;
    int hw = hwt * 32 + hw_l;
    int y = hw / W;
    int x0 = hw % W;
    const float* pl = in + ((size_t)b * C + c) * HW;
    float cs[6] = {0, 0, 0, 0, 0, 0};
    #pragma unroll
    for (int dy = -1; dy <= 1; dy++) {
      int yy = y + dy;
      if ((unsigned)yy < (unsigned)H) {
        const float* row = pl + yy * W;
        #pragma unroll
        for (int k = 0; k < 6; k++) {
          int xx = x0 - 1 + k;
          if ((unsigned)xx < (unsigned)W) cs[k] += row[xx];
        }
      }
    }
    #pragma unroll
    for (int k = 0; k < 4; k++)
      t[c_l][hw_l + k] = (cs[k] + cs[k + 1] + cs[k + 2]) * (1.0f / 9.0f);
  }
  __syncthreads();
  int hw_w = tid >> 3;           // 0..31
  int c_w = (tid & 7) * 4;       // 0,4,...,28
  u16x4 o;
  #pragma unroll
  for (int j = 0; j < 4; j++) o[j] = f2bf(t[c_w + j][hw_w]);
  *(u16x4*)&PT[((size_t)b * HW + hwt * 32 + hw_w) * C + ct * 32 + c_w] = o;
}

// ---------------- w[O][K+2] fp32 -> Wb[O][K] bf16 ----------------
__global__ void wconv_bf16(const float* __restrict__ wf, u16* __restrict__ wb,
                           int logk, int total) {
  int idx = blockIdx.x * 256 + threadIdx.x;
  if (idx >= total) return;
  int K = 1 << logk;
  int o = idx >> (logk - 3);
  int k0 = (idx & ((K >> 3) - 1)) * 8;
  const float* src = wf + (size_t)o * (K + 2) + k0;
  bf16x8 v;
  #pragma unroll
  for (int e = 0; e < 8; e++) v[e] = (short)f2bf(src[e]);
  *(bf16x8*)&wb[(size_t)o * K + k0] = v;
}

// ======== MFMA CoordConv GEMM, dual-layout epilogue ========
template <int K, int HW, int WD, int OC, int PHIC, int CST>
__global__ __launch_bounds__(256) void conv_gemm(
    const u16* __restrict__ Wb,   // [OC][K] bf16
    const u16* __restrict__ PT,   // [4*HW][K] bf16
    const float* __restrict__ wf, // [OC][K+2] fp32 (coord cols)
    const float* __restrict__ bias,
    float* __restrict__ outHW, size_t outHW_bstride,
    u16* __restrict__ outCM) {
  constexpr int LOGW = (WD == 64) ? 6 : (WD == 32) ? 5 : 4;
  constexpr int LOGHW = 2 * LOGW;
  int n0 = blockIdx.x * 128, m0 = blockIdx.y * 128;
  int tid = threadIdx.x;
  int wid = tid >> 6, lane = tid & 63;
  int wm = wid >> 1, wn = wid & 1;
  __shared__ u16 As[128 * 64];
  __shared__ u16 Bs[128 * 64];
  f32x4 acc[4][4] = {};
  int lrow = tid >> 3;           // 0..31
  int lcol = (tid & 7) * 8;
  const u16* ga = Wb + (size_t)(m0 + lrow) * K + lcol;
  const u16* gb = PT + (size_t)(n0 + lrow) * K + lcol;
  char* lbaseA = (char*)As + wid * 1024;
  char* lbaseB = (char*)Bs + wid * 1024;
  for (int k0 = 0; k0 < K; k0 += 64) {
    #pragma unroll
    for (int q = 0; q < 4; q++) {
      gload_lds16(ga + (size_t)q * 32 * K + k0, lbaseA + q * 4096);
      gload_lds16(gb + (size_t)q * 32 * K + k0, lbaseB + q * 4096);
    }
    __syncthreads();
    #pragma unroll
    for (int kk = 0; kk < 2; kk++) {
      bf16x8 af[4], bfr[4];
      int kb = kk * 32 + (lane >> 4) * 8;
      #pragma unroll
      for (int i = 0; i < 4; i++)
        af[i] = *(const bf16x8*)&As[(wm * 64 + i * 16 + (lane & 15)) * 64 + kb];
      #pragma unroll
      for (int j = 0; j < 4; j++)
        bfr[j] = *(const bf16x8*)&Bs[(wn * 64 + j * 16 + (lane & 15)) * 64 + kb];
      #pragma unroll
      for (int i = 0; i < 4; i++)
        #pragma unroll
        for (int j = 0; j < 4; j++)
          acc[i][j] = __builtin_amdgcn_mfma_f32_16x16x32_bf16(af[i], bfr[j], acc[i][j], 0, 0, 0);
    }
    __syncthreads();
  }
  int rq = lane >> 4, cq = lane & 15;
  #pragma unroll
  for (int mi = 0; mi < 4; mi++) {
    int lm = m0 + wm * 64 + mi * 16 + rq * 4;
    float wxr[4], wyr[4], bbr[4];
    #pragma unroll
    for (int r = 0; r < 4; r++) {
      int o = lm + r;
      wxr[r] = wf[(size_t)o * (K + 2) + K];
      wyr[r] = wf[(size_t)o * (K + 2) + K + 1];
      bbr[r] = bias[o];
    }
    #pragma unroll
    for (int ni = 0; ni < 4; ni++) {
      int gn = n0 + wn * 64 + ni * 16 + cq;
      int b = gn >> LOGHW;
      int hw = gn & (HW - 1);
      int x = hw & (WD - 1), y = hw >> LOGW;
      float xg = -1.0f + x * (2.0f / (WD - 1));
      float yg = -1.0f + y * (2.0f / (WD - 1));
      float vals[4];
      #pragma unroll
      for (int r = 0; r < 4; r++)
        vals[r] = acc[mi][ni][r] + wxr[r] * xg + wyr[r] * yg + bbr[r];
      if (lm < PHIC) {
        #pragma unroll
        for (int r = 0; r < 4; r++)
          outHW[(size_t)b * outHW_bstride + (size_t)(lm + r) * HW + hw] = vals[r];
      }
      u16x4 pk;
      #pragma unroll
      for (int r = 0; r < 4; r++) pk[r] = f2bf(vals[r]);
      *(u16x4*)&outCM[((size_t)b * HW + hw) * CST + lm] = pk;
    }
  }
}

// bilinear helpers (half-pixel, edge clamp)
template <int Hin>
__device__ __forceinline__ void bilin_coords(int v, int& i0, int& i1, float& wgt) {
  constexpr float scale = (float)Hin / 64.0f;
  float f = ((float)v + 0.5f) * scale - 0.5f;
  float f0 = floorf(f);
  wgt = f - f0;
  int i = (int)f0;
  i1 = min(i + 1, Hin - 1);
  i0 = max(i, 0);
}

// ---------------- emit out_phi (fp32, hw fastest) — 4 px/thread ----------------
template <int C, int Cin, int Hin>
__global__ void emit_phi_v(const float* __restrict__ in, float* __restrict__ outp,
                           int ch_off) {
  int idx = blockIdx.x * 256 + threadIdx.x;  // over B*C*1024
  int x0 = (idx & 15) * 4;
  int y = (idx >> 4) & 63;
  int c = (idx >> 10) % C;
  int b = idx / (C * 1024);
  const float* pl = in + (size_t)(b * Cin + c) * (Hin * Hin);
  int y0, y1; float wy;
  bilin_coords<Hin>(y, y0, y1, wy);
  const float* r0 = pl + y0 * Hin;
  const float* r1 = pl + y1 * Hin;
  f32x4 o;
  #pragma unroll
  for (int k = 0; k < 4; k++) {
    int xx0, xx1; float wx;
    bilin_coords<Hin>(x0 + k, xx0, xx1, wx);
    float top = (1.0f - wx) * r0[xx0] + wx * r0[xx1];
    float bot = (1.0f - wx) * r1[xx0] + wx * r1[xx1];
    o[k] = (1.0f - wy) * top + wy * bot;
  }
  *(f32x4*)&outp[((size_t)b * 896 + ch_off + c) * 4096 + (y << 6) + x0] = o;
}

// ---------------- fp32 [R][Cc] -> bf16 [c][r] transpose (strided out) ----------------
__global__ __launch_bounds__(256) void trans_f32_bf16(
    const float* __restrict__ in, u16* __restrict__ outT, int R, int Cc, int OS,
    size_t in_bstride, size_t out_bstride) {
  int b = blockIdx.z;
  in += (size_t)b * in_bstride;
  outT += (size_t)b * out_bstride;
  int r0 = blockIdx.y * 32, c0 = blockIdx.x * 32;
  __shared__ float t[32][33];
  int tid = threadIdx.x;
  int cl = tid & 31, rl = tid >> 5;  // rl 0..7
  #pragma unroll
  for (int q = 0; q < 4; q++)
    t[rl + q * 8][cl] = in[(size_t)(r0 + rl + q * 8) * Cc + c0 + cl];
  __syncthreads();
  #pragma unroll
  for (int q = 0; q < 4; q++) {
    int c = c0 + rl + q * 8;
    outT[(size_t)c * OS + r0 + cl] = f2bf(t[cl][rl + q * 8]);
  }
}

// ---------------- gather A from transposed OT[b][p][C] (bf16), 8 ch/thread ----------------
template <int C, int Hin, int L>  // L = log2(C/8)
__global__ void gather_A(const u16* __restrict__ OT, u16* __restrict__ A,
                         int ch_off) {
  int idx = blockIdx.x * 256 + threadIdx.x;  // over B*4096*(C/8)
  int co = (idx & ((C / 8) - 1)) * 8;
  int hw = (idx >> L) & 4095;
  int b = idx >> (L + 12);
  int x = hw & 63, y = hw >> 6;
  int y0, y1, x0, x1; float wy, wx;
  bilin_coords<Hin>(y, y0, y1, wy);
  bilin_coords<Hin>(x, x0, x1, wx);
  float w00 = (1.0f - wy) * (1.0f - wx), w01 = (1.0f - wy) * wx;
  float w10 = wy * (1.0f - wx), w11 = wy * wx;
  const u16* base = OT + (size_t)b * (Hin * Hin) * C + co;
  bf16x8 t00 = *(const bf16x8*)&base[(y0 * Hin + x0) * C];
  bf16x8 t01 = *(const bf16x8*)&base[(y0 * Hin + x1) * C];
  bf16x8 t10 = *(const bf16x8*)&base[(y1 * Hin + x0) * C];
  bf16x8 t11 = *(const bf16x8*)&base[(y1 * Hin + x1) * C];
  bf16x8 o;
  #pragma unroll
  for (int e = 0; e < 8; e++) {
    float v = w00 * bf2f((u16)t00[e]) + w01 * bf2f((u16)t01[e]) +
              w10 * bf2f((u16)t10[e]) + w11 * bf2f((u16)t11[e]);
    o[e] = (short)f2bf(v);
  }
  *(bf16x8*)&A[((size_t)b * 4096 + hw) * 1792 + ch_off + co] = o;
}

// ---------------- row sum of squares over bf16 rows ----------------
__global__ __launch_bounds__(256) void rownorm2(const u16* __restrict__ X,
                                                float* __restrict__ out, int ncols) {
  int row = blockIdx.x * 4 + (threadIdx.x >> 6);
  int lane = threadIdx.x & 63;
  const u16* xr = X + (size_t)row * ncols;
  int n8 = ncols >> 3;
  float s = 0.0f;
  for (int c8 = lane; c8 < n8; c8 += 64) {
    bf16x8 v = *(const bf16x8*)&xr[c8 * 8];
    #pragma unroll
    for (int e = 0; e < 8; e++) {
      float f = bf2f((u16)v[e]);
      s = fmaf(f, f, s);
    }
  }
  #pragma unroll
  for (int off = 32; off; off >>= 1) s += __shfl_down(s, off);
  if (lane == 0) out[row] = s;
}

// ======== 256x256-tile deep-pipelined distance GEMM (bf16 S output) ========
#define GD_NT 56  // K/32

// LDS row stride 64B -> conflict-free 16B-slot swizzle: phys = logical ^ ((row>>1)&3).
__device__ __forceinline__ void stage16k(const u16* __restrict__ G, int row0,
                                         int k0, char* lds_wavebase, int lane) {
  const int K = 1792;
  int sub = lane >> 2;                            // row within 16-row group
  int colsw = 8 * ((lane & 3) ^ ((lane >> 3) & 3));  // logical col for phys slot lane&3
  #pragma unroll
  for (int q = 0; q < 2; q++) {
    gload_lds16(G + (size_t)(row0 + q * 128 + sub) * K + k0 + colsw,
                lds_wavebase + q * 8192);
  }
}

__global__ __launch_bounds__(512, 2) void gemm_dist2(
    const u16* __restrict__ A,   // [16384][1792]
    const u16* __restrict__ Bt,  // [4096][1792]
    const float* __restrict__ feats, const float* __restrict__ cents,
    u16* __restrict__ S16, int m_base) {
  const int K = 1792, N = 4096;
  extern __shared__ u16 lds[];  // 4 bufs x (A 8192 + B 8192) elems = 128 KiB
  int bid = blockIdx.x;
  int swz = (bid & 7) * 32 + (bid >> 3);
  int m0 = (swz >> 4) * 256;
  int n0 = (swz & 15) * 256;
  int tid = threadIdx.x;
  int wid = tid >> 6, lane = tid & 63;
  int wr = wid >> 2, wc = wid & 3;  // wave -> 128x64 output sub-tile
  int ln15 = lane & 15;
  int fo = 8 * ((lane >> 4) ^ ((lane >> 1) & 3));  // phys slot for row=ln15

  f32x4 acc[8][4] = {};

  #pragma unroll
  for (int t = 0; t < 3; t++) {
    char* bufb = (char*)lds + (t & 3) * 32768 + wid * 1024;
    stage16k(A, m_base + m0 + wid * 16, t * 32, bufb, lane);
    stage16k(Bt, n0 + wid * 16, t * 32, bufb + 16384, lane);
  }

  // single barrier per K-tile: {vmcnt(8); barrier; 12 ds_reads; 4 stage loads;
  // 32 MFMA with compiler-fine lgkmcnt}.
  #pragma unroll 1
  for (int t = 0; t < GD_NT; t++) {
    asm volatile("s_waitcnt vmcnt(8)" ::: "memory");
    __builtin_amdgcn_s_barrier();
    __builtin_amdgcn_sched_barrier(0);
    const u16* Ab = lds + (t & 3) * 16384;
    const u16* Bb = Ab + 8192;
    char* nbuf = (char*)lds + ((t + 3) & 3) * 32768 + wid * 1024;

    bf16x8 bq[4], af[8];
    #pragma unroll
    for (int ni = 0; ni < 4; ni++)
      bq[ni] = *(const bf16x8*)&Bb[(wc * 64 + ni * 16 + ln15) * 32 + fo];
    #pragma unroll
    for (int mi = 0; mi < 8; mi++)
      af[mi] = *(const bf16x8*)&Ab[(wr * 128 + mi * 16 + ln15) * 32 + fo];

    if (t + 3 < GD_NT) {
      stage16k(A, m_base + m0 + wid * 16, (t + 3) * 32, nbuf, lane);
      stage16k(Bt, n0 + wid * 16, (t + 3) * 32, nbuf + 16384, lane);
    }

    __builtin_amdgcn_s_setprio(1);
    #pragma unroll
    for (int mi = 0; mi < 8; mi++)
      #pragma unroll
      for (int ni = 0; ni < 4; ni++)
        acc[mi][ni] = __builtin_amdgcn_mfma_f32_16x16x32_bf16(af[mi], bq[ni], acc[mi][ni], 0, 0, 0);
    __builtin_amdgcn_s_setprio(0);
  }

  int rq = lane >> 4, cq = lane & 15;
  #pragma unroll
  for (int mi = 0; mi < 8; mi++) {
    int lm = m0 + wr * 128 + mi * 16 + rq * 4;
    #pragma unroll
    for (int ni = 0; ni < 4; ni++) {
      int gn = n0 + wc * 64 + ni * 16 + cq;
      float cn = cents[gn];
      #pragma unroll
      for (int r = 0; r < 4; r++)
        S16[(size_t)(lm + r) * N + gn] =
            f2bf(feats[m_base + lm + r] + cn - 2.0f * acc[mi][ni][r]);
    }
  }
}

// ---------------- per-row top-200 smallest (sorted) of 4096 bf16 keys ----------------
// wave-per-row; 16-bit ordinal binary search (<=16 iters); register bitonic sort.
__global__ __launch_bounds__(256) void select_topk(const u16* __restrict__ S16,
                                                   float* __restrict__ out,
                                                   int row_base) {
  int wv = threadIdx.x >> 6, lane = threadIdx.x & 63;
  int row_local = blockIdx.x * 4 + wv;
  const u16* Sr = S16 + (size_t)row_local * 4096;
  uint32_t ku[64];
  #pragma unroll
  for (int g = 0; g < 8; g++) {
    bf16x8 v = *(const bf16x8*)&Sr[g * 512 + lane * 8];
    #pragma unroll
    for (int e = 0; e < 8; e++) {
      uint32_t u = (uint32_t)(u16)v[e];
      u ^= (u & 0x8000u) ? 0xFFFFu : 0x8000u;  // order-preserving 16-bit ordinal
      ku[g * 8 + e] = u;
    }
  }
  uint32_t mn = 0xFFFFu, mx = 0u;
  #pragma unroll
  for (int j = 0; j < 64; j++) {
    mn = min(mn, ku[j]);
    mx = max(mx, ku[j]);
  }
  #pragma unroll
  for (int off = 1; off < 64; off <<= 1) {
    mn = min(mn, (uint32_t)__shfl_xor((int)mn, off));
    mx = max(mx, (uint32_t)__shfl_xor((int)mx, off));
  }
  // binary search for the 200th smallest ordinal T (<=16 iterations)
  uint32_t lo = mn, hi = mx;
  while (lo < hi) {
    uint32_t mid = (lo + hi) >> 1;
    int c = 0;
    #pragma unroll
    for (int j = 0; j < 64; j++) c += (ku[j] <= mid) ? 1 : 0;
    #pragma unroll
    for (int off = 1; off < 64; off <<= 1) c += __shfl_xor(c, off);
    if (c >= 200) hi = mid; else lo = mid + 1;
  }
  uint32_t T = lo;
  int cl = 0;
  #pragma unroll
  for (int j = 0; j < 64; j++) cl += (ku[j] < T) ? 1 : 0;
  int incl = cl;
  #pragma unroll
  for (int off = 1; off < 64; off <<= 1) {
    int v = __shfl_up(incl, off);
    if (lane >= off) incl += v;
  }
  int nless = __shfl(incl, 63);  // < 200 by definition of T
  int pos = incl - cl;
  __shared__ uint32_t selv[4][256];
  uint32_t* sv = selv[wv];
  #pragma unroll
  for (int g = 0; g < 4; g++) sv[g * 64 + lane] = 0xFFFFFFFFu;
  for (int p = nless + lane; p < 200; p += 64) sv[p] = T;
  #pragma unroll
  for (int j = 0; j < 64; j++)
    if (ku[j] < T) sv[pos++] = ku[j];
  uint32_t v[4];
  #pragma unroll
  for (int q = 0; q < 4; q++) v[q] = sv[q * 64 + lane];
  #pragma unroll
  for (int kk = 2; kk <= 256; kk <<= 1) {
    #pragma unroll
    for (int jj = kk >> 1; jj > 0; jj >>= 1) {
      if (jj >= 64) {
        int qb = jj >> 6;
        #pragma unroll
        for (int q = 0; q < 4; q++) {
          if ((q & qb) == 0) {
            int q2 = q | qb;
            bool up = (kk == 256) ? true : ((q & (kk >> 6)) == 0);
            uint32_t a = v[q], b2 = v[q2];
            uint32_t lo2 = min(a, b2), hi2 = max(a, b2);
            v[q] = up ? lo2 : hi2;
            v[q2] = up ? hi2 : lo2;
          }
        }
      } else {
        #pragma unroll
        for (int q = 0; q < 4; q++) {
          bool up;
          if (kk == 256) up = true;
          else if (kk == 128) up = ((q & 2) == 0);
          else if (kk == 64) up = ((q & 1) == 0);
          else up = ((lane & kk) == 0);
          uint32_t other = (uint32_t)__shfl_xor((int)v[q], jj);
          bool lower = ((lane & jj) == 0);
          uint32_t lo2 = min(v[q], other), hi2 = max(v[q], other);
          v[q] = (up == lower) ? lo2 : hi2;
        }
      }
    }
  }
  int grow = row_base + row_local;
  int b = grow >> 12, r = grow & 4095;
  #pragma unroll
  for (int q = 0; q < 4; q++) {
    int i = q * 64 + lane;
    if (i < 200) {
      uint32_t u = v[q] & 0xFFFFu;
      u ^= (u & 0x8000u) ? 0x8000u : 0xFFFFu;  // undo ordinal
      out[((size_t)b * 200 + i) * 4096 + r] = sqrtf(bf2f((u16)u));
    }
  }
}

extern "C" void kernel_launch(void* const* d_in, const int* in_sizes, int n_in,
                              void* d_out, int out_size, void* d_ws, size_t ws_size,
                              hipStream_t stream) {
  const float* p0 = (const float*)d_in[0];   // (4,256,64,64)
  const float* p1 = (const float*)d_in[1];   // (4,512,32,32)
  const float* p2 = (const float*)d_in[2];   // (4,1024,16,16)
  const float* w1 = (const float*)d_in[5];   // (256,258)
  const float* b1 = (const float*)d_in[6];
  const float* w2 = (const float*)d_in[7];   // (512,514)
  const float* b2 = (const float*)d_in[8];
  const float* w3 = (const float*)d_in[9];   // (1024,1026)
  const float* b3 = (const float*)d_in[10];
  const float* Cm = (const float*)d_in[11];  // (1792,4096)

  float* out_score = (float*)d_out;                  // 4*200*4096 fp32
  float* out_phi = (float*)d_out + 3276800;          // 4*896*4096 fp32

  // workspace layout (peak ~107 MB)
  char* w = (char*)d_ws;
  u16* Abf = (u16*)w;                                //  58,720,256 B
  u16* Ct = (u16*)(w + 58720256);                    //  14,680,064 B
  float* feats = (float*)(w + 73400320);             //      65,536 B
  float* cents = (float*)(w + 73465856);             //      16,384 B
  u16* S16 = (u16*)(w + 73482240);                   //  33,554,432 B (bf16, per-chunk) -> ends 107,036,672
  // stage-A temps all alias the S region (dead before first gemm_dist2):
  u16* PT1 = (u16*)(w + 73482240);                   //   8,388,608 B [16384][256]
  u16* PT2 = (u16*)(w + 81870848);                   //   4,194,304 B [4096][512]
  u16* PT3 = (u16*)(w + 86065152);                   //   2,097,152 B [1024][1024]
  u16* Wbf1 = (u16*)(w + 88162304);                  //     131,072 B
  u16* Wbf2 = (u16*)(w + 88293376);                  //     524,288 B
  u16* Wbf3 = (u16*)(w + 88817664);                  //   2,097,152 B
  float* O2 = (float*)(w + 90914816);                //   8,388,608 B [4][512][1024]
  float* O3 = (float*)(w + 99303424);                //     524,288 B [4][128][256]
  u16* OT2 = (u16*)(w + 99827712);                   //   4,194,304 B [4][1024][512]
  u16* OT3 = (u16*)(w + 104022016);                  //   2,097,152 B [4][256][1024] -> ends 106,119,168 (< 107,036,672 OK)

  // ---- fused pool + transpose + bf16 -> PT ----
  pool_trans<256, 64, 64><<<dim3(128, 8, 4), 256, 0, stream>>>(p0, PT1);
  pool_trans<512, 32, 32><<<dim3(32, 16, 4), 256, 0, stream>>>(p1, PT2);
  pool_trans<1024, 16, 16><<<dim3(8, 32, 4), 256, 0, stream>>>(p2, PT3);

  // ---- weights -> bf16 ----
  wconv_bf16<<<32, 256, 0, stream>>>(w1, Wbf1, 8, 8192);
  wconv_bf16<<<128, 256, 0, stream>>>(w2, Wbf2, 9, 32768);
  wconv_bf16<<<512, 256, 0, stream>>>(w3, Wbf3, 10, 131072);

  // ---- coordconv via MFMA GEMM, dual-layout epilogue ----
  conv_gemm<256, 4096, 64, 256, 256, 1792><<<dim3(128, 2), 256, 0, stream>>>(
      Wbf1, PT1, w1, b1, out_phi, (size_t)896 * 4096, Abf);
  conv_gemm<512, 1024, 32, 512, 512, 512><<<dim3(32, 4), 256, 0, stream>>>(
      Wbf2, PT2, w2, b2, O2, (size_t)512 * 1024, OT2);
  conv_gemm<1024, 256, 16, 1024, 128, 1024><<<dim3(8, 8), 256, 0, stream>>>(
      Wbf3, PT3, w3, b3, O3, (size_t)128 * 256, OT3);

  // ---- out_phi levels 2,3 (bilinear resize) ----
  emit_phi_v<512, 512, 32><<<8192, 256, 0, stream>>>(O2, out_phi, 256);
  emit_phi_v<128, 128, 16><<<2048, 256, 0, stream>>>(O3, out_phi, 768);

  // ---- A matrix cols [256,1792): coalesced gather from OT ----
  gather_A<512, 32, 6><<<4096, 256, 0, stream>>>(OT2, Abf, 256);
  gather_A<1024, 16, 7><<<8192, 256, 0, stream>>>(OT3, Abf, 768);

  // ---- C transpose + bf16 ----
  trans_f32_bf16<<<dim3(128, 56, 1), 256, 0, stream>>>(Cm, Ct, 1792, 4096, 1792, 0, 0);

  // ---- norms ----
  rownorm2<<<4096, 256, 0, stream>>>(Abf, feats, 1792);
  rownorm2<<<1024, 256, 0, stream>>>(Ct, cents, 1792);

  // ---- distance GEMM (bf16 S) + top-200, chunked by batch image ----
  for (int mc = 0; mc < 4; mc++) {
    gemm_dist2<<<256, 512, 131072, stream>>>(Abf, Ct, feats, cents, S16, mc * 4096);
    select_topk<<<1024, 256, 0, stream>>>(S16, out_score, mc * 4096);
  }
}